// Round 9
// baseline (204.066 us; speedup 1.0000x reference)
//
#include <hip/hip_runtime.h>
#include <math.h>

#define BB 4
#define TT 512
#define MM 77
#define HH 10
#define DD 64
#define LATD 640
#define EE 8
#define FFND 256
#define NS 685     // 512 + 48 + 48 + 77
#define NCH 11     // ceil(685/64)
#define NSP 704    // NCH*64 padded s extent
#define NROWS 20480

#define NTOK_M (BB*TT*HH)   // 20480
#define NTOK_T (BB*MM*HH)   // 3080
#define MAXB_M 647
#define MAXB_T 103

typedef float f32x4 __attribute__((ext_vector_type(4)));
typedef __bf16 bf16x8_t __attribute__((ext_vector_type(8)));
typedef unsigned short u16x8 __attribute__((ext_vector_type(8)));

__device__ __forceinline__ float geluf(float x){
    float u = 0.7978845608028654f*(x + 0.044715f*x*x*x);
    u = fminf(fmaxf(u, -15.f), 15.f);
    float e = __expf(2.f*u);
    return 0.5f*x*(1.f + (e-1.f)/(e+1.f));
}
__device__ __forceinline__ float siluf(float x){
    return x / (1.0f + __expf(-x));
}
__device__ __forceinline__ unsigned short f2bf(float f){
    unsigned int u = __float_as_uint(f);
    u += 0x7fff + ((u >> 16) & 1);
    return (unsigned short)(u >> 16);
}
__device__ __forceinline__ uint2 pack4bf(float a, float b, float c, float d){
    uint2 r;
    r.x = (unsigned)f2bf(a) | ((unsigned)f2bf(b)<<16);
    r.y = (unsigned)f2bf(c) | ((unsigned)f2bf(d)<<16);
    return r;
}

// ---------------- fused weight prep: all transposes+bf16 in one launch ----------------
__global__ __launch_bounds__(256) void prep_weights_kernel(
    const float* __restrict__ m_w1, unsigned short* __restrict__ w1Tm,
    const float* __restrict__ m_w2, unsigned short* __restrict__ w2Tm,
    const float* __restrict__ c_w1, unsigned short* __restrict__ w1Tt,
    const float* __restrict__ c_w2, unsigned short* __restrict__ w2Tt,
    const float* __restrict__ st_ew, unsigned short* __restrict__ stewT,
    const float* __restrict__ st_ow, unsigned short* __restrict__ stowT,
    const float* __restrict__ m_pw, unsigned short* __restrict__ mpwT,
    const float* __restrict__ c_pw, unsigned short* __restrict__ cpwT)
{
    __shared__ float t[64][65];
    const int bid = blockIdx.x, tid = threadIdx.x;
    const float* in; unsigned short* out; int R, C, z, rt, ct;
    if (bid < 32)      { int l=bid;     in=m_w1;  out=w1Tm;  R=64;  C=256;  z=l>>2; rt=0;    ct=l&3; }
    else if (bid < 64) { int l=bid-32;  in=m_w2;  out=w2Tm;  R=256; C=64;   z=l>>2; rt=l&3;  ct=0; }
    else if (bid < 96) { int l=bid-64;  in=c_w1;  out=w1Tt;  R=64;  C=256;  z=l>>2; rt=0;    ct=l&3; }
    else if (bid < 128){ int l=bid-96;  in=c_w2;  out=w2Tt;  R=256; C=64;   z=l>>2; rt=l&3;  ct=0; }
    else if (bid < 288){ int l=bid-128; in=st_ew; out=stewT; R=512; C=1280; z=0;    rt=l/20; ct=l%20; }
    else if (bid < 388){ int l=bid-288; in=st_ow; out=stowT; R=640; C=640;  z=0;    rt=l/10; ct=l%10; }
    else if (bid < 393){ int l=bid-388; in=m_pw;  out=mpwT;  R=64;  C=320;  z=0;    rt=0;    ct=l; }
    else               { int l=bid-393; in=c_pw;  out=cpwT;  R=64;  C=128;  z=0;    rt=0;    ct=l; }
    const size_t base = (size_t)z*R*C;
    const int r0 = rt*64, c0 = ct*64;
    #pragma unroll
    for (int p=0; p<16; ++p){
        int i = tid + p*256;
        int r = i>>6, c = i&63;
        t[r][c] = in[base + (size_t)(r0+r)*C + c0 + c];
    }
    __syncthreads();
    #pragma unroll
    for (int p=0; p<16; ++p){
        int i = tid + p*256;
        int c = i>>6, r = i&63;
        out[base + (size_t)(c0+c)*R + r0 + r] = f2bf(t[r][c]);
    }
}

// ---------------- LayerNorm (rows of 640), optional additive emb (T,640) ----------------
__global__ __launch_bounds__(256) void ln_kernel(
    const float* __restrict__ in, const float* __restrict__ g, const float* __restrict__ bb,
    const float* __restrict__ addv, float* __restrict__ out, int seqLen)
{
    int row = blockIdx.x, tid = threadIdx.x;
    __shared__ float xsr[LATD];
    __shared__ float red[256];
    const float* rp = in + (size_t)row*LATD;
    float s = 0.f;
    for (int i=tid;i<LATD;i+=256){ float v = rp[i]; xsr[i]=v; s+=v; }
    red[tid]=s; __syncthreads();
    for (int k=128;k>0;k>>=1){ if (tid<k) red[tid]+=red[tid+k]; __syncthreads(); }
    float mean = red[0]*(1.0f/LATD);
    __syncthreads();
    float vs=0.f;
    for (int i=tid;i<LATD;i+=256){ float d=xsr[i]-mean; vs+=d*d; }
    red[tid]=vs; __syncthreads();
    for (int k=128;k>0;k>>=1){ if (tid<k) red[tid]+=red[tid+k]; __syncthreads(); }
    float rstd = rsqrtf(red[0]*(1.0f/LATD)+1e-5f);
    int t = row % seqLen;
    const float* ap = addv ? (addv + (size_t)t*LATD) : nullptr;
    float* op = out + (size_t)row*LATD;
    for (int i=tid;i<LATD;i+=256){
        float v = (xsr[i]-mean)*rstd*g[i] + bb[i];
        if (ap) v += ap[i];
        op[i] = v;
    }
}

// ---------------- MoE routing (block-aggregated atomics) ----------------
__global__ void zero_counts_kernel(int* __restrict__ c){
    if (threadIdx.x < 16) c[threadIdx.x] = 0;
}

__global__ __launch_bounds__(256) void route_kernel(
    const float* __restrict__ xin, const float* __restrict__ wg, int nTok,
    int* __restrict__ counts, int* __restrict__ list, float* __restrict__ wA)
{
    __shared__ int bcnt[EE];
    __shared__ int bbase[EE];
    const int tid = threadIdx.x;
    const int t = blockIdx.x*256 + tid;
    if (tid < EE) bcnt[tid] = 0;
    __syncthreads();

    int e0 = 0, e1 = 0, p0 = 0, p1 = 0;
    bool act = (t < nTok);
    if (act){
        float lg[EE];
        #pragma unroll
        for (int e=0;e<EE;e++) lg[e]=0.f;
        const float4* xp = (const float4*)(xin + (size_t)t*DD);
        #pragma unroll 4
        for (int dq=0; dq<16; ++dq){
            float4 xv = xp[dq];
            const float* w0 = wg + (dq*4+0)*EE;
            const float* w1 = wg + (dq*4+1)*EE;
            const float* w2 = wg + (dq*4+2)*EE;
            const float* w3 = wg + (dq*4+3)*EE;
            #pragma unroll
            for (int e=0;e<EE;e++)
                lg[e] += xv.x*w0[e] + xv.y*w1[e] + xv.z*w2[e] + xv.w*w3[e];
        }
        float mx = lg[0];
        #pragma unroll
        for (int e=1;e<EE;e++) mx = fmaxf(mx, lg[e]);
        float sum = 0.f;
        #pragma unroll
        for (int e=0;e<EE;e++){ lg[e] = __expf(lg[e]-mx); sum += lg[e]; }
        float inv = 1.0f/sum;
        #pragma unroll
        for (int e=0;e<EE;e++) lg[e] *= inv;
        float v0=lg[0];
        #pragma unroll
        for (int e=1;e<EE;e++){ if (lg[e] > v0){ v0 = lg[e]; e0 = e; } }
        float v1=-1e30f; e1 = (e0==0) ? 1 : 0;
        #pragma unroll
        for (int e=0;e<EE;e++){ if (e==e0) continue; if (lg[e] > v1){ v1 = lg[e]; e1 = e; } }
        wA[t*2+0]=v0; wA[t*2+1]=v1;
        p0 = atomicAdd(&bcnt[e0], 1);
        p1 = atomicAdd(&bcnt[e1], 1);
    }
    __syncthreads();
    if (tid < EE){
        bbase[tid] = (bcnt[tid] > 0) ? atomicAdd(&counts[tid], bcnt[tid]) : 0;
    }
    __syncthreads();
    if (act){
        list[(size_t)e0*nTok + bbase[e0] + p0] = t*2;
        list[(size_t)e1*nTok + bbase[e1] + p1] = t*2+1;
    }
}

// ---------------- grouped expert FFN (MFMA): block = (expert, 64-token tile), 4 waves ----
__global__ __launch_bounds__(256) void moe_ffn_kernel(
    const float* __restrict__ xin,
    const unsigned short* __restrict__ w1T,
    const float* __restrict__ b1g,
    const unsigned short* __restrict__ w2T,
    const float* __restrict__ b2g,
    const int* __restrict__ counts, const int* __restrict__ list,
    const float* __restrict__ wA, int nTok,
    float* __restrict__ yslot)
{
    __shared__ __align__(16) unsigned short xs[64][72];
    __shared__ __align__(16) unsigned short w1s[64][72];
    __shared__ __align__(16) unsigned short w2s[64][72];
    __shared__ __align__(16) unsigned short hs[64][72];
    __shared__ int sCnt[EE];
    __shared__ int encs[64];
    __shared__ float wgts[64];
    const int tid = threadIdx.x;
    if (tid < EE) sCnt[tid] = counts[tid];
    __syncthreads();
    int e = -1, tile = 0;
    {
        int acc = 0, bid = blockIdx.x;
        #pragma unroll
        for (int i=0;i<EE;++i){
            int tc = (sCnt[i]+63)>>6;
            if (e < 0 && bid < acc + tc){ e = i; tile = bid - acc; }
            acc += tc;
        }
    }
    if (e < 0) return;
    const int cnt = sCnt[e];
    if (tid < 64){
        int idx = tile*64 + tid;
        int enc = (idx < cnt) ? list[(size_t)e*nTok + idx] : -1;
        encs[tid] = enc;
        wgts[tid] = (enc >= 0) ? wA[enc] : 0.f;
    }
    __syncthreads();
    for (int i=tid; i<64*16; i+=256){
        int r = i>>4, dq4 = (i&15)*4;
        int enc = encs[r];
        float4 xv = make_float4(0.f,0.f,0.f,0.f);
        if (enc >= 0) xv = *(const float4*)(xin + (size_t)(enc>>1)*DD + dq4);
        *(uint2*)&xs[r][dq4] = pack4bf(xv.x, xv.y, xv.z, xv.w);
    }

    const int w    = tid >> 6;
    const int lane = tid & 63;
    const int lq   = lane & 15;
    const int lg   = lane >> 4;

    const unsigned short* w1e = w1T + (size_t)e*FFND*DD;
    const unsigned short* w2e = w2T + (size_t)e*DD*FFND;

    f32x4 acc2[4] = {};

    for (int fc=0; fc<4; ++fc){
        __syncthreads();
        for (int i=tid; i<512; i+=256){
            int r = i>>3, jq = i&7;
            *(uint4*)&w1s[r][jq*8] = *(const uint4*)(w1e + (size_t)(fc*64+r)*DD + jq*8);
            *(uint4*)&w2s[r][jq*8] = *(const uint4*)(w2e + (size_t)r*FFND + fc*64 + jq*8);
        }
        __syncthreads();
        f32x4 acc1[4] = {};
        #pragma unroll
        for (int fb=0; fb<4; ++fb){
            #pragma unroll
            for (int ks=0; ks<2; ++ks){
                bf16x8_t xf = *reinterpret_cast<const bf16x8_t*>(&xs[w*16+lq][ks*32+lg*8]);
                bf16x8_t wf = *reinterpret_cast<const bf16x8_t*>(&w1s[fb*16+lq][ks*32+lg*8]);
                acc1[fb] = __builtin_amdgcn_mfma_f32_16x16x32_bf16(xf, wf, acc1[fb], 0, 0, 0);
            }
        }
        #pragma unroll
        for (int fb=0; fb<4; ++fb){
            float b1v = b1g[e*FFND + fc*64 + fb*16 + lq];
            #pragma unroll
            for (int r=0; r<4; ++r)
                hs[w*16 + lg*4 + r][fb*16 + lq] = f2bf(geluf(acc1[fb][r] + b1v));
        }
        #pragma unroll
        for (int db=0; db<4; ++db){
            #pragma unroll
            for (int ks=0; ks<2; ++ks){
                bf16x8_t hf  = *reinterpret_cast<const bf16x8_t*>(&hs[w*16+lq][ks*32+lg*8]);
                bf16x8_t w2f = *reinterpret_cast<const bf16x8_t*>(&w2s[db*16+lq][ks*32+lg*8]);
                acc2[db] = __builtin_amdgcn_mfma_f32_16x16x32_bf16(hf, w2f, acc2[db], 0, 0, 0);
            }
        }
    }
    #pragma unroll
    for (int r=0; r<4; ++r){
        int tok = w*16 + lg*4 + r;
        int enc = encs[tok];
        if (enc >= 0){
            float gw = wgts[tok];
            #pragma unroll
            for (int db=0; db<4; ++db){
                int d = db*16 + lq;
                yslot[(size_t)enc*DD + d] = gw*(acc2[db][r] + b2g[e*DD + d]);
            }
        }
    }
}

// ---------------- combine slots + gelu + MFMA projection (token-major output) ----------------
template<int NPROJ>
__global__ __launch_bounds__(256) void moe_proj_mfma_kernel(
    const float* __restrict__ yslot, const unsigned short* __restrict__ pwT,
    const float* __restrict__ pbg, int nTok,
    float* __restrict__ out0, float* __restrict__ out1, float* __restrict__ out2)
{
    __shared__ __align__(16) unsigned short gs[64][72];
    const int tid = threadIdx.x;
    const int base = blockIdx.x*64;
    for (int i=tid; i<64*16; i+=256){
        int r = i>>4, dq4 = (i&15)*4;
        int tok = base + r;
        float4 g4 = make_float4(0.f,0.f,0.f,0.f);
        if (tok < nTok){
            float4 a = *(const float4*)(yslot + (size_t)tok*128 + dq4);
            float4 b = *(const float4*)(yslot + (size_t)tok*128 + 64 + dq4);
            g4.x = geluf(a.x+b.x); g4.y = geluf(a.y+b.y);
            g4.z = geluf(a.z+b.z); g4.w = geluf(a.w+b.w);
        }
        *(uint2*)&gs[r][dq4] = pack4bf(g4.x, g4.y, g4.z, g4.w);
    }
    __syncthreads();

    const int w    = tid >> 6;
    const int lane = tid & 63;
    const int lq   = lane & 15;
    const int lg   = lane >> 4;
    constexpr int NC = NPROJ/64;
    const int colbase = w*16*NC;

    bf16x8_t wf[NC][2];
    #pragma unroll
    for (int cb=0; cb<NC; ++cb)
        #pragma unroll
        for (int ks=0; ks<2; ++ks)
            wf[cb][ks] = *reinterpret_cast<const bf16x8_t*>(
                pwT + (size_t)(colbase + cb*16 + lq)*DD + ks*32 + lg*8);

    f32x4 acc[4][NC] = {};
    #pragma unroll
    for (int m=0; m<4; ++m){
        #pragma unroll
        for (int ks=0; ks<2; ++ks){
            bf16x8_t af = *reinterpret_cast<const bf16x8_t*>(&gs[m*16+lq][ks*32+lg*8]);
            #pragma unroll
            for (int cb=0; cb<NC; ++cb)
                acc[m][cb] = __builtin_amdgcn_mfma_f32_16x16x32_bf16(af, wf[cb][ks], acc[m][cb], 0, 0, 0);
        }
    }
    #pragma unroll
    for (int m=0; m<4; ++m){
        #pragma unroll
        for (int r=0; r<4; ++r){
            int tok = base + m*16 + lg*4 + r;
            if (tok >= nTok) continue;
            #pragma unroll
            for (int cb=0; cb<NC; ++cb){
                int j = colbase + cb*16 + lq;
                float v = acc[m][cb][r] + pbg[j];
                int bufi = j >> 6, jd = j & 63;
                float* dst = (bufi==0) ? out0 : (bufi==1) ? out1 : out2;
                dst[(size_t)tok*DD + jd] = v;
            }
        }
    }
}

// ---------------- KV prep: fused scaled bf16 K, transposed bf16 V, mask-bias row ----------
__global__ __launch_bounds__(256) void kv_prep_kernel(
    const float* __restrict__ kmb, const float* __restrict__ vmb,   // (B,T,H,64)
    const float* __restrict__ ktb, const float* __restrict__ vtb,   // (B,M,H,64)
    const float* __restrict__ kd,  const float* __restrict__ vd,    // (NDS,48,H,64)->[0]
    const float* __restrict__ kr,  const float* __restrict__ vr,    // (48,H,64)
    const int*   __restrict__ smask, const float* __restrict__ tcond,
    const float* __restrict__ kms_p, const float* __restrict__ kds_p,
    const float* __restrict__ krs_p, const float* __restrict__ kts_p,
    unsigned short* __restrict__ Kbf,   // (B*H, NSP, 64)
    unsigned short* __restrict__ VTbf,  // (B*H, 64, NSP)
    float* __restrict__ maddg)          // (B, NSP)
{
    __shared__ __align__(16) unsigned short Vs[64][72];
    const int tid = threadIdx.x;
    const int bh = blockIdx.x, ch = blockIdx.y;
    const int b = bh / HH, h = bh % HH;
    const float sc = 0.125f;
    const float kms = kms_p[0]*sc, kds = kds_p[0]*sc, krs = krs_p[0]*sc, kts = kts_p[0]*sc;
    for (int i=tid; i<64*16; i+=256){
        int r = i>>4, dq4 = (i&15)*4;
        int s = ch*64 + r;
        float4 kv = make_float4(0,0,0,0), vv = make_float4(0,0,0,0);
        if (s < TT){
            size_t o = ((size_t)(b*TT + s)*HH + h)*DD + dq4;
            kv = *(const float4*)(&kmb[o]);
            kv.x*=kms; kv.y*=kms; kv.z*=kms; kv.w*=kms;
            vv = *(const float4*)(&vmb[o]);
        } else if (s < TT+48){
            kv = *(const float4*)(&kd[((size_t)(s-TT)*HH + h)*DD + dq4]);
            kv.x*=kds; kv.y*=kds; kv.z*=kds; kv.w*=kds;
            vv = *(const float4*)(&vd[((size_t)(s-TT)*HH + h)*DD + dq4]);
        } else if (s < TT+96){
            kv = *(const float4*)(&kr[((size_t)(s-TT-48)*HH + h)*DD + dq4]);
            kv.x*=krs; kv.y*=krs; kv.z*=krs; kv.w*=krs;
            vv = *(const float4*)(&vr[((size_t)(s-TT-48)*HH + h)*DD + dq4]);
        } else if (s < NS){
            size_t o = ((size_t)(b*MM + (s-TT-96))*HH + h)*DD + dq4;
            kv = *(const float4*)(&ktb[o]);
            kv.x*=kts; kv.y*=kts; kv.z*=kts; kv.w*=kts;
            vv = *(const float4*)(&vtb[o]);
        }
        *(uint2*)(Kbf + ((size_t)bh*NSP + s)*DD + dq4) = pack4bf(kv.x, kv.y, kv.z, kv.w);
        Vs[dq4+0][r] = f2bf(vv.x);
        Vs[dq4+1][r] = f2bf(vv.y);
        Vs[dq4+2][r] = f2bf(vv.z);
        Vs[dq4+3][r] = f2bf(vv.w);
    }
    __syncthreads();
    for (int i=tid; i<512; i+=256){
        int d = i>>3, sg8 = (i&7)*8;
        *(uint4*)(VTbf + ((size_t)(bh*DD + d))*NSP + ch*64 + sg8) = *(const uint4*)&Vs[d][sg8];
    }
    if (h == 0 && tid < 64){
        int s = ch*64 + tid;
        float a;
        if (s < TT)            a = (smask[b*TT + s] == 0) ? -1e9f : 0.f;
        else if (s < TT+96)    a = 0.f;
        else if (s < NS)       a = (tcond[b] > 0.f) ? 0.f : -1e9f;
        else                   a = -1e30f;
        maddg[b*NSP + s] = a;
    }
}

// ---------------- MFMA flash attention, barrier-free main loop ----------------
// block = (b,h,32-row t-tile), 4 waves: wave = (shalf = w>>1, qhalf = w&1).
// shalf 0 -> chunks 0..5, shalf 1 -> chunks 6..10. Merge halves in LDS at end.
__global__ __launch_bounds__(256) void attn_kernel(
    const float* __restrict__ qb,          // (B,T,H,64)
    const unsigned short* __restrict__ Kbf,
    const unsigned short* __restrict__ VTbf,
    const float* __restrict__ maddg,
    const float* __restrict__ sigma_p,
    float* __restrict__ outb)              // (B,T,640)
{
    __shared__ __align__(16) unsigned short Pl[4][16][72];
    __shared__ float obuf[32][68];
    __shared__ float mlbuf[32][2];

    const int tid  = threadIdx.x;
    const int w    = tid >> 6;
    const int lane = tid & 63;
    const int lq   = lane & 15;
    const int lg   = lane >> 4;
    const int qhalf = w & 1;
    const int shalf = w >> 1;

    const int bid   = blockIdx.x;
    const int ttile = bid & 15;
    const int bh    = bid >> 4;
    const int b = bh / HH, h = bh % HH;
    const int t0 = ttile * 32;

    const float sg = sigma_p[0];
    const float inv2s = 1.0f/(2.0f*sg*sg);

    const int tgq = t0 + qhalf*16 + lq;

    bf16x8_t qf[2];
    {
        const float* qrow = qb + ((size_t)(b*TT + tgq)*HH + h)*DD;
        #pragma unroll
        for (int ks=0; ks<2; ++ks){
            float4 v0 = *(const float4*)(qrow + ks*32 + lg*8);
            float4 v1 = *(const float4*)(qrow + ks*32 + lg*8 + 4);
            u16x8 qt;
            qt[0]=f2bf(v0.x); qt[1]=f2bf(v0.y); qt[2]=f2bf(v0.z); qt[3]=f2bf(v0.w);
            qt[4]=f2bf(v1.x); qt[5]=f2bf(v1.y); qt[6]=f2bf(v1.z); qt[7]=f2bf(v1.w);
            qf[ks] = __builtin_bit_cast(bf16x8_t, qt);
        }
    }

    float m_r = -1e30f, l_r = 0.f;
    f32x4 oacc[4] = {};

    const int ch_lo = shalf ? 6 : 0;
    const int ch_hi = shalf ? NCH : 6;
    const unsigned short* Kb = Kbf + (size_t)bh*NSP*DD;
    const unsigned short* Vb = VTbf + (size_t)bh*DD*NSP;
    const float* mrow = maddg + b*NSP;

    for (int ch=ch_lo; ch<ch_hi; ++ch){
        f32x4 sacc[4] = {};
        #pragma unroll
        for (int sl=0; sl<4; ++sl){
            #pragma unroll
            for (int ks=0; ks<2; ++ks){
                bf16x8_t kf = *reinterpret_cast<const bf16x8_t*>(
                    Kb + ((size_t)(ch*64 + sl*16 + lq))*DD + ks*32 + lg*8);
                sacc[sl] = __builtin_amdgcn_mfma_f32_16x16x32_bf16(kf, qf[ks], sacc[sl], 0, 0, 0);
            }
        }
        float sv[4][4];
        float pmax = -1e30f;
        #pragma unroll
        for (int sl=0; sl<4; ++sl){
            #pragma unroll
            for (int r=0; r<4; ++r){
                int s_loc = sl*16 + lg*4 + r;
                float a = mrow[ch*64 + s_loc];
                if (ch < 8){ float dt = (float)(tgq - (ch*64 + s_loc)); a -= dt*dt*inv2s; }
                float v = sacc[sl][r] + a;
                sv[sl][r] = v;
                pmax = fmaxf(pmax, v);
            }
        }
        pmax = fmaxf(pmax, __shfl_xor(pmax, 16));
        pmax = fmaxf(pmax, __shfl_xor(pmax, 32));
        float mn  = fmaxf(m_r, pmax);
        float scl = __expf(m_r - mn);
        m_r = mn;
        float psum = 0.f;
        #pragma unroll
        for (int sl=0; sl<4; ++sl){
            #pragma unroll
            for (int r=0; r<4; ++r){
                float p = __expf(sv[sl][r] - mn);
                sv[sl][r] = p;
                psum += p;
            }
        }
        psum += __shfl_xor(psum, 16);
        psum += __shfl_xor(psum, 32);
        l_r = l_r*scl + psum;
        #pragma unroll
        for (int sl=0; sl<4; ++sl)
            *(uint2*)&Pl[w][lq][sl*16 + lg*4] = pack4bf(sv[sl][0], sv[sl][1], sv[sl][2], sv[sl][3]);

        #pragma unroll
        for (int r=0; r<4; ++r){
            float so = __shfl(scl, lg*4 + r);
            #pragma unroll
            for (int ds_=0; ds_<4; ++ds_) oacc[ds_][r] *= so;
        }
        #pragma unroll
        for (int ds_=0; ds_<4; ++ds_){
            #pragma unroll
            for (int ks=0; ks<2; ++ks){
                bf16x8_t pf = *reinterpret_cast<const bf16x8_t*>(&Pl[w][lq][ks*32 + lg*8]);
                bf16x8_t vf = *reinterpret_cast<const bf16x8_t*>(
                    Vb + ((size_t)(ds_*16 + lq))*NSP + ch*64 + ks*32 + lg*8);
                oacc[ds_] = __builtin_amdgcn_mfma_f32_16x16x32_bf16(pf, vf, oacc[ds_], 0, 0, 0);
            }
        }
    }
    // merge halves: shalf1 dumps to LDS, shalf0 combines and writes
    if (shalf == 1){
        #pragma unroll
        for (int r=0; r<4; ++r)
            #pragma unroll
            for (int ds_=0; ds_<4; ++ds_)
                obuf[qhalf*16 + lg*4 + r][ds_*16 + lq] = oacc[ds_][r];
        if (lg == 0){
            mlbuf[qhalf*16 + lq][0] = m_r;
            mlbuf[qhalf*16 + lq][1] = l_r;
        }
    }
    __syncthreads();
    if (shalf == 0){
        float m1 = mlbuf[qhalf*16 + lq][0];
        float l1 = mlbuf[qhalf*16 + lq][1];
        float m = fmaxf(m_r, m1);
        float s0 = __expf(m_r - m), s1 = __expf(m1 - m);
        float inv = 1.0f/(l_r*s0 + l1*s1);
        float f0l = s0*inv, f1l = s1*inv;
        #pragma unroll
        for (int r=0; r<4; ++r){
            float f0 = __shfl(f0l, lg*4 + r);
            float f1 = __shfl(f1l, lg*4 + r);
            int t = t0 + qhalf*16 + lg*4 + r;
            float* orow = outb + ((size_t)(b*TT + t))*LATD + h*64;
            #pragma unroll
            for (int ds_=0; ds_<4; ++ds_)
                orow[ds_*16 + lq] = oacc[ds_][r]*f0 + obuf[qhalf*16 + lg*4 + r][ds_*16 + lq]*f1;
        }
    }
}

// ---------------- bf16 MFMA GEMM 64x128 tile, BK=64. Wt pre-transposed bf16 [N][K] --------
template<bool ACT_SILU>
__global__ __launch_bounds__(256) void gemm_mfma_kernel(
    const float* __restrict__ A, const unsigned short* __restrict__ Wt,
    const float* __restrict__ bias, const float* __restrict__ res,
    float* __restrict__ C, int Mr, int Nr, int Kr)
{
    __shared__ __align__(16) unsigned short As[64][72];
    __shared__ __align__(16) unsigned short Bs[128][72];
    const int tid = threadIdx.x;
    const int row0 = blockIdx.x*64, col0 = blockIdx.y*128;
    const int w = tid >> 6, lane = tid & 63;
    const int lq = lane & 15, lg = lane >> 4;

    f32x4 acc[4][2] = {};

    for (int k0 = 0; k0 < Kr; k0 += 64){
        __syncthreads();
        #pragma unroll
        for (int it=0; it<4; ++it){
            int i = tid + it*256;
            int r = i>>4, kq4 = (i&15)*4;
            float4 v = *(const float4*)(A + (size_t)(row0 + r)*Kr + k0 + kq4);
            if (ACT_SILU){ v.x=siluf(v.x); v.y=siluf(v.y); v.z=siluf(v.z); v.w=siluf(v.w); }
            *(uint2*)&As[r][kq4] = pack4bf(v.x, v.y, v.z, v.w);
        }
        #pragma unroll
        for (int it=0; it<4; ++it){
            int i = tid + it*256;
            int n = i>>3, oq8 = (i&7)*8;
            *(uint4*)&Bs[n][oq8] = *(const uint4*)(Wt + (size_t)(col0+n)*Kr + k0 + oq8);
        }
        __syncthreads();
        #pragma unroll
        for (int ks=0; ks<2; ++ks){
            bf16x8_t af[4], bfr[2];
            #pragma unroll
            for (int rf=0; rf<4; ++rf)
                af[rf] = *reinterpret_cast<const bf16x8_t*>(&As[rf*16+lq][ks*32+lg*8]);
            #pragma unroll
            for (int cb=0; cb<2; ++cb)
                bfr[cb] = *reinterpret_cast<const bf16x8_t*>(&Bs[w*32+cb*16+lq][ks*32+lg*8]);
            #pragma unroll
            for (int rf=0; rf<4; ++rf)
                #pragma unroll
                for (int cb=0; cb<2; ++cb)
                    acc[rf][cb] = __builtin_amdgcn_mfma_f32_16x16x32_bf16(af[rf], bfr[cb], acc[rf][cb], 0, 0, 0);
        }
    }
    #pragma unroll
    for (int cb=0; cb<2; ++cb){
        int gc = col0 + w*32 + cb*16 + lq;
        float bv = bias[gc];
        #pragma unroll
        for (int rf=0; rf<4; ++rf){
            #pragma unroll
            for (int r=0; r<4; ++r){
                int gr = row0 + rf*16 + lg*4 + r;
                float v = acc[rf][cb][r] + bv;
                size_t off = (size_t)gr*Nr + gc;
                if (res) v += res[off];
                C[off] = v;
            }
        }
    }
}

// ---------------- modulated LN + silu ----------------
__global__ __launch_bounds__(256) void lnmod_kernel(
    const float* __restrict__ in, const float* __restrict__ g, const float* __restrict__ bb,
    const float* __restrict__ eo, float* __restrict__ out)
{
    int row = blockIdx.x, tid = threadIdx.x;
    __shared__ float xsr[LATD];
    __shared__ float red[256];
    const float* rp = in + (size_t)row*LATD;
    float s = 0.f;
    for (int i=tid;i<LATD;i+=256){ float v = rp[i]; xsr[i]=v; s+=v; }
    red[tid]=s; __syncthreads();
    for (int k=128;k>0;k>>=1){ if (tid<k) red[tid]+=red[tid+k]; __syncthreads(); }
    float mean = red[0]*(1.0f/LATD);
    __syncthreads();
    float vs=0.f;
    for (int i=tid;i<LATD;i+=256){ float d=xsr[i]-mean; vs+=d*d; }
    red[tid]=vs; __syncthreads();
    for (int k=128;k>0;k>>=1){ if (tid<k) red[tid]+=red[tid+k]; __syncthreads(); }
    float rstd = rsqrtf(red[0]*(1.0f/LATD)+1e-5f);
    const float* ep = eo + (size_t)row*(2*LATD);
    float* op = out + (size_t)row*LATD;
    for (int i=tid;i<LATD;i+=256){
        float v = (xsr[i]-mean)*rstd*g[i] + bb[i];
        v = v*(1.0f + ep[i]) + ep[LATD+i];
        op[i] = siluf(v);
    }
}

extern "C" void kernel_launch(void* const* d_in, const int* in_sizes, int n_in,
                              void* d_out, int out_size, void* d_ws, size_t ws_size,
                              hipStream_t stream)
{
    (void)in_sizes; (void)n_in; (void)out_size; (void)ws_size;
    const float* x     = (const float*)d_in[0];
    const float* emb   = (const float*)d_in[1];
    const int*   smask = (const int*)d_in[2];
    const float* tcond = (const float*)d_in[5];
    const float* two   = (const float*)d_in[6];
    const float* ng    = (const float*)d_in[7];
    const float* nb    = (const float*)d_in[8];
    const float* memb  = (const float*)d_in[9];
    const float* m_wg  = (const float*)d_in[10];
    const float* m_w1  = (const float*)d_in[11];
    const float* m_b1  = (const float*)d_in[12];
    const float* m_w2  = (const float*)d_in[13];
    const float* m_b2  = (const float*)d_in[14];
    const float* m_pw  = (const float*)d_in[15];
    const float* m_pb  = (const float*)d_in[16];
    const float* kms   = (const float*)d_in[17];
    const float* sigma = (const float*)d_in[18];
    const float* kdat  = (const float*)d_in[19];
    const float* kds   = (const float*)d_in[20];
    const float* vdat  = (const float*)d_in[21];
    const float* krot  = (const float*)d_in[22];
    const float* krs   = (const float*)d_in[23];
    const float* vrot  = (const float*)d_in[24];
    const float* ntg   = (const float*)d_in[25];
    const float* ntb   = (const float*)d_in[26];
    const float* c_wg  = (const float*)d_in[27];
    const float* c_w1  = (const float*)d_in[28];
    const float* c_b1  = (const float*)d_in[29];
    const float* c_w2  = (const float*)d_in[30];
    const float* c_b2  = (const float*)d_in[31];
    const float* c_pw  = (const float*)d_in[32];
    const float* c_pb  = (const float*)d_in[33];
    const float* kts   = (const float*)d_in[34];
    const float* st_ew = (const float*)d_in[35];
    const float* st_eb = (const float*)d_in[36];
    const float* st_ng = (const float*)d_in[37];
    const float* st_nb = (const float*)d_in[38];
    const float* st_ow = (const float*)d_in[39];
    const float* st_ob = (const float*)d_in[40];

    float* ws = (float*)d_ws;
    float* xh   = ws;                    // 1310720
    float* qB   = xh  + 1310720;         // (B,T,H,64) token-major
    float* kmB  = qB  + 1310720;
    float* vmB  = kmB + 1310720;
    float* ctB  = vmB + 1310720;         // 197120
    float* ktB  = ctB + 197120;          // (B,M,H,64)
    float* vtB  = ktB + 197120;
    float* aout = vtB + 197120;          // 1310720
    float* eoB  = aout + 1310720;        // 2621440
    float* shB  = eoB + 2621440;         // 1310720

    // pre-transposed bf16 weights (persist whole launch)
    unsigned short* w1Tm = (unsigned short*)(shB + 1310720);
    unsigned short* w2Tm = w1Tm + EE*FFND*DD;
    unsigned short* w1Tt = w2Tm + EE*FFND*DD;
    unsigned short* w2Tt = w1Tt + EE*FFND*DD;
    unsigned short* stewT = w2Tt + EE*FFND*DD;
    unsigned short* stowT = stewT + 512*1280;
    unsigned short* mpwT  = stowT + 640*640;
    unsigned short* cpwT  = mpwT + 320*64;

    // aliases (stream-ordered, dead-at-use regions)
    float* yslotM = eoB;                         // dead after proj M (gemm1 writes later)
    float* yslotT = shB;                         // dead after proj T
    float* wAm   = aout;                         // routing scratch, dead after ffn
    float* wAt   = wAm + NTOK_M*2;
    int*   cntA  = (int*)(wAt + NTOK_T*2);
    int*   listM = cntA + 16;
    int*   listT = listM + EE*NTOK_M;
    unsigned short* KbfB  = (unsigned short*)xh;  // 1.8M u16, xh dead after ffn M
    unsigned short* VTbfB = (unsigned short*)shB; // 1.8M u16, shB dead after proj T; lnmod overwrites later
    float* maddB = ctB;                           // ctB dead after ffn T

    prep_weights_kernel<<<395, 256, 0, stream>>>(
        m_w1, w1Tm, m_w2, w2Tm, c_w1, w1Tt, c_w2, w2Tt,
        st_ew, stewT, st_ow, stowT, m_pw, mpwT, c_pw, cpwT);

    ln_kernel<<<BB*TT, 256, 0, stream>>>(x, ng, nb, memb, xh, TT);
    ln_kernel<<<BB*MM, 256, 0, stream>>>(two, ntg, ntb, nullptr, ctB, MM);
    zero_counts_kernel<<<1, 64, 0, stream>>>(cntA);
    route_kernel<<<(NTOK_M+255)/256, 256, 0, stream>>>(xh, m_wg, NTOK_M, cntA, listM, wAm);
    route_kernel<<<(NTOK_T+255)/256, 256, 0, stream>>>(ctB, c_wg, NTOK_T, cntA+8, listT, wAt);
    moe_ffn_kernel<<<MAXB_M, 256, 0, stream>>>(
        xh, w1Tm, m_b1, w2Tm, m_b2, cntA, listM, wAm, NTOK_M, yslotM);
    moe_ffn_kernel<<<MAXB_T, 256, 0, stream>>>(
        ctB, w1Tt, c_b1, w2Tt, c_b2, cntA+8, listT, wAt, NTOK_T, yslotT);
    moe_proj_mfma_kernel<192><<<(NTOK_M+63)/64, 256, 0, stream>>>(
        yslotM, mpwT, m_pb, NTOK_M, qB, kmB, vmB);
    moe_proj_mfma_kernel<128><<<(NTOK_T+63)/64, 256, 0, stream>>>(
        yslotT, cpwT, c_pb, NTOK_T, ktB, vtB, nullptr);
    // KV prep (fused bf16 K + V^T + mask row), then barrier-free attention -> aout
    {
        dim3 gp(BB*HH, NCH);
        kv_prep_kernel<<<gp, 256, 0, stream>>>(
            kmB, vmB, ktB, vtB, kdat, vdat, krot, vrot, smask, tcond,
            kms, kds, krs, kts, KbfB, VTbfB, maddB);
        attn_kernel<<<BB*HH*16, 256, 0, stream>>>(
            qB, KbfB, VTbfB, maddB, sigma, aout);
    }
    {
        dim3 g1(2048/64, 1280/128);
        gemm_mfma_kernel<true><<<g1, 256, 0, stream>>>(emb, stewT, st_eb, nullptr, eoB, 2048, 1280, 512);
    }
    lnmod_kernel<<<BB*TT, 256, 0, stream>>>(aout, st_ng, st_nb, eoB, shB);
    {
        dim3 g2(2048/64, 640/128);
        gemm_mfma_kernel<false><<<g2, 256, 0, stream>>>(shB, stowT, st_ob, x, (float*)d_out, 2048, 640, 640);
    }
}

// Round 10
// 166.047 us; speedup vs baseline: 1.2290x; 1.2290x over previous
//
#include <hip/hip_runtime.h>
#include <math.h>

#define BB 4
#define TT 512
#define MM 77
#define HH 10
#define DD 64
#define LATD 640
#define EE 8
#define FFND 256
#define NS 685     // 512 + 48 + 48 + 77
#define NCH 11     // ceil(685/64)
#define NROWS 20480

#define NTOK_M (BB*TT*HH)   // 20480
#define NTOK_T (BB*MM*HH)   // 3080
#define MAXB_M 647
#define MAXB_T 103

typedef float f32x4 __attribute__((ext_vector_type(4)));
typedef __bf16 bf16x8_t __attribute__((ext_vector_type(8)));
typedef unsigned short u16x8 __attribute__((ext_vector_type(8)));

__device__ __forceinline__ float geluf(float x){
    float u = 0.7978845608028654f*(x + 0.044715f*x*x*x);
    u = fminf(fmaxf(u, -15.f), 15.f);
    float e = __expf(2.f*u);
    return 0.5f*x*(1.f + (e-1.f)/(e+1.f));
}
__device__ __forceinline__ float siluf(float x){
    return x / (1.0f + __expf(-x));
}
__device__ __forceinline__ unsigned short f2bf(float f){
    unsigned int u = __float_as_uint(f);
    u += 0x7fff + ((u >> 16) & 1);
    return (unsigned short)(u >> 16);
}
__device__ __forceinline__ uint2 pack4bf(float a, float b, float c, float d){
    uint2 r;
    r.x = (unsigned)f2bf(a) | ((unsigned)f2bf(b)<<16);
    r.y = (unsigned)f2bf(c) | ((unsigned)f2bf(d)<<16);
    return r;
}

// ---------------- fused weight prep: all transposes+bf16 in one launch ----------------
__global__ __launch_bounds__(256) void prep_weights_kernel(
    const float* __restrict__ m_w1, unsigned short* __restrict__ w1Tm,
    const float* __restrict__ m_w2, unsigned short* __restrict__ w2Tm,
    const float* __restrict__ c_w1, unsigned short* __restrict__ w1Tt,
    const float* __restrict__ c_w2, unsigned short* __restrict__ w2Tt,
    const float* __restrict__ st_ew, unsigned short* __restrict__ stewT,
    const float* __restrict__ st_ow, unsigned short* __restrict__ stowT,
    const float* __restrict__ m_pw, unsigned short* __restrict__ mpwT,
    const float* __restrict__ c_pw, unsigned short* __restrict__ cpwT)
{
    __shared__ float t[64][65];
    const int bid = blockIdx.x, tid = threadIdx.x;
    const float* in; unsigned short* out; int R, C, z, rt, ct;
    if (bid < 32)      { int l=bid;     in=m_w1;  out=w1Tm;  R=64;  C=256;  z=l>>2; rt=0;    ct=l&3; }
    else if (bid < 64) { int l=bid-32;  in=m_w2;  out=w2Tm;  R=256; C=64;   z=l>>2; rt=l&3;  ct=0; }
    else if (bid < 96) { int l=bid-64;  in=c_w1;  out=w1Tt;  R=64;  C=256;  z=l>>2; rt=0;    ct=l&3; }
    else if (bid < 128){ int l=bid-96;  in=c_w2;  out=w2Tt;  R=256; C=64;   z=l>>2; rt=l&3;  ct=0; }
    else if (bid < 288){ int l=bid-128; in=st_ew; out=stewT; R=512; C=1280; z=0;    rt=l/20; ct=l%20; }
    else if (bid < 388){ int l=bid-288; in=st_ow; out=stowT; R=640; C=640;  z=0;    rt=l/10; ct=l%10; }
    else if (bid < 393){ int l=bid-388; in=m_pw;  out=mpwT;  R=64;  C=320;  z=0;    rt=0;    ct=l; }
    else               { int l=bid-393; in=c_pw;  out=cpwT;  R=64;  C=128;  z=0;    rt=0;    ct=l; }
    const size_t base = (size_t)z*R*C;
    const int r0 = rt*64, c0 = ct*64;
    #pragma unroll
    for (int p=0; p<16; ++p){
        int i = tid + p*256;
        int r = i>>6, c = i&63;
        t[r][c] = in[base + (size_t)(r0+r)*C + c0 + c];
    }
    __syncthreads();
    #pragma unroll
    for (int p=0; p<16; ++p){
        int i = tid + p*256;
        int c = i>>6, r = i&63;
        out[base + (size_t)(c0+c)*R + r0 + r] = f2bf(t[r][c]);
    }
}

// ---------------- LayerNorm (rows of 640), optional additive emb (T,640) ----------------
__global__ __launch_bounds__(256) void ln_kernel(
    const float* __restrict__ in, const float* __restrict__ g, const float* __restrict__ bb,
    const float* __restrict__ addv, float* __restrict__ out, int seqLen)
{
    int row = blockIdx.x, tid = threadIdx.x;
    __shared__ float xsr[LATD];
    __shared__ float red[256];
    const float* rp = in + (size_t)row*LATD;
    float s = 0.f;
    for (int i=tid;i<LATD;i+=256){ float v = rp[i]; xsr[i]=v; s+=v; }
    red[tid]=s; __syncthreads();
    for (int k=128;k>0;k>>=1){ if (tid<k) red[tid]+=red[tid+k]; __syncthreads(); }
    float mean = red[0]*(1.0f/LATD);
    __syncthreads();
    float vs=0.f;
    for (int i=tid;i<LATD;i+=256){ float d=xsr[i]-mean; vs+=d*d; }
    red[tid]=vs; __syncthreads();
    for (int k=128;k>0;k>>=1){ if (tid<k) red[tid]+=red[tid+k]; __syncthreads(); }
    float rstd = rsqrtf(red[0]*(1.0f/LATD)+1e-5f);
    int t = row % seqLen;
    const float* ap = addv ? (addv + (size_t)t*LATD) : nullptr;
    float* op = out + (size_t)row*LATD;
    for (int i=tid;i<LATD;i+=256){
        float v = (xsr[i]-mean)*rstd*g[i] + bb[i];
        if (ap) v += ap[i];
        op[i] = v;
    }
}

// ---------------- MoE routing (block-aggregated atomics) ----------------
__global__ void zero_counts_kernel(int* __restrict__ c){
    if (threadIdx.x < 16) c[threadIdx.x] = 0;
}

__global__ __launch_bounds__(256) void route_kernel(
    const float* __restrict__ xin, const float* __restrict__ wg, int nTok,
    int* __restrict__ counts, int* __restrict__ list, float* __restrict__ wA)
{
    __shared__ int bcnt[EE];
    __shared__ int bbase[EE];
    const int tid = threadIdx.x;
    const int t = blockIdx.x*256 + tid;
    if (tid < EE) bcnt[tid] = 0;
    __syncthreads();

    int e0 = 0, e1 = 0, p0 = 0, p1 = 0;
    bool act = (t < nTok);
    if (act){
        float lg[EE];
        #pragma unroll
        for (int e=0;e<EE;e++) lg[e]=0.f;
        const float4* xp = (const float4*)(xin + (size_t)t*DD);
        #pragma unroll 4
        for (int dq=0; dq<16; ++dq){
            float4 xv = xp[dq];
            const float* w0 = wg + (dq*4+0)*EE;
            const float* w1 = wg + (dq*4+1)*EE;
            const float* w2 = wg + (dq*4+2)*EE;
            const float* w3 = wg + (dq*4+3)*EE;
            #pragma unroll
            for (int e=0;e<EE;e++)
                lg[e] += xv.x*w0[e] + xv.y*w1[e] + xv.z*w2[e] + xv.w*w3[e];
        }
        float mx = lg[0];
        #pragma unroll
        for (int e=1;e<EE;e++) mx = fmaxf(mx, lg[e]);
        float sum = 0.f;
        #pragma unroll
        for (int e=0;e<EE;e++){ lg[e] = __expf(lg[e]-mx); sum += lg[e]; }
        float inv = 1.0f/sum;
        #pragma unroll
        for (int e=0;e<EE;e++) lg[e] *= inv;
        float v0=lg[0];
        #pragma unroll
        for (int e=1;e<EE;e++){ if (lg[e] > v0){ v0 = lg[e]; e0 = e; } }
        float v1=-1e30f; e1 = (e0==0) ? 1 : 0;
        #pragma unroll
        for (int e=0;e<EE;e++){ if (e==e0) continue; if (lg[e] > v1){ v1 = lg[e]; e1 = e; } }
        wA[t*2+0]=v0; wA[t*2+1]=v1;
        p0 = atomicAdd(&bcnt[e0], 1);
        p1 = atomicAdd(&bcnt[e1], 1);
    }
    __syncthreads();
    if (tid < EE){
        bbase[tid] = (bcnt[tid] > 0) ? atomicAdd(&counts[tid], bcnt[tid]) : 0;
    }
    __syncthreads();
    if (act){
        list[(size_t)e0*nTok + bbase[e0] + p0] = t*2;
        list[(size_t)e1*nTok + bbase[e1] + p1] = t*2+1;
    }
}

// ---------------- grouped expert FFN (MFMA): block = (expert, 64-token tile), 4 waves ----
__global__ __launch_bounds__(256) void moe_ffn_kernel(
    const float* __restrict__ xin,
    const unsigned short* __restrict__ w1T,
    const float* __restrict__ b1g,
    const unsigned short* __restrict__ w2T,
    const float* __restrict__ b2g,
    const int* __restrict__ counts, const int* __restrict__ list,
    const float* __restrict__ wA, int nTok,
    float* __restrict__ yslot)
{
    __shared__ __align__(16) unsigned short xs[64][72];
    __shared__ __align__(16) unsigned short w1s[64][72];
    __shared__ __align__(16) unsigned short w2s[64][72];
    __shared__ __align__(16) unsigned short hs[64][72];
    __shared__ int sCnt[EE];
    __shared__ int encs[64];
    __shared__ float wgts[64];
    const int tid = threadIdx.x;
    if (tid < EE) sCnt[tid] = counts[tid];
    __syncthreads();
    int e = -1, tile = 0;
    {
        int acc = 0, bid = blockIdx.x;
        #pragma unroll
        for (int i=0;i<EE;++i){
            int tc = (sCnt[i]+63)>>6;
            if (e < 0 && bid < acc + tc){ e = i; tile = bid - acc; }
            acc += tc;
        }
    }
    if (e < 0) return;
    const int cnt = sCnt[e];
    if (tid < 64){
        int idx = tile*64 + tid;
        int enc = (idx < cnt) ? list[(size_t)e*nTok + idx] : -1;
        encs[tid] = enc;
        wgts[tid] = (enc >= 0) ? wA[enc] : 0.f;
    }
    __syncthreads();
    for (int i=tid; i<64*16; i+=256){
        int r = i>>4, dq4 = (i&15)*4;
        int enc = encs[r];
        float4 xv = make_float4(0.f,0.f,0.f,0.f);
        if (enc >= 0) xv = *(const float4*)(xin + (size_t)(enc>>1)*DD + dq4);
        *(uint2*)&xs[r][dq4] = pack4bf(xv.x, xv.y, xv.z, xv.w);
    }

    const int w    = tid >> 6;
    const int lane = tid & 63;
    const int lq   = lane & 15;
    const int lg   = lane >> 4;

    const unsigned short* w1e = w1T + (size_t)e*FFND*DD;
    const unsigned short* w2e = w2T + (size_t)e*DD*FFND;

    f32x4 acc2[4] = {};

    for (int fc=0; fc<4; ++fc){
        __syncthreads();
        for (int i=tid; i<512; i+=256){
            int r = i>>3, jq = i&7;
            *(uint4*)&w1s[r][jq*8] = *(const uint4*)(w1e + (size_t)(fc*64+r)*DD + jq*8);
            *(uint4*)&w2s[r][jq*8] = *(const uint4*)(w2e + (size_t)r*FFND + fc*64 + jq*8);
        }
        __syncthreads();
        f32x4 acc1[4] = {};
        #pragma unroll
        for (int fb=0; fb<4; ++fb){
            #pragma unroll
            for (int ks=0; ks<2; ++ks){
                bf16x8_t xf = *reinterpret_cast<const bf16x8_t*>(&xs[w*16+lq][ks*32+lg*8]);
                bf16x8_t wf = *reinterpret_cast<const bf16x8_t*>(&w1s[fb*16+lq][ks*32+lg*8]);
                acc1[fb] = __builtin_amdgcn_mfma_f32_16x16x32_bf16(xf, wf, acc1[fb], 0, 0, 0);
            }
        }
        #pragma unroll
        for (int fb=0; fb<4; ++fb){
            float b1v = b1g[e*FFND + fc*64 + fb*16 + lq];
            #pragma unroll
            for (int r=0; r<4; ++r)
                hs[w*16 + lg*4 + r][fb*16 + lq] = f2bf(geluf(acc1[fb][r] + b1v));
        }
        #pragma unroll
        for (int db=0; db<4; ++db){
            #pragma unroll
            for (int ks=0; ks<2; ++ks){
                bf16x8_t hf  = *reinterpret_cast<const bf16x8_t*>(&hs[w*16+lq][ks*32+lg*8]);
                bf16x8_t w2f = *reinterpret_cast<const bf16x8_t*>(&w2s[db*16+lq][ks*32+lg*8]);
                acc2[db] = __builtin_amdgcn_mfma_f32_16x16x32_bf16(hf, w2f, acc2[db], 0, 0, 0);
            }
        }
    }
    #pragma unroll
    for (int r=0; r<4; ++r){
        int tok = w*16 + lg*4 + r;
        int enc = encs[tok];
        if (enc >= 0){
            float gw = wgts[tok];
            #pragma unroll
            for (int db=0; db<4; ++db){
                int d = db*16 + lq;
                yslot[(size_t)enc*DD + d] = gw*(acc2[db][r] + b2g[e*DD + d]);
            }
        }
    }
}

// ---------------- combine slots + gelu + MFMA projection (token-major output) ----------------
template<int NPROJ>
__global__ __launch_bounds__(256) void moe_proj_mfma_kernel(
    const float* __restrict__ yslot, const unsigned short* __restrict__ pwT,
    const float* __restrict__ pbg, int nTok,
    float* __restrict__ out0, float* __restrict__ out1, float* __restrict__ out2)
{
    __shared__ __align__(16) unsigned short gs[64][72];
    const int tid = threadIdx.x;
    const int base = blockIdx.x*64;
    for (int i=tid; i<64*16; i+=256){
        int r = i>>4, dq4 = (i&15)*4;
        int tok = base + r;
        float4 g4 = make_float4(0.f,0.f,0.f,0.f);
        if (tok < nTok){
            float4 a = *(const float4*)(yslot + (size_t)tok*128 + dq4);
            float4 b = *(const float4*)(yslot + (size_t)tok*128 + 64 + dq4);
            g4.x = geluf(a.x+b.x); g4.y = geluf(a.y+b.y);
            g4.z = geluf(a.z+b.z); g4.w = geluf(a.w+b.w);
        }
        *(uint2*)&gs[r][dq4] = pack4bf(g4.x, g4.y, g4.z, g4.w);
    }
    __syncthreads();

    const int w    = tid >> 6;
    const int lane = tid & 63;
    const int lq   = lane & 15;
    const int lg   = lane >> 4;
    constexpr int NC = NPROJ/64;
    const int colbase = w*16*NC;

    bf16x8_t wf[NC][2];
    #pragma unroll
    for (int cb=0; cb<NC; ++cb)
        #pragma unroll
        for (int ks=0; ks<2; ++ks)
            wf[cb][ks] = *reinterpret_cast<const bf16x8_t*>(
                pwT + (size_t)(colbase + cb*16 + lq)*DD + ks*32 + lg*8);

    f32x4 acc[4][NC] = {};
    #pragma unroll
    for (int m=0; m<4; ++m){
        #pragma unroll
        for (int ks=0; ks<2; ++ks){
            bf16x8_t af = *reinterpret_cast<const bf16x8_t*>(&gs[m*16+lq][ks*32+lg*8]);
            #pragma unroll
            for (int cb=0; cb<NC; ++cb)
                acc[m][cb] = __builtin_amdgcn_mfma_f32_16x16x32_bf16(af, wf[cb][ks], acc[m][cb], 0, 0, 0);
        }
    }
    #pragma unroll
    for (int m=0; m<4; ++m){
        #pragma unroll
        for (int r=0; r<4; ++r){
            int tok = base + m*16 + lg*4 + r;
            if (tok >= nTok) continue;
            #pragma unroll
            for (int cb=0; cb<NC; ++cb){
                int j = colbase + cb*16 + lq;
                float v = acc[m][cb][r] + pbg[j];
                int bufi = j >> 6, jd = j & 63;
                float* dst = (bufi==0) ? out0 : (bufi==1) ? out1 : out2;
                dst[(size_t)tok*DD + jd] = v;
            }
        }
    }
}

// ---------------- MFMA flash attention (split-s): block = (b,h,64-row t-tile), 4 waves ----
// Q/K/V motion buffers are token-major (B,T,H,64); text buffers (B,M,H,64).
__global__ __launch_bounds__(256) void attn_kernel(
    const float* __restrict__ qb,
    const float* __restrict__ kmb,
    const float* __restrict__ vmb,
    const float* __restrict__ ktb,
    const float* __restrict__ vtb,
    const float* __restrict__ kd,   // (NDS,48,H,64) -> [0]
    const float* __restrict__ vd,
    const float* __restrict__ kr,   // (48,H,64)
    const float* __restrict__ vr,
    const int*   __restrict__ smask, // (B,T)
    const float* __restrict__ tcond, // (B,1)
    const float* __restrict__ kms_p, const float* __restrict__ kds_p,
    const float* __restrict__ krs_p, const float* __restrict__ kts_p,
    const float* __restrict__ sigma_p,
    float* __restrict__ po,          // (2, NROWS, 64)
    float* __restrict__ pm,          // (2, NROWS)
    float* __restrict__ pl)          // (2, NROWS)
{
    __shared__ __align__(16) unsigned short Ks[64][72];
    __shared__ __align__(16) unsigned short Vt[64][72];
    __shared__ __align__(16) unsigned short Pl[4][16][72];
    __shared__ float madd[64];

    const int tid  = threadIdx.x;
    const int w    = tid >> 6;
    const int lane = tid & 63;
    const int lq   = lane & 15;
    const int lg   = lane >> 4;

    const int bid   = blockIdx.x;
    const int split = blockIdx.y;
    const int ch_lo = split ? 6 : 0;
    const int ch_hi = split ? NCH : 6;
    const int ttile = bid & 7;
    const int bh    = bid >> 3;
    const int b = bh / HH, h = bh % HH;
    const int t0 = ttile * 64;

    const float sc = 0.125f;
    const float kms = kms_p[0]*sc, kds = kds_p[0]*sc, krs = krs_p[0]*sc, kts = kts_p[0]*sc;
    const float sg = sigma_p[0];
    const float inv2s = 1.0f/(2.0f*sg*sg);
    const bool text_on = tcond[b] > 0.f;

    bf16x8_t qf[2];
    {
        const float* qrow = qb + ((size_t)(b*TT + t0 + w*16 + lq)*HH + h)*DD;
        #pragma unroll
        for (int ks=0; ks<2; ++ks){
            float4 v0 = *(const float4*)(qrow + ks*32 + lg*8);
            float4 v1 = *(const float4*)(qrow + ks*32 + lg*8 + 4);
            u16x8 qt;
            qt[0]=f2bf(v0.x); qt[1]=f2bf(v0.y); qt[2]=f2bf(v0.z); qt[3]=f2bf(v0.w);
            qt[4]=f2bf(v1.x); qt[5]=f2bf(v1.y); qt[6]=f2bf(v1.z); qt[7]=f2bf(v1.w);
            qf[ks] = __builtin_bit_cast(bf16x8_t, qt);
        }
    }

    float m_r = -1e30f, l_r = 0.f;
    f32x4 oacc[4] = {};

    const int tgq = t0 + w*16 + lq;

    for (int ch=ch_lo; ch<ch_hi; ++ch){
        __syncthreads();
        for (int i=tid; i<64*16; i+=256){
            int r = i>>4, dq4 = (i&15)*4;
            int s = ch*64 + r;
            float4 kv = make_float4(0,0,0,0), vv = make_float4(0,0,0,0);
            if (s < TT){
                size_t o = ((size_t)(b*TT + s)*HH + h)*DD + dq4;
                kv = *(const float4*)(&kmb[o]);
                kv.x*=kms; kv.y*=kms; kv.z*=kms; kv.w*=kms;
                vv = *(const float4*)(&vmb[o]);
            } else if (s < TT+48){
                kv = *(const float4*)(&kd[((size_t)(s-TT)*HH + h)*DD + dq4]);
                kv.x*=kds; kv.y*=kds; kv.z*=kds; kv.w*=kds;
                vv = *(const float4*)(&vd[((size_t)(s-TT)*HH + h)*DD + dq4]);
            } else if (s < TT+96){
                kv = *(const float4*)(&kr[((size_t)(s-TT-48)*HH + h)*DD + dq4]);
                kv.x*=krs; kv.y*=krs; kv.z*=krs; kv.w*=krs;
                vv = *(const float4*)(&vr[((size_t)(s-TT-48)*HH + h)*DD + dq4]);
            } else if (s < NS){
                size_t o = ((size_t)(b*MM + (s-TT-96))*HH + h)*DD + dq4;
                kv = *(const float4*)(&ktb[o]);
                kv.x*=kts; kv.y*=kts; kv.z*=kts; kv.w*=kts;
                vv = *(const float4*)(&vtb[o]);
            }
            *(uint2*)&Ks[r][dq4] = pack4bf(kv.x, kv.y, kv.z, kv.w);
            int swcol = r ^ (((i&15)&7)<<3);
            Vt[dq4+0][swcol] = f2bf(vv.x);
            Vt[dq4+1][swcol] = f2bf(vv.y);
            Vt[dq4+2][swcol] = f2bf(vv.z);
            Vt[dq4+3][swcol] = f2bf(vv.w);
        }
        if (tid < 64){
            int s = ch*64 + tid;
            float a;
            if (s < TT)            a = (smask[b*TT + s] == 0) ? -1e9f : 0.f;
            else if (s < TT+96)    a = 0.f;
            else if (s < NS)       a = text_on ? 0.f : -1e9f;
            else                   a = -1e30f;
            madd[tid] = a;
        }
        __syncthreads();

        f32x4 sacc[4] = {};
        #pragma unroll
        for (int sl=0; sl<4; ++sl){
            #pragma unroll
            for (int ks=0; ks<2; ++ks){
                bf16x8_t kf = *reinterpret_cast<const bf16x8_t*>(&Ks[sl*16 + lq][ks*32 + lg*8]);
                sacc[sl] = __builtin_amdgcn_mfma_f32_16x16x32_bf16(kf, qf[ks], sacc[sl], 0, 0, 0);
            }
        }
        float sv[4][4];
        float pmax = -1e30f;
        #pragma unroll
        for (int sl=0; sl<4; ++sl){
            #pragma unroll
            for (int r=0; r<4; ++r){
                int s_loc = sl*16 + lg*4 + r;
                float a = madd[s_loc];
                if (ch < 8){ float dt = (float)(tgq - (ch*64 + s_loc)); a -= dt*dt*inv2s; }
                float v = sacc[sl][r] + a;
                sv[sl][r] = v;
                pmax = fmaxf(pmax, v);
            }
        }
        pmax = fmaxf(pmax, __shfl_xor(pmax, 16));
        pmax = fmaxf(pmax, __shfl_xor(pmax, 32));
        float mn  = fmaxf(m_r, pmax);
        float scl = __expf(m_r - mn);
        m_r = mn;
        float psum = 0.f;
        #pragma unroll
        for (int sl=0; sl<4; ++sl){
            #pragma unroll
            for (int r=0; r<4; ++r){
                float p = __expf(sv[sl][r] - mn);
                sv[sl][r] = p;
                psum += p;
            }
        }
        psum += __shfl_xor(psum, 16);
        psum += __shfl_xor(psum, 32);
        l_r = l_r*scl + psum;
        #pragma unroll
        for (int sl=0; sl<4; ++sl)
            *(uint2*)&Pl[w][lq][sl*16 + lg*4] = pack4bf(sv[sl][0], sv[sl][1], sv[sl][2], sv[sl][3]);

        #pragma unroll
        for (int r=0; r<4; ++r){
            float so = __shfl(scl, lg*4 + r);
            #pragma unroll
            for (int ds_=0; ds_<4; ++ds_) oacc[ds_][r] *= so;
        }
        #pragma unroll
        for (int ds_=0; ds_<4; ++ds_){
            int dcol = ds_*16 + lq;
            int swz = (((dcol>>2)&7)<<3);
            #pragma unroll
            for (int ks=0; ks<2; ++ks){
                bf16x8_t pf = *reinterpret_cast<const bf16x8_t*>(&Pl[w][lq][ks*32 + lg*8]);
                bf16x8_t vf = *reinterpret_cast<const bf16x8_t*>(&Vt[dcol][(ks*32 + lg*8) ^ swz]);
                oacc[ds_] = __builtin_amdgcn_mfma_f32_16x16x32_bf16(pf, vf, oacc[ds_], 0, 0, 0);
            }
        }
    }
    #pragma unroll
    for (int r=0; r<4; ++r){
        int t = t0 + w*16 + lg*4 + r;
        size_t off = (size_t)split*NROWS + (size_t)bh*TT + t;
        #pragma unroll
        for (int ds_=0; ds_<4; ++ds_)
            po[off*64 + ds_*16 + lq] = oacc[ds_][r];
    }
    if (lg == 0){
        size_t off = (size_t)split*NROWS + (size_t)bh*TT + (t0 + w*16 + lq);
        pm[off] = m_r;
        pl[off] = l_r;
    }
}

// ---------------- merge the 2 s-splits ----------------
__global__ __launch_bounds__(256) void attn_combine_kernel(
    const float* __restrict__ po, const float* __restrict__ pm, const float* __restrict__ pl,
    float* __restrict__ outb)
{
    int tid = threadIdx.x, bid = blockIdx.x;
    int ttile = bid & 15, bh = bid >> 4;
    int b = bh / HH, h = bh % HH;
    int tp = tid >> 4, sq = tid & 15;
    #pragma unroll
    for (int i=0;i<2;++i){
        int t = ttile*32 + tp*2 + i;
        size_t rowid = (size_t)bh*TT + t;
        float m0 = pm[rowid], m1 = pm[NROWS + rowid];
        float l0 = pl[rowid], l1 = pl[NROWS + rowid];
        float m = fmaxf(m0, m1);
        float s0 = __expf(m0 - m), s1 = __expf(m1 - m);
        float inv = 1.0f / (l0*s0 + l1*s1);
        float4 o0 = *(const float4*)(po + rowid*64 + sq*4);
        float4 o1 = *(const float4*)(po + ((size_t)NROWS + rowid)*64 + sq*4);
        float4 o;
        o.x = (o0.x*s0 + o1.x*s1)*inv;
        o.y = (o0.y*s0 + o1.y*s1)*inv;
        o.z = (o0.z*s0 + o1.z*s1)*inv;
        o.w = (o0.w*s0 + o1.w*s1)*inv;
        *(float4*)(&outb[((size_t)(b*TT + t))*LATD + h*64 + sq*4]) = o;
    }
}

// ---------------- bf16 MFMA GEMM: C = act(A) @ W + bias (+res). Wt pre-transposed bf16 [N][K]
template<bool ACT_SILU>
__global__ __launch_bounds__(256) void gemm_mfma_kernel(
    const float* __restrict__ A, const unsigned short* __restrict__ Wt,
    const float* __restrict__ bias, const float* __restrict__ res,
    float* __restrict__ C, int Mr, int Nr, int Kr)
{
    __shared__ __align__(16) unsigned short As[32][40];
    __shared__ __align__(16) unsigned short Bs[64][40];
    int tid = threadIdx.x;
    int row0 = blockIdx.x*32, col0 = blockIdx.y*64;
    int wave = tid >> 6, lane = tid & 63;
    int lr = lane & 15, lk = lane >> 4;

    f32x4 acc[2] = {};

    for (int k0 = 0; k0 < Kr; k0 += 32){
        __syncthreads();
        {
            int r = tid >> 3, kq = tid & 7;
            float4 v = *(const float4*)(A + (size_t)(row0 + r)*Kr + k0 + kq*4);
            if (ACT_SILU){ v.x=siluf(v.x); v.y=siluf(v.y); v.z=siluf(v.z); v.w=siluf(v.w); }
            *(uint2*)&As[r][kq*4] = pack4bf(v.x, v.y, v.z, v.w);
        }
        {
            int n = tid >> 2, oq = tid & 3;
            *(uint4*)&Bs[n][oq*8] = *(const uint4*)(Wt + (size_t)(col0+n)*Kr + k0 + oq*8);
        }
        __syncthreads();
        bf16x8_t a0 = *reinterpret_cast<const bf16x8_t*>(&As[lr][lk*8]);
        bf16x8_t a1 = *reinterpret_cast<const bf16x8_t*>(&As[16 + lr][lk*8]);
        bf16x8_t bfr = *reinterpret_cast<const bf16x8_t*>(&Bs[wave*16 + lr][lk*8]);
        acc[0] = __builtin_amdgcn_mfma_f32_16x16x32_bf16(a0, bfr, acc[0], 0, 0, 0);
        acc[1] = __builtin_amdgcn_mfma_f32_16x16x32_bf16(a1, bfr, acc[1], 0, 0, 0);
    }
    int gc = col0 + wave*16 + lr;
    float bv = bias[gc];
    #pragma unroll
    for (int m=0;m<2;++m){
        #pragma unroll
        for (int r=0;r<4;++r){
            int gr = row0 + m*16 + lk*4 + r;
            float v = acc[m][r] + bv;
            size_t off = (size_t)gr*Nr + gc;
            if (res) v += res[off];
            C[off] = v;
        }
    }
}

// ---------------- modulated LN + silu ----------------
__global__ __launch_bounds__(256) void lnmod_kernel(
    const float* __restrict__ in, const float* __restrict__ g, const float* __restrict__ bb,
    const float* __restrict__ eo, float* __restrict__ out)
{
    int row = blockIdx.x, tid = threadIdx.x;
    __shared__ float xsr[LATD];
    __shared__ float red[256];
    const float* rp = in + (size_t)row*LATD;
    float s = 0.f;
    for (int i=tid;i<LATD;i+=256){ float v = rp[i]; xsr[i]=v; s+=v; }
    red[tid]=s; __syncthreads();
    for (int k=128;k>0;k>>=1){ if (tid<k) red[tid]+=red[tid+k]; __syncthreads(); }
    float mean = red[0]*(1.0f/LATD);
    __syncthreads();
    float vs=0.f;
    for (int i=tid;i<LATD;i+=256){ float d=xsr[i]-mean; vs+=d*d; }
    red[tid]=vs; __syncthreads();
    for (int k=128;k>0;k>>=1){ if (tid<k) red[tid]+=red[tid+k]; __syncthreads(); }
    float rstd = rsqrtf(red[0]*(1.0f/LATD)+1e-5f);
    const float* ep = eo + (size_t)row*(2*LATD);
    float* op = out + (size_t)row*LATD;
    for (int i=tid;i<LATD;i+=256){
        float v = (xsr[i]-mean)*rstd*g[i] + bb[i];
        v = v*(1.0f + ep[i]) + ep[LATD+i];
        op[i] = siluf(v);
    }
}

extern "C" void kernel_launch(void* const* d_in, const int* in_sizes, int n_in,
                              void* d_out, int out_size, void* d_ws, size_t ws_size,
                              hipStream_t stream)
{
    (void)in_sizes; (void)n_in; (void)out_size; (void)ws_size;
    const float* x     = (const float*)d_in[0];
    const float* emb   = (const float*)d_in[1];
    const int*   smask = (const int*)d_in[2];
    const float* tcond = (const float*)d_in[5];
    const float* two   = (const float*)d_in[6];
    const float* ng    = (const float*)d_in[7];
    const float* nb    = (const float*)d_in[8];
    const float* memb  = (const float*)d_in[9];
    const float* m_wg  = (const float*)d_in[10];
    const float* m_w1  = (const float*)d_in[11];
    const float* m_b1  = (const float*)d_in[12];
    const float* m_w2  = (const float*)d_in[13];
    const float* m_b2  = (const float*)d_in[14];
    const float* m_pw  = (const float*)d_in[15];
    const float* m_pb  = (const float*)d_in[16];
    const float* kms   = (const float*)d_in[17];
    const float* sigma = (const float*)d_in[18];
    const float* kdat  = (const float*)d_in[19];
    const float* kds   = (const float*)d_in[20];
    const float* vdat  = (const float*)d_in[21];
    const float* krot  = (const float*)d_in[22];
    const float* krs   = (const float*)d_in[23];
    const float* vrot  = (const float*)d_in[24];
    const float* ntg   = (const float*)d_in[25];
    const float* ntb   = (const float*)d_in[26];
    const float* c_wg  = (const float*)d_in[27];
    const float* c_w1  = (const float*)d_in[28];
    const float* c_b1  = (const float*)d_in[29];
    const float* c_w2  = (const float*)d_in[30];
    const float* c_b2  = (const float*)d_in[31];
    const float* c_pw  = (const float*)d_in[32];
    const float* c_pb  = (const float*)d_in[33];
    const float* kts   = (const float*)d_in[34];
    const float* st_ew = (const float*)d_in[35];
    const float* st_eb = (const float*)d_in[36];
    const float* st_ng = (const float*)d_in[37];
    const float* st_nb = (const float*)d_in[38];
    const float* st_ow = (const float*)d_in[39];
    const float* st_ob = (const float*)d_in[40];

    float* ws = (float*)d_ws;
    float* xh   = ws;                    // 1310720
    float* qB   = xh  + 1310720;         // (B,T,H,64) token-major
    float* kmB  = qB  + 1310720;
    float* vmB  = kmB + 1310720;
    float* ctB  = vmB + 1310720;         // 197120
    float* ktB  = ctB + 197120;          // (B,M,H,64)
    float* vtB  = ktB + 197120;
    float* aout = vtB + 197120;          // 1310720
    float* eoB  = aout + 1310720;        // 2621440
    float* shB  = eoB + 2621440;         // 1310720

    // pre-transposed bf16 weights (persist whole launch)
    unsigned short* w1Tm = (unsigned short*)(shB + 1310720);
    unsigned short* w2Tm = w1Tm + EE*FFND*DD;
    unsigned short* w1Tt = w2Tm + EE*FFND*DD;
    unsigned short* w2Tt = w1Tt + EE*FFND*DD;
    unsigned short* stewT = w2Tt + EE*FFND*DD;
    unsigned short* stowT = stewT + 512*1280;
    unsigned short* mpwT  = stowT + 640*640;
    unsigned short* cpwT  = mpwT + 320*64;

    float* yslotM = eoB;
    float* yslotT = shB;
    float* wAm   = aout;
    float* wAt   = wAm + NTOK_M*2;
    int*   cntA  = (int*)(wAt + NTOK_T*2);
    int*   listM = cntA + 16;
    int*   listT = listM + EE*NTOK_M;
    float* poB = eoB;
    float* pmB = ctB;
    float* plB = ctB + 2*NROWS;

    prep_weights_kernel<<<395, 256, 0, stream>>>(
        m_w1, w1Tm, m_w2, w2Tm, c_w1, w1Tt, c_w2, w2Tt,
        st_ew, stewT, st_ow, stowT, m_pw, mpwT, c_pw, cpwT);

    ln_kernel<<<BB*TT, 256, 0, stream>>>(x, ng, nb, memb, xh, TT);
    ln_kernel<<<BB*MM, 256, 0, stream>>>(two, ntg, ntb, nullptr, ctB, MM);
    zero_counts_kernel<<<1, 64, 0, stream>>>(cntA);
    route_kernel<<<(NTOK_M+255)/256, 256, 0, stream>>>(xh, m_wg, NTOK_M, cntA, listM, wAm);
    route_kernel<<<(NTOK_T+255)/256, 256, 0, stream>>>(ctB, c_wg, NTOK_T, cntA+8, listT, wAt);
    moe_ffn_kernel<<<MAXB_M, 256, 0, stream>>>(
        xh, w1Tm, m_b1, w2Tm, m_b2, cntA, listM, wAm, NTOK_M, yslotM);
    moe_ffn_kernel<<<MAXB_T, 256, 0, stream>>>(
        ctB, w1Tt, c_b1, w2Tt, c_b2, cntA+8, listT, wAt, NTOK_T, yslotT);
    moe_proj_mfma_kernel<192><<<(NTOK_M+63)/64, 256, 0, stream>>>(
        yslotM, mpwT, m_pb, NTOK_M, qB, kmB, vmB);
    moe_proj_mfma_kernel<128><<<(NTOK_T+63)/64, 256, 0, stream>>>(
        yslotT, cpwT, c_pb, NTOK_T, ktB, vtB, nullptr);
    {
        dim3 ga(BB*HH*8, 2);
        attn_kernel<<<ga, 256, 0, stream>>>(
            qB, kmB, vmB, ktB, vtB, kdat, vdat, krot, vrot, smask, tcond,
            kms, kds, krs, kts, sigma, poB, pmB, plB);
        attn_combine_kernel<<<BB*HH*16, 256, 0, stream>>>(poB, pmB, plB, aout);
    }
    {
        dim3 g1(2048/32, 1280/64);
        gemm_mfma_kernel<true><<<g1, 256, 0, stream>>>(emb, stewT, st_eb, nullptr, eoB, 2048, 1280, 512);
    }
    lnmod_kernel<<<BB*TT, 256, 0, stream>>>(aout, st_ng, st_nb, eoB, shB);
    {
        dim3 g2(2048/32, 640/64);
        gemm_mfma_kernel<false><<<g2, 256, 0, stream>>>(shB, stowT, st_ob, x, (float*)d_out, 2048, 640, 640);
    }
}

// Round 11
// 151.538 us; speedup vs baseline: 1.3466x; 1.0957x over previous
//
#include <hip/hip_runtime.h>
#include <math.h>

#define BB 4
#define TT 512
#define MM 77
#define HH 10
#define DD 64
#define LATD 640
#define EE 8
#define FFND 256
#define NS 685     // 512 + 48 + 48 + 77
#define NCH 11     // ceil(685/64)
#define NROWS 20480

#define NTOK_M (BB*TT*HH)   // 20480
#define NTOK_T (BB*MM*HH)   // 3080
#define MAXB_M 647
#define MAXB_T 103

typedef float f32x4 __attribute__((ext_vector_type(4)));
typedef __bf16 bf16x8_t __attribute__((ext_vector_type(8)));
typedef unsigned short u16x8 __attribute__((ext_vector_type(8)));

__device__ __forceinline__ float geluf(float x){
    float u = 0.7978845608028654f*(x + 0.044715f*x*x*x);
    u = fminf(fmaxf(u, -15.f), 15.f);
    float e = __expf(2.f*u);
    return 0.5f*x*(1.f + (e-1.f)/(e+1.f));
}
__device__ __forceinline__ float siluf(float x){
    return x / (1.0f + __expf(-x));
}
__device__ __forceinline__ unsigned short f2bf(float f){
    unsigned int u = __float_as_uint(f);
    u += 0x7fff + ((u >> 16) & 1);
    return (unsigned short)(u >> 16);
}
__device__ __forceinline__ uint2 pack4bf(float a, float b, float c, float d){
    uint2 r;
    r.x = (unsigned)f2bf(a) | ((unsigned)f2bf(b)<<16);
    r.y = (unsigned)f2bf(c) | ((unsigned)f2bf(d)<<16);
    return r;
}

// ---------------- fused prep: weight transposes+bf16, silu(emb)->bf16, zero counts -------
__global__ __launch_bounds__(256) void prep_weights_kernel(
    const float* __restrict__ m_w1, unsigned short* __restrict__ w1Tm,
    const float* __restrict__ m_w2, unsigned short* __restrict__ w2Tm,
    const float* __restrict__ c_w1, unsigned short* __restrict__ w1Tt,
    const float* __restrict__ c_w2, unsigned short* __restrict__ w2Tt,
    const float* __restrict__ st_ew, unsigned short* __restrict__ stewT,
    const float* __restrict__ st_ow, unsigned short* __restrict__ stowT,
    const float* __restrict__ m_pw, unsigned short* __restrict__ mpwT,
    const float* __restrict__ c_pw, unsigned short* __restrict__ cpwT,
    const float* __restrict__ emb, unsigned short* __restrict__ embBf,
    int* __restrict__ cnt)
{
    __shared__ float t[64][65];
    const int bid = blockIdx.x, tid = threadIdx.x;
    if (bid >= 395){
        // silu(emb) -> bf16, 256 blocks x 4096 elems (emb: 2048x512 = 1048576)
        int l = bid - 395;
        if (l == 0 && tid < 16) cnt[tid] = 0;
        size_t base = (size_t)l*4096;
        #pragma unroll
        for (int p=0; p<4; ++p){
            size_t i = base + (size_t)p*1024 + tid*4;
            float4 v = *(const float4*)(emb + i);
            *(uint2*)(embBf + i) = pack4bf(siluf(v.x), siluf(v.y), siluf(v.z), siluf(v.w));
        }
        return;
    }
    const float* in; unsigned short* out; int R, C, z, rt, ct;
    if (bid < 32)      { int l=bid;     in=m_w1;  out=w1Tm;  R=64;  C=256;  z=l>>2; rt=0;    ct=l&3; }
    else if (bid < 64) { int l=bid-32;  in=m_w2;  out=w2Tm;  R=256; C=64;   z=l>>2; rt=l&3;  ct=0; }
    else if (bid < 96) { int l=bid-64;  in=c_w1;  out=w1Tt;  R=64;  C=256;  z=l>>2; rt=0;    ct=l&3; }
    else if (bid < 128){ int l=bid-96;  in=c_w2;  out=w2Tt;  R=256; C=64;   z=l>>2; rt=l&3;  ct=0; }
    else if (bid < 288){ int l=bid-128; in=st_ew; out=stewT; R=512; C=1280; z=0;    rt=l/20; ct=l%20; }
    else if (bid < 388){ int l=bid-288; in=st_ow; out=stowT; R=640; C=640;  z=0;    rt=l/10; ct=l%10; }
    else if (bid < 393){ int l=bid-388; in=m_pw;  out=mpwT;  R=64;  C=320;  z=0;    rt=0;    ct=l; }
    else               { int l=bid-393; in=c_pw;  out=cpwT;  R=64;  C=128;  z=0;    rt=0;    ct=l; }
    const size_t base = (size_t)z*R*C;
    const int r0 = rt*64, c0 = ct*64;
    #pragma unroll
    for (int p=0; p<16; ++p){
        int i = tid + p*256;
        int r = i>>6, c = i&63;
        t[r][c] = in[base + (size_t)(r0+r)*C + c0 + c];
    }
    __syncthreads();
    #pragma unroll
    for (int p=0; p<16; ++p){
        int i = tid + p*256;
        int c = i>>6, r = i&63;
        out[base + (size_t)(c0+c)*R + r0 + r] = f2bf(t[r][c]);
    }
}

// ---------------- LayerNorm (motion + text fused in one launch) ----------------
__global__ __launch_bounds__(256) void ln_kernel(
    const float* __restrict__ inM, const float* __restrict__ gM, const float* __restrict__ bM,
    const float* __restrict__ addv, float* __restrict__ outM,
    const float* __restrict__ inT, const float* __restrict__ gT, const float* __restrict__ bT,
    float* __restrict__ outT)
{
    int bid = blockIdx.x, tid = threadIdx.x;
    const float* in; const float* g; const float* bb; const float* ap; float* out;
    int row;
    if (bid < BB*TT){
        row = bid; in = inM; g = gM; bb = bM; out = outM;
        ap = addv + (size_t)(row % TT)*LATD;
    } else {
        row = bid - BB*TT; in = inT; g = gT; bb = bT; out = outT;
        ap = nullptr;
    }
    __shared__ float xsr[LATD];
    __shared__ float red[256];
    const float* rp = in + (size_t)row*LATD;
    float s = 0.f;
    for (int i=tid;i<LATD;i+=256){ float v = rp[i]; xsr[i]=v; s+=v; }
    red[tid]=s; __syncthreads();
    for (int k=128;k>0;k>>=1){ if (tid<k) red[tid]+=red[tid+k]; __syncthreads(); }
    float mean = red[0]*(1.0f/LATD);
    __syncthreads();
    float vs=0.f;
    for (int i=tid;i<LATD;i+=256){ float d=xsr[i]-mean; vs+=d*d; }
    red[tid]=vs; __syncthreads();
    for (int k=128;k>0;k>>=1){ if (tid<k) red[tid]+=red[tid+k]; __syncthreads(); }
    float rstd = rsqrtf(red[0]*(1.0f/LATD)+1e-5f);
    float* op = out + (size_t)row*LATD;
    for (int i=tid;i<LATD;i+=256){
        float v = (xsr[i]-mean)*rstd*g[i] + bb[i];
        if (ap) v += ap[i];
        op[i] = v;
    }
}

// ---------------- MoE routing (block-aggregated atomics) ----------------
__global__ __launch_bounds__(256) void route_kernel(
    const float* __restrict__ xin, const float* __restrict__ wg, int nTok,
    int* __restrict__ counts, int* __restrict__ list, float* __restrict__ wA)
{
    __shared__ int bcnt[EE];
    __shared__ int bbase[EE];
    const int tid = threadIdx.x;
    const int t = blockIdx.x*256 + tid;
    if (tid < EE) bcnt[tid] = 0;
    __syncthreads();

    int e0 = 0, e1 = 0, p0 = 0, p1 = 0;
    bool act = (t < nTok);
    if (act){
        float lg[EE];
        #pragma unroll
        for (int e=0;e<EE;e++) lg[e]=0.f;
        const float4* xp = (const float4*)(xin + (size_t)t*DD);
        #pragma unroll 4
        for (int dq=0; dq<16; ++dq){
            float4 xv = xp[dq];
            const float* w0 = wg + (dq*4+0)*EE;
            const float* w1 = wg + (dq*4+1)*EE;
            const float* w2 = wg + (dq*4+2)*EE;
            const float* w3 = wg + (dq*4+3)*EE;
            #pragma unroll
            for (int e=0;e<EE;e++)
                lg[e] += xv.x*w0[e] + xv.y*w1[e] + xv.z*w2[e] + xv.w*w3[e];
        }
        float mx = lg[0];
        #pragma unroll
        for (int e=1;e<EE;e++) mx = fmaxf(mx, lg[e]);
        float sum = 0.f;
        #pragma unroll
        for (int e=0;e<EE;e++){ lg[e] = __expf(lg[e]-mx); sum += lg[e]; }
        float inv = 1.0f/sum;
        #pragma unroll
        for (int e=0;e<EE;e++) lg[e] *= inv;
        float v0=lg[0];
        #pragma unroll
        for (int e=1;e<EE;e++){ if (lg[e] > v0){ v0 = lg[e]; e0 = e; } }
        float v1=-1e30f; e1 = (e0==0) ? 1 : 0;
        #pragma unroll
        for (int e=0;e<EE;e++){ if (e==e0) continue; if (lg[e] > v1){ v1 = lg[e]; e1 = e; } }
        wA[t*2+0]=v0; wA[t*2+1]=v1;
        p0 = atomicAdd(&bcnt[e0], 1);
        p1 = atomicAdd(&bcnt[e1], 1);
    }
    __syncthreads();
    if (tid < EE){
        bbase[tid] = (bcnt[tid] > 0) ? atomicAdd(&counts[tid], bcnt[tid]) : 0;
    }
    __syncthreads();
    if (act){
        list[(size_t)e0*nTok + bbase[e0] + p0] = t*2;
        list[(size_t)e1*nTok + bbase[e1] + p1] = t*2+1;
    }
}

// ---------------- grouped expert FFN (MFMA): block = (expert, 64-token tile), 4 waves ----
__global__ __launch_bounds__(256) void moe_ffn_kernel(
    const float* __restrict__ xin,
    const unsigned short* __restrict__ w1T,
    const float* __restrict__ b1g,
    const unsigned short* __restrict__ w2T,
    const float* __restrict__ b2g,
    const int* __restrict__ counts, const int* __restrict__ list,
    const float* __restrict__ wA, int nTok,
    float* __restrict__ yslot)
{
    __shared__ __align__(16) unsigned short xs[64][72];
    __shared__ __align__(16) unsigned short w1s[64][72];
    __shared__ __align__(16) unsigned short w2s[64][72];
    __shared__ __align__(16) unsigned short hs[64][72];
    __shared__ int sCnt[EE];
    __shared__ int encs[64];
    __shared__ float wgts[64];
    const int tid = threadIdx.x;
    if (tid < EE) sCnt[tid] = counts[tid];
    __syncthreads();
    int e = -1, tile = 0;
    {
        int acc = 0, bid = blockIdx.x;
        #pragma unroll
        for (int i=0;i<EE;++i){
            int tc = (sCnt[i]+63)>>6;
            if (e < 0 && bid < acc + tc){ e = i; tile = bid - acc; }
            acc += tc;
        }
    }
    if (e < 0) return;
    const int cnt = sCnt[e];
    if (tid < 64){
        int idx = tile*64 + tid;
        int enc = (idx < cnt) ? list[(size_t)e*nTok + idx] : -1;
        encs[tid] = enc;
        wgts[tid] = (enc >= 0) ? wA[enc] : 0.f;
    }
    __syncthreads();
    for (int i=tid; i<64*16; i+=256){
        int r = i>>4, dq4 = (i&15)*4;
        int enc = encs[r];
        float4 xv = make_float4(0.f,0.f,0.f,0.f);
        if (enc >= 0) xv = *(const float4*)(xin + (size_t)(enc>>1)*DD + dq4);
        *(uint2*)&xs[r][dq4] = pack4bf(xv.x, xv.y, xv.z, xv.w);
    }

    const int w    = tid >> 6;
    const int lane = tid & 63;
    const int lq   = lane & 15;
    const int lg   = lane >> 4;

    const unsigned short* w1e = w1T + (size_t)e*FFND*DD;
    const unsigned short* w2e = w2T + (size_t)e*DD*FFND;

    f32x4 acc2[4] = {};

    for (int fc=0; fc<4; ++fc){
        __syncthreads();
        for (int i=tid; i<512; i+=256){
            int r = i>>3, jq = i&7;
            *(uint4*)&w1s[r][jq*8] = *(const uint4*)(w1e + (size_t)(fc*64+r)*DD + jq*8);
            *(uint4*)&w2s[r][jq*8] = *(const uint4*)(w2e + (size_t)r*FFND + fc*64 + jq*8);
        }
        __syncthreads();
        f32x4 acc1[4] = {};
        #pragma unroll
        for (int fb=0; fb<4; ++fb){
            #pragma unroll
            for (int ks=0; ks<2; ++ks){
                bf16x8_t xf = *reinterpret_cast<const bf16x8_t*>(&xs[w*16+lq][ks*32+lg*8]);
                bf16x8_t wf = *reinterpret_cast<const bf16x8_t*>(&w1s[fb*16+lq][ks*32+lg*8]);
                acc1[fb] = __builtin_amdgcn_mfma_f32_16x16x32_bf16(xf, wf, acc1[fb], 0, 0, 0);
            }
        }
        #pragma unroll
        for (int fb=0; fb<4; ++fb){
            float b1v = b1g[e*FFND + fc*64 + fb*16 + lq];
            #pragma unroll
            for (int r=0; r<4; ++r)
                hs[w*16 + lg*4 + r][fb*16 + lq] = f2bf(geluf(acc1[fb][r] + b1v));
        }
        #pragma unroll
        for (int db=0; db<4; ++db){
            #pragma unroll
            for (int ks=0; ks<2; ++ks){
                bf16x8_t hf  = *reinterpret_cast<const bf16x8_t*>(&hs[w*16+lq][ks*32+lg*8]);
                bf16x8_t w2f = *reinterpret_cast<const bf16x8_t*>(&w2s[db*16+lq][ks*32+lg*8]);
                acc2[db] = __builtin_amdgcn_mfma_f32_16x16x32_bf16(hf, w2f, acc2[db], 0, 0, 0);
            }
        }
    }
    #pragma unroll
    for (int r=0; r<4; ++r){
        int tok = w*16 + lg*4 + r;
        int enc = encs[tok];
        if (enc >= 0){
            float gw = wgts[tok];
            #pragma unroll
            for (int db=0; db<4; ++db){
                int d = db*16 + lq;
                yslot[(size_t)enc*DD + d] = gw*(acc2[db][r] + b2g[e*DD + d]);
            }
        }
    }
}

// ---------------- combine slots + gelu + MFMA projection (token-major output) ----------------
template<int NPROJ>
__global__ __launch_bounds__(256) void moe_proj_mfma_kernel(
    const float* __restrict__ yslot, const unsigned short* __restrict__ pwT,
    const float* __restrict__ pbg, int nTok,
    float* __restrict__ out0, float* __restrict__ out1, float* __restrict__ out2)
{
    __shared__ __align__(16) unsigned short gs[64][72];
    const int tid = threadIdx.x;
    const int base = blockIdx.x*64;
    for (int i=tid; i<64*16; i+=256){
        int r = i>>4, dq4 = (i&15)*4;
        int tok = base + r;
        float4 g4 = make_float4(0.f,0.f,0.f,0.f);
        if (tok < nTok){
            float4 a = *(const float4*)(yslot + (size_t)tok*128 + dq4);
            float4 b = *(const float4*)(yslot + (size_t)tok*128 + 64 + dq4);
            g4.x = geluf(a.x+b.x); g4.y = geluf(a.y+b.y);
            g4.z = geluf(a.z+b.z); g4.w = geluf(a.w+b.w);
        }
        *(uint2*)&gs[r][dq4] = pack4bf(g4.x, g4.y, g4.z, g4.w);
    }
    __syncthreads();

    const int w    = tid >> 6;
    const int lane = tid & 63;
    const int lq   = lane & 15;
    const int lg   = lane >> 4;
    constexpr int NC = NPROJ/64;
    const int colbase = w*16*NC;

    bf16x8_t wf[NC][2];
    #pragma unroll
    for (int cb=0; cb<NC; ++cb)
        #pragma unroll
        for (int ks=0; ks<2; ++ks)
            wf[cb][ks] = *reinterpret_cast<const bf16x8_t*>(
                pwT + (size_t)(colbase + cb*16 + lq)*DD + ks*32 + lg*8);

    f32x4 acc[4][NC] = {};
    #pragma unroll
    for (int m=0; m<4; ++m){
        #pragma unroll
        for (int ks=0; ks<2; ++ks){
            bf16x8_t af = *reinterpret_cast<const bf16x8_t*>(&gs[m*16+lq][ks*32+lg*8]);
            #pragma unroll
            for (int cb=0; cb<NC; ++cb)
                acc[m][cb] = __builtin_amdgcn_mfma_f32_16x16x32_bf16(af, wf[cb][ks], acc[m][cb], 0, 0, 0);
        }
    }
    #pragma unroll
    for (int m=0; m<4; ++m){
        #pragma unroll
        for (int r=0; r<4; ++r){
            int tok = base + m*16 + lg*4 + r;
            if (tok >= nTok) continue;
            #pragma unroll
            for (int cb=0; cb<NC; ++cb){
                int j = colbase + cb*16 + lq;
                float v = acc[m][cb][r] + pbg[j];
                int bufi = j >> 6, jd = j & 63;
                float* dst = (bufi==0) ? out0 : (bufi==1) ? out1 : out2;
                dst[(size_t)tok*DD + jd] = v;
            }
        }
    }
}

// ---------------- MFMA flash attention (split-s): block = (b,h,64-row t-tile), 4 waves ----
__global__ __launch_bounds__(256) void attn_kernel(
    const float* __restrict__ qb,
    const float* __restrict__ kmb,
    const float* __restrict__ vmb,
    const float* __restrict__ ktb,
    const float* __restrict__ vtb,
    const float* __restrict__ kd,   // (NDS,48,H,64) -> [0]
    const float* __restrict__ vd,
    const float* __restrict__ kr,   // (48,H,64)
    const float* __restrict__ vr,
    const int*   __restrict__ smask, // (B,T)
    const float* __restrict__ tcond, // (B,1)
    const float* __restrict__ kms_p, const float* __restrict__ kds_p,
    const float* __restrict__ krs_p, const float* __restrict__ kts_p,
    const float* __restrict__ sigma_p,
    float* __restrict__ po,          // (2, NROWS, 64)
    float* __restrict__ pm,          // (2, NROWS)
    float* __restrict__ pl)          // (2, NROWS)
{
    __shared__ __align__(16) unsigned short Ks[64][72];
    __shared__ __align__(16) unsigned short Vt[64][72];
    __shared__ __align__(16) unsigned short Pl[4][16][72];
    __shared__ float madd[64];

    const int tid  = threadIdx.x;
    const int w    = tid >> 6;
    const int lane = tid & 63;
    const int lq   = lane & 15;
    const int lg   = lane >> 4;

    const int bid   = blockIdx.x;
    const int split = blockIdx.y;
    const int ch_lo = split ? 6 : 0;
    const int ch_hi = split ? NCH : 6;
    const int ttile = bid & 7;
    const int bh    = bid >> 3;
    const int b = bh / HH, h = bh % HH;
    const int t0 = ttile * 64;

    const float sc = 0.125f;
    const float kms = kms_p[0]*sc, kds = kds_p[0]*sc, krs = krs_p[0]*sc, kts = kts_p[0]*sc;
    const float sg = sigma_p[0];
    const float inv2s = 1.0f/(2.0f*sg*sg);
    const bool text_on = tcond[b] > 0.f;

    bf16x8_t qf[2];
    {
        const float* qrow = qb + ((size_t)(b*TT + t0 + w*16 + lq)*HH + h)*DD;
        #pragma unroll
        for (int ks=0; ks<2; ++ks){
            float4 v0 = *(const float4*)(qrow + ks*32 + lg*8);
            float4 v1 = *(const float4*)(qrow + ks*32 + lg*8 + 4);
            u16x8 qt;
            qt[0]=f2bf(v0.x); qt[1]=f2bf(v0.y); qt[2]=f2bf(v0.z); qt[3]=f2bf(v0.w);
            qt[4]=f2bf(v1.x); qt[5]=f2bf(v1.y); qt[6]=f2bf(v1.z); qt[7]=f2bf(v1.w);
            qf[ks] = __builtin_bit_cast(bf16x8_t, qt);
        }
    }

    float m_r = -1e30f, l_r = 0.f;
    f32x4 oacc[4] = {};

    const int tgq = t0 + w*16 + lq;

    for (int ch=ch_lo; ch<ch_hi; ++ch){
        __syncthreads();
        for (int i=tid; i<64*16; i+=256){
            int r = i>>4, dq4 = (i&15)*4;
            int s = ch*64 + r;
            float4 kv = make_float4(0,0,0,0), vv = make_float4(0,0,0,0);
            if (s < TT){
                size_t o = ((size_t)(b*TT + s)*HH + h)*DD + dq4;
                kv = *(const float4*)(&kmb[o]);
                kv.x*=kms; kv.y*=kms; kv.z*=kms; kv.w*=kms;
                vv = *(const float4*)(&vmb[o]);
            } else if (s < TT+48){
                kv = *(const float4*)(&kd[((size_t)(s-TT)*HH + h)*DD + dq4]);
                kv.x*=kds; kv.y*=kds; kv.z*=kds; kv.w*=kds;
                vv = *(const float4*)(&vd[((size_t)(s-TT)*HH + h)*DD + dq4]);
            } else if (s < TT+96){
                kv = *(const float4*)(&kr[((size_t)(s-TT-48)*HH + h)*DD + dq4]);
                kv.x*=krs; kv.y*=krs; kv.z*=krs; kv.w*=krs;
                vv = *(const float4*)(&vr[((size_t)(s-TT-48)*HH + h)*DD + dq4]);
            } else if (s < NS){
                size_t o = ((size_t)(b*MM + (s-TT-96))*HH + h)*DD + dq4;
                kv = *(const float4*)(&ktb[o]);
                kv.x*=kts; kv.y*=kts; kv.z*=kts; kv.w*=kts;
                vv = *(const float4*)(&vtb[o]);
            }
            *(uint2*)&Ks[r][dq4] = pack4bf(kv.x, kv.y, kv.z, kv.w);
            int swcol = r ^ (((i&15)&7)<<3);
            Vt[dq4+0][swcol] = f2bf(vv.x);
            Vt[dq4+1][swcol] = f2bf(vv.y);
            Vt[dq4+2][swcol] = f2bf(vv.z);
            Vt[dq4+3][swcol] = f2bf(vv.w);
        }
        if (tid < 64){
            int s = ch*64 + tid;
            float a;
            if (s < TT)            a = (smask[b*TT + s] == 0) ? -1e9f : 0.f;
            else if (s < TT+96)    a = 0.f;
            else if (s < NS)       a = text_on ? 0.f : -1e9f;
            else                   a = -1e30f;
            madd[tid] = a;
        }
        __syncthreads();

        f32x4 sacc[4] = {};
        #pragma unroll
        for (int sl=0; sl<4; ++sl){
            #pragma unroll
            for (int ks=0; ks<2; ++ks){
                bf16x8_t kf = *reinterpret_cast<const bf16x8_t*>(&Ks[sl*16 + lq][ks*32 + lg*8]);
                sacc[sl] = __builtin_amdgcn_mfma_f32_16x16x32_bf16(kf, qf[ks], sacc[sl], 0, 0, 0);
            }
        }
        float sv[4][4];
        float pmax = -1e30f;
        #pragma unroll
        for (int sl=0; sl<4; ++sl){
            #pragma unroll
            for (int r=0; r<4; ++r){
                int s_loc = sl*16 + lg*4 + r;
                float a = madd[s_loc];
                if (ch < 8){ float dt = (float)(tgq - (ch*64 + s_loc)); a -= dt*dt*inv2s; }
                float v = sacc[sl][r] + a;
                sv[sl][r] = v;
                pmax = fmaxf(pmax, v);
            }
        }
        pmax = fmaxf(pmax, __shfl_xor(pmax, 16));
        pmax = fmaxf(pmax, __shfl_xor(pmax, 32));
        float mn  = fmaxf(m_r, pmax);
        float scl = __expf(m_r - mn);
        m_r = mn;
        float psum = 0.f;
        #pragma unroll
        for (int sl=0; sl<4; ++sl){
            #pragma unroll
            for (int r=0; r<4; ++r){
                float p = __expf(sv[sl][r] - mn);
                sv[sl][r] = p;
                psum += p;
            }
        }
        psum += __shfl_xor(psum, 16);
        psum += __shfl_xor(psum, 32);
        l_r = l_r*scl + psum;
        #pragma unroll
        for (int sl=0; sl<4; ++sl)
            *(uint2*)&Pl[w][lq][sl*16 + lg*4] = pack4bf(sv[sl][0], sv[sl][1], sv[sl][2], sv[sl][3]);

        #pragma unroll
        for (int r=0; r<4; ++r){
            float so = __shfl(scl, lg*4 + r);
            #pragma unroll
            for (int ds_=0; ds_<4; ++ds_) oacc[ds_][r] *= so;
        }
        #pragma unroll
        for (int ds_=0; ds_<4; ++ds_){
            int dcol = ds_*16 + lq;
            int swz = (((dcol>>2)&7)<<3);
            #pragma unroll
            for (int ks=0; ks<2; ++ks){
                bf16x8_t pf = *reinterpret_cast<const bf16x8_t*>(&Pl[w][lq][ks*32 + lg*8]);
                bf16x8_t vf = *reinterpret_cast<const bf16x8_t*>(&Vt[dcol][(ks*32 + lg*8) ^ swz]);
                oacc[ds_] = __builtin_amdgcn_mfma_f32_16x16x32_bf16(pf, vf, oacc[ds_], 0, 0, 0);
            }
        }
    }
    #pragma unroll
    for (int r=0; r<4; ++r){
        int t = t0 + w*16 + lg*4 + r;
        size_t off = (size_t)split*NROWS + (size_t)bh*TT + t;
        #pragma unroll
        for (int ds_=0; ds_<4; ++ds_)
            po[off*64 + ds_*16 + lq] = oacc[ds_][r];
    }
    if (lg == 0){
        size_t off = (size_t)split*NROWS + (size_t)bh*TT + (t0 + w*16 + lq);
        pm[off] = m_r;
        pl[off] = l_r;
    }
}

// ---------------- bf16 MFMA GEMM: C = A(or bf16 A) @ W + bias (+res). Wt bf16 [N][K] ------
template<bool A_BF16>
__global__ __launch_bounds__(256) void gemm_mfma_kernel(
    const void* __restrict__ Ap, const unsigned short* __restrict__ Wt,
    const float* __restrict__ bias, const float* __restrict__ res,
    float* __restrict__ C, int Mr, int Nr, int Kr)
{
    __shared__ __align__(16) unsigned short As[32][40];
    __shared__ __align__(16) unsigned short Bs[64][40];
    int tid = threadIdx.x;
    int row0 = blockIdx.x*32, col0 = blockIdx.y*64;
    int wave = tid >> 6, lane = tid & 63;
    int lr = lane & 15, lk = lane >> 4;

    f32x4 acc[2] = {};

    for (int k0 = 0; k0 < Kr; k0 += 32){
        __syncthreads();
        {
            int r = tid >> 3, kq = tid & 7;
            if (A_BF16){
                const unsigned short* A = (const unsigned short*)Ap;
                *(uint2*)&As[r][kq*4] = *(const uint2*)(A + (size_t)(row0 + r)*Kr + k0 + kq*4);
            } else {
                const float* A = (const float*)Ap;
                float4 v = *(const float4*)(A + (size_t)(row0 + r)*Kr + k0 + kq*4);
                *(uint2*)&As[r][kq*4] = pack4bf(v.x, v.y, v.z, v.w);
            }
        }
        {
            int n = tid >> 2, oq = tid & 3;
            *(uint4*)&Bs[n][oq*8] = *(const uint4*)(Wt + (size_t)(col0+n)*Kr + k0 + oq*8);
        }
        __syncthreads();
        bf16x8_t a0 = *reinterpret_cast<const bf16x8_t*>(&As[lr][lk*8]);
        bf16x8_t a1 = *reinterpret_cast<const bf16x8_t*>(&As[16 + lr][lk*8]);
        bf16x8_t bfr = *reinterpret_cast<const bf16x8_t*>(&Bs[wave*16 + lr][lk*8]);
        acc[0] = __builtin_amdgcn_mfma_f32_16x16x32_bf16(a0, bfr, acc[0], 0, 0, 0);
        acc[1] = __builtin_amdgcn_mfma_f32_16x16x32_bf16(a1, bfr, acc[1], 0, 0, 0);
    }
    int gc = col0 + wave*16 + lr;
    float bv = bias[gc];
    #pragma unroll
    for (int m=0;m<2;++m){
        #pragma unroll
        for (int r=0;r<4;++r){
            int gr = row0 + m*16 + lk*4 + r;
            float v = acc[m][r] + bv;
            size_t off = (size_t)gr*Nr + gc;
            if (res) v += res[off];
            C[off] = v;
        }
    }
}

// ---------------- fused split-combine + modulated LN + silu ----------------
// block = one token row (b*TT + t). Combines the 2 attn s-splits, then LN/mod/silu.
__global__ __launch_bounds__(256) void lnmod_combine_kernel(
    const float* __restrict__ po, const float* __restrict__ pm, const float* __restrict__ pl,
    const float* __restrict__ g, const float* __restrict__ bb,
    const float* __restrict__ eo, float* __restrict__ out)
{
    int row = blockIdx.x, tid = threadIdx.x;
    int b = row / TT, t = row % TT;
    __shared__ float xsr[LATD];
    __shared__ float red[256];
    float s = 0.f;
    for (int i=tid;i<LATD;i+=256){
        int h = i >> 6, d = i & 63;
        size_t rowid = ((size_t)(b*HH + h))*TT + t;
        float m0 = pm[rowid], m1 = pm[NROWS + rowid];
        float l0 = pl[rowid], l1 = pl[NROWS + rowid];
        float m = fmaxf(m0, m1);
        float s0 = __expf(m0 - m), s1 = __expf(m1 - m);
        float inv = 1.0f / (l0*s0 + l1*s1);
        float o0 = po[rowid*64 + d];
        float o1 = po[((size_t)NROWS + rowid)*64 + d];
        float v = (o0*s0 + o1*s1)*inv;
        xsr[i] = v; s += v;
    }
    red[tid]=s; __syncthreads();
    for (int k=128;k>0;k>>=1){ if (tid<k) red[tid]+=red[tid+k]; __syncthreads(); }
    float mean = red[0]*(1.0f/LATD);
    __syncthreads();
    float vs=0.f;
    for (int i=tid;i<LATD;i+=256){ float d=xsr[i]-mean; vs+=d*d; }
    red[tid]=vs; __syncthreads();
    for (int k=128;k>0;k>>=1){ if (tid<k) red[tid]+=red[tid+k]; __syncthreads(); }
    float rstd = rsqrtf(red[0]*(1.0f/LATD)+1e-5f);
    const float* ep = eo + (size_t)row*(2*LATD);
    float* op = out + (size_t)row*LATD;
    for (int i=tid;i<LATD;i+=256){
        float v = (xsr[i]-mean)*rstd*g[i] + bb[i];
        v = v*(1.0f + ep[i]) + ep[LATD+i];
        op[i] = siluf(v);
    }
}

extern "C" void kernel_launch(void* const* d_in, const int* in_sizes, int n_in,
                              void* d_out, int out_size, void* d_ws, size_t ws_size,
                              hipStream_t stream)
{
    (void)in_sizes; (void)n_in; (void)out_size; (void)ws_size;
    const float* x     = (const float*)d_in[0];
    const float* emb   = (const float*)d_in[1];
    const int*   smask = (const int*)d_in[2];
    const float* tcond = (const float*)d_in[5];
    const float* two   = (const float*)d_in[6];
    const float* ng    = (const float*)d_in[7];
    const float* nb    = (const float*)d_in[8];
    const float* memb  = (const float*)d_in[9];
    const float* m_wg  = (const float*)d_in[10];
    const float* m_w1  = (const float*)d_in[11];
    const float* m_b1  = (const float*)d_in[12];
    const float* m_w2  = (const float*)d_in[13];
    const float* m_b2  = (const float*)d_in[14];
    const float* m_pw  = (const float*)d_in[15];
    const float* m_pb  = (const float*)d_in[16];
    const float* kms   = (const float*)d_in[17];
    const float* sigma = (const float*)d_in[18];
    const float* kdat  = (const float*)d_in[19];
    const float* kds   = (const float*)d_in[20];
    const float* vdat  = (const float*)d_in[21];
    const float* krot  = (const float*)d_in[22];
    const float* krs   = (const float*)d_in[23];
    const float* vrot  = (const float*)d_in[24];
    const float* ntg   = (const float*)d_in[25];
    const float* ntb   = (const float*)d_in[26];
    const float* c_wg  = (const float*)d_in[27];
    const float* c_w1  = (const float*)d_in[28];
    const float* c_b1  = (const float*)d_in[29];
    const float* c_w2  = (const float*)d_in[30];
    const float* c_b2  = (const float*)d_in[31];
    const float* c_pw  = (const float*)d_in[32];
    const float* c_pb  = (const float*)d_in[33];
    const float* kts   = (const float*)d_in[34];
    const float* st_ew = (const float*)d_in[35];
    const float* st_eb = (const float*)d_in[36];
    const float* st_ng = (const float*)d_in[37];
    const float* st_nb = (const float*)d_in[38];
    const float* st_ow = (const float*)d_in[39];
    const float* st_ob = (const float*)d_in[40];

    float* ws = (float*)d_ws;
    float* xh   = ws;                    // 1310720
    float* qB   = xh  + 1310720;         // (B,T,H,64) token-major
    float* kmB  = qB  + 1310720;
    float* vmB  = kmB + 1310720;
    float* ctB  = vmB + 1310720;         // 197120
    float* ktB  = ctB + 197120;          // (B,M,H,64)
    float* vtB  = ktB + 197120;
    float* aout = vtB + 197120;          // 1310720 (routing scratch only)
    float* eoB  = aout + 1310720;        // 2621440
    float* shB  = eoB + 2621440;         // 1310720

    // pre-transposed bf16 weights (persist whole launch)
    unsigned short* w1Tm = (unsigned short*)(shB + 1310720);
    unsigned short* w2Tm = w1Tm + EE*FFND*DD;
    unsigned short* w1Tt = w2Tm + EE*FFND*DD;
    unsigned short* w2Tt = w1Tt + EE*FFND*DD;
    unsigned short* stewT = w2Tt + EE*FFND*DD;
    unsigned short* stowT = stewT + 512*1280;
    unsigned short* mpwT  = stowT + 640*640;
    unsigned short* cpwT  = mpwT + 320*64;
    unsigned short* embBf = cpwT + 128*64;       // 2048*512 bf16
    // attn partials in dedicated space (must not alias eoB: gemm1 writes eoB before lnmod reads po)
    float* poB = (float*)(embBf + 2048*512);     // 2*NROWS*64 = 2621440 f
    float* pmB = poB + 2*NROWS*64;               // 40960 f
    float* plB = pmB + 2*NROWS;                  // 40960 f

    float* yslotM = eoB;
    float* yslotT = shB;
    float* wAm   = aout;
    float* wAt   = wAm + NTOK_M*2;
    int*   cntA  = (int*)(wAt + NTOK_T*2);
    int*   listM = cntA + 16;
    int*   listT = listM + EE*NTOK_M;

    prep_weights_kernel<<<651, 256, 0, stream>>>(
        m_w1, w1Tm, m_w2, w2Tm, c_w1, w1Tt, c_w2, w2Tt,
        st_ew, stewT, st_ow, stowT, m_pw, mpwT, c_pw, cpwT,
        emb, embBf, cntA);

    ln_kernel<<<BB*TT + BB*MM, 256, 0, stream>>>(
        x, ng, nb, memb, xh, two, ntg, ntb, ctB);
    route_kernel<<<(NTOK_M+255)/256, 256, 0, stream>>>(xh, m_wg, NTOK_M, cntA, listM, wAm);
    route_kernel<<<(NTOK_T+255)/256, 256, 0, stream>>>(ctB, c_wg, NTOK_T, cntA+8, listT, wAt);
    moe_ffn_kernel<<<MAXB_M, 256, 0, stream>>>(
        xh, w1Tm, m_b1, w2Tm, m_b2, cntA, listM, wAm, NTOK_M, yslotM);
    moe_ffn_kernel<<<MAXB_T, 256, 0, stream>>>(
        ctB, w1Tt, c_b1, w2Tt, c_b2, cntA+8, listT, wAt, NTOK_T, yslotT);
    moe_proj_mfma_kernel<192><<<(NTOK_M+63)/64, 256, 0, stream>>>(
        yslotM, mpwT, m_pb, NTOK_M, qB, kmB, vmB);
    moe_proj_mfma_kernel<128><<<(NTOK_T+63)/64, 256, 0, stream>>>(
        yslotT, cpwT, c_pb, NTOK_T, ktB, vtB, nullptr);
    {
        dim3 ga(BB*HH*8, 2);
        attn_kernel<<<ga, 256, 0, stream>>>(
            qB, kmB, vmB, ktB, vtB, kdat, vdat, krot, vrot, smask, tcond,
            kms, kds, krs, kts, sigma, poB, pmB, plB);
    }
    {
        dim3 g1(2048/32, 1280/64);
        gemm_mfma_kernel<true><<<g1, 256, 0, stream>>>(embBf, stewT, st_eb, nullptr, eoB, 2048, 1280, 512);
    }
    lnmod_combine_kernel<<<BB*TT, 256, 0, stream>>>(
        poB, pmB, plB, st_ng, st_nb, eoB, shB);
    {
        dim3 g2(2048/32, 640/64);
        gemm_mfma_kernel<false><<<g2, 256, 0, stream>>>(shB, stowT, st_ob, x, (float*)d_out, 2048, 640, 640);
    }
}

// Round 12
// 121.126 us; speedup vs baseline: 1.6847x; 1.2511x over previous
//
#include <hip/hip_runtime.h>
#include <math.h>

#define BB 4
#define TT 512
#define MM 77
#define HH 10
#define DD 64
#define LATD 640
#define EE 8
#define FFND 256
#define NS 685     // 512 + 48 + 48 + 77
#define NCH 11     // ceil(685/64)
#define NROWS 20480
#define NSPLIT 4

#define NTOK_M (BB*TT*HH)   // 20480
#define NTOK_T (BB*MM*HH)   // 3080
#define MAXB_M 647
#define MAXB_T 103
#define PROJB_M 320         // NTOK_M/64
#define PROJB_T 49          // ceil(NTOK_T/64)
#define ROUTEB_M 80
#define ROUTEB_T 13

typedef float f32x4 __attribute__((ext_vector_type(4)));
typedef __bf16 bf16x8_t __attribute__((ext_vector_type(8)));
typedef unsigned short u16x8 __attribute__((ext_vector_type(8)));

__device__ __forceinline__ float geluf(float x){
    float u = 0.7978845608028654f*(x + 0.044715f*x*x*x);
    u = fminf(fmaxf(u, -15.f), 15.f);
    float e = __expf(2.f*u);
    return 0.5f*x*(1.f + (e-1.f)/(e+1.f));
}
__device__ __forceinline__ float siluf(float x){
    return x / (1.0f + __expf(-x));
}
__device__ __forceinline__ unsigned short f2bf(float f){
    unsigned int u = __float_as_uint(f);
    u += 0x7fff + ((u >> 16) & 1);
    return (unsigned short)(u >> 16);
}
__device__ __forceinline__ uint2 pack4bf(float a, float b, float c, float d){
    uint2 r;
    r.x = (unsigned)f2bf(a) | ((unsigned)f2bf(b)<<16);
    r.y = (unsigned)f2bf(c) | ((unsigned)f2bf(d)<<16);
    return r;
}

// ======== fused prep + LN: weight transposes+bf16, silu(emb)->bf16, zero counts, LN M/T ===
__global__ __launch_bounds__(256) void prep_ln_kernel(
    const float* __restrict__ m_w1, unsigned short* __restrict__ w1Tm,
    const float* __restrict__ m_w2, unsigned short* __restrict__ w2Tm,
    const float* __restrict__ c_w1, unsigned short* __restrict__ w1Tt,
    const float* __restrict__ c_w2, unsigned short* __restrict__ w2Tt,
    const float* __restrict__ st_ew, unsigned short* __restrict__ stewT,
    const float* __restrict__ st_ow, unsigned short* __restrict__ stowT,
    const float* __restrict__ m_pw, unsigned short* __restrict__ mpwT,
    const float* __restrict__ c_pw, unsigned short* __restrict__ cpwT,
    const float* __restrict__ emb, unsigned short* __restrict__ embBf,
    int* __restrict__ cnt,
    const float* __restrict__ x, const float* __restrict__ ng, const float* __restrict__ nb,
    const float* __restrict__ memb, float* __restrict__ xh,
    const float* __restrict__ two, const float* __restrict__ ntg, const float* __restrict__ ntb,
    float* __restrict__ ctB)
{
    __shared__ float buf[64*65];
    const int bid = blockIdx.x, tid = threadIdx.x;
    if (bid >= 651){
        // ---- LN branch: blocks [651, 651+2048+308) ----
        int lrow = bid - 651;
        const float* in; const float* g; const float* bb; const float* ap; float* out;
        int row;
        if (lrow < BB*TT){
            row = lrow; in = x; g = ng; bb = nb; out = xh;
            ap = memb + (size_t)(row % TT)*LATD;
        } else {
            row = lrow - BB*TT; in = two; g = ntg; bb = ntb; out = ctB;
            ap = nullptr;
        }
        float* xsr = buf;
        float* red = buf + LATD;
        const float* rp = in + (size_t)row*LATD;
        float s = 0.f;
        for (int i=tid;i<LATD;i+=256){ float v = rp[i]; xsr[i]=v; s+=v; }
        red[tid]=s; __syncthreads();
        for (int k=128;k>0;k>>=1){ if (tid<k) red[tid]+=red[tid+k]; __syncthreads(); }
        float mean = red[0]*(1.0f/LATD);
        __syncthreads();
        float vs=0.f;
        for (int i=tid;i<LATD;i+=256){ float d=xsr[i]-mean; vs+=d*d; }
        red[tid]=vs; __syncthreads();
        for (int k=128;k>0;k>>=1){ if (tid<k) red[tid]+=red[tid+k]; __syncthreads(); }
        float rstd = rsqrtf(red[0]*(1.0f/LATD)+1e-5f);
        float* op = out + (size_t)row*LATD;
        for (int i=tid;i<LATD;i+=256){
            float v = (xsr[i]-mean)*rstd*g[i] + bb[i];
            if (ap) v += ap[i];
            op[i] = v;
        }
        return;
    }
    if (bid >= 395){
        // ---- silu(emb)->bf16 branch ----
        int l = bid - 395;
        if (l == 0 && tid < 16) cnt[tid] = 0;
        size_t base = (size_t)l*4096;
        #pragma unroll
        for (int p=0; p<4; ++p){
            size_t i = base + (size_t)p*1024 + tid*4;
            float4 v = *(const float4*)(emb + i);
            *(uint2*)(embBf + i) = pack4bf(siluf(v.x), siluf(v.y), siluf(v.z), siluf(v.w));
        }
        return;
    }
    // ---- transpose+bf16 branch ----
    float (*t)[65] = (float(*)[65])buf;
    const float* in; unsigned short* out; int R, C, z, rt, ct;
    if (bid < 32)      { int l=bid;     in=m_w1;  out=w1Tm;  R=64;  C=256;  z=l>>2; rt=0;    ct=l&3; }
    else if (bid < 64) { int l=bid-32;  in=m_w2;  out=w2Tm;  R=256; C=64;   z=l>>2; rt=l&3;  ct=0; }
    else if (bid < 96) { int l=bid-64;  in=c_w1;  out=w1Tt;  R=64;  C=256;  z=l>>2; rt=0;    ct=l&3; }
    else if (bid < 128){ int l=bid-96;  in=c_w2;  out=w2Tt;  R=256; C=64;   z=l>>2; rt=l&3;  ct=0; }
    else if (bid < 288){ int l=bid-128; in=st_ew; out=stewT; R=512; C=1280; z=0;    rt=l/20; ct=l%20; }
    else if (bid < 388){ int l=bid-288; in=st_ow; out=stowT; R=640; C=640;  z=0;    rt=l/10; ct=l%10; }
    else if (bid < 393){ int l=bid-388; in=m_pw;  out=mpwT;  R=64;  C=320;  z=0;    rt=0;    ct=l; }
    else               { int l=bid-393; in=c_pw;  out=cpwT;  R=64;  C=128;  z=0;    rt=0;    ct=l; }
    const size_t base = (size_t)z*R*C;
    const int r0 = rt*64, c0 = ct*64;
    #pragma unroll
    for (int p=0; p<16; ++p){
        int i = tid + p*256;
        int r = i>>6, c = i&63;
        t[r][c] = in[base + (size_t)(r0+r)*C + c0 + c];
    }
    __syncthreads();
    #pragma unroll
    for (int p=0; p<16; ++p){
        int i = tid + p*256;
        int c = i>>6, r = i&63;
        out[base + (size_t)(c0+c)*R + r0 + r] = f2bf(t[r][c]);
    }
}

// ======== MoE routing, M+T merged (block-aggregated atomics) ========
__global__ __launch_bounds__(256) void route_kernel(
    const float* __restrict__ xinM, const float* __restrict__ wgM,
    int* __restrict__ countsM, int* __restrict__ listM, float* __restrict__ wAM,
    const float* __restrict__ xinT, const float* __restrict__ wgT,
    int* __restrict__ countsT, int* __restrict__ listT, float* __restrict__ wAT)
{
    __shared__ int bcnt[EE];
    __shared__ int bbase[EE];
    const int tid = threadIdx.x;
    const int bid = blockIdx.x;
    const float* xin; const float* wg; int* counts; int* list; float* wA; int nTok, t;
    if (bid < ROUTEB_M){
        xin = xinM; wg = wgM; counts = countsM; list = listM; wA = wAM; nTok = NTOK_M;
        t = bid*256 + tid;
    } else {
        xin = xinT; wg = wgT; counts = countsT; list = listT; wA = wAT; nTok = NTOK_T;
        t = (bid - ROUTEB_M)*256 + tid;
    }
    if (tid < EE) bcnt[tid] = 0;
    __syncthreads();

    int e0 = 0, e1 = 0, p0 = 0, p1 = 0;
    bool act = (t < nTok);
    if (act){
        float lg[EE];
        #pragma unroll
        for (int e=0;e<EE;e++) lg[e]=0.f;
        const float4* xp = (const float4*)(xin + (size_t)t*DD);
        #pragma unroll 4
        for (int dq=0; dq<16; ++dq){
            float4 xv = xp[dq];
            const float* w0 = wg + (dq*4+0)*EE;
            const float* w1 = wg + (dq*4+1)*EE;
            const float* w2 = wg + (dq*4+2)*EE;
            const float* w3 = wg + (dq*4+3)*EE;
            #pragma unroll
            for (int e=0;e<EE;e++)
                lg[e] += xv.x*w0[e] + xv.y*w1[e] + xv.z*w2[e] + xv.w*w3[e];
        }
        float mx = lg[0];
        #pragma unroll
        for (int e=1;e<EE;e++) mx = fmaxf(mx, lg[e]);
        float sum = 0.f;
        #pragma unroll
        for (int e=0;e<EE;e++){ lg[e] = __expf(lg[e]-mx); sum += lg[e]; }
        float inv = 1.0f/sum;
        #pragma unroll
        for (int e=0;e<EE;e++) lg[e] *= inv;
        float v0=lg[0];
        #pragma unroll
        for (int e=1;e<EE;e++){ if (lg[e] > v0){ v0 = lg[e]; e0 = e; } }
        float v1=-1e30f; e1 = (e0==0) ? 1 : 0;
        #pragma unroll
        for (int e=0;e<EE;e++){ if (e==e0) continue; if (lg[e] > v1){ v1 = lg[e]; e1 = e; } }
        wA[t*2+0]=v0; wA[t*2+1]=v1;
        p0 = atomicAdd(&bcnt[e0], 1);
        p1 = atomicAdd(&bcnt[e1], 1);
    }
    __syncthreads();
    if (tid < EE){
        bbase[tid] = (bcnt[tid] > 0) ? atomicAdd(&counts[tid], bcnt[tid]) : 0;
    }
    __syncthreads();
    if (act){
        list[(size_t)e0*nTok + bbase[e0] + p0] = t*2;
        list[(size_t)e1*nTok + bbase[e1] + p1] = t*2+1;
    }
}

// ======== grouped expert FFN (MFMA), M+T merged ========
__global__ __launch_bounds__(256) void moe_ffn_kernel(
    const float* __restrict__ xinM, const unsigned short* __restrict__ w1TM,
    const float* __restrict__ b1M, const unsigned short* __restrict__ w2TM,
    const float* __restrict__ b2M, const int* __restrict__ countsM,
    const int* __restrict__ listM, const float* __restrict__ wAM,
    float* __restrict__ yslotM,
    const float* __restrict__ xinT, const unsigned short* __restrict__ w1TT,
    const float* __restrict__ b1T, const unsigned short* __restrict__ w2TT,
    const float* __restrict__ b2T, const int* __restrict__ countsT,
    const int* __restrict__ listT, const float* __restrict__ wAT,
    float* __restrict__ yslotT)
{
    __shared__ __align__(16) unsigned short xs[64][72];
    __shared__ __align__(16) unsigned short w1s[64][72];
    __shared__ __align__(16) unsigned short w2s[64][72];
    __shared__ __align__(16) unsigned short hs[64][72];
    __shared__ int sCnt[EE];
    __shared__ int encs[64];
    __shared__ float wgts[64];
    const int tid = threadIdx.x;
    const float* xin; const unsigned short* w1T; const float* b1g;
    const unsigned short* w2T; const float* b2g; const int* counts;
    const int* list; const float* wA; float* yslot; int nTok, bidl;
    if (blockIdx.x < MAXB_M){
        xin=xinM; w1T=w1TM; b1g=b1M; w2T=w2TM; b2g=b2M; counts=countsM;
        list=listM; wA=wAM; yslot=yslotM; nTok=NTOK_M; bidl=blockIdx.x;
    } else {
        xin=xinT; w1T=w1TT; b1g=b1T; w2T=w2TT; b2g=b2T; counts=countsT;
        list=listT; wA=wAT; yslot=yslotT; nTok=NTOK_T; bidl=blockIdx.x-MAXB_M;
    }
    if (tid < EE) sCnt[tid] = counts[tid];
    __syncthreads();
    int e = -1, tile = 0;
    {
        int acc = 0;
        #pragma unroll
        for (int i=0;i<EE;++i){
            int tc = (sCnt[i]+63)>>6;
            if (e < 0 && bidl < acc + tc){ e = i; tile = bidl - acc; }
            acc += tc;
        }
    }
    if (e < 0) return;
    const int cnt = sCnt[e];
    if (tid < 64){
        int idx = tile*64 + tid;
        int enc = (idx < cnt) ? list[(size_t)e*nTok + idx] : -1;
        encs[tid] = enc;
        wgts[tid] = (enc >= 0) ? wA[enc] : 0.f;
    }
    __syncthreads();
    for (int i=tid; i<64*16; i+=256){
        int r = i>>4, dq4 = (i&15)*4;
        int enc = encs[r];
        float4 xv = make_float4(0.f,0.f,0.f,0.f);
        if (enc >= 0) xv = *(const float4*)(xin + (size_t)(enc>>1)*DD + dq4);
        *(uint2*)&xs[r][dq4] = pack4bf(xv.x, xv.y, xv.z, xv.w);
    }

    const int w    = tid >> 6;
    const int lane = tid & 63;
    const int lq   = lane & 15;
    const int lg   = lane >> 4;

    const unsigned short* w1e = w1T + (size_t)e*FFND*DD;
    const unsigned short* w2e = w2T + (size_t)e*DD*FFND;

    f32x4 acc2[4] = {};

    for (int fc=0; fc<4; ++fc){
        __syncthreads();
        for (int i=tid; i<512; i+=256){
            int r = i>>3, jq = i&7;
            *(uint4*)&w1s[r][jq*8] = *(const uint4*)(w1e + (size_t)(fc*64+r)*DD + jq*8);
            *(uint4*)&w2s[r][jq*8] = *(const uint4*)(w2e + (size_t)r*FFND + fc*64 + jq*8);
        }
        __syncthreads();
        f32x4 acc1[4] = {};
        #pragma unroll
        for (int fb=0; fb<4; ++fb){
            #pragma unroll
            for (int ks=0; ks<2; ++ks){
                bf16x8_t xf = *reinterpret_cast<const bf16x8_t*>(&xs[w*16+lq][ks*32+lg*8]);
                bf16x8_t wf = *reinterpret_cast<const bf16x8_t*>(&w1s[fb*16+lq][ks*32+lg*8]);
                acc1[fb] = __builtin_amdgcn_mfma_f32_16x16x32_bf16(xf, wf, acc1[fb], 0, 0, 0);
            }
        }
        #pragma unroll
        for (int fb=0; fb<4; ++fb){
            float b1v = b1g[e*FFND + fc*64 + fb*16 + lq];
            #pragma unroll
            for (int r=0; r<4; ++r)
                hs[w*16 + lg*4 + r][fb*16 + lq] = f2bf(geluf(acc1[fb][r] + b1v));
        }
        #pragma unroll
        for (int db=0; db<4; ++db){
            #pragma unroll
            for (int ks=0; ks<2; ++ks){
                bf16x8_t hf  = *reinterpret_cast<const bf16x8_t*>(&hs[w*16+lq][ks*32+lg*8]);
                bf16x8_t w2f = *reinterpret_cast<const bf16x8_t*>(&w2s[db*16+lq][ks*32+lg*8]);
                acc2[db] = __builtin_amdgcn_mfma_f32_16x16x32_bf16(hf, w2f, acc2[db], 0, 0, 0);
            }
        }
    }
    #pragma unroll
    for (int r=0; r<4; ++r){
        int tok = w*16 + lg*4 + r;
        int enc = encs[tok];
        if (enc >= 0){
            float gw = wgts[tok];
            #pragma unroll
            for (int db=0; db<4; ++db){
                int d = db*16 + lq;
                yslot[(size_t)enc*DD + d] = gw*(acc2[db][r] + b2g[e*DD + d]);
            }
        }
    }
}

// ======== combine slots + gelu + MFMA projection, M+T merged ========
template<int NPROJ>
__device__ __forceinline__ void proj_body(
    const float* __restrict__ yslot, const unsigned short* __restrict__ pwT,
    const float* __restrict__ pbg, int nTok, int base,
    float* __restrict__ out0, float* __restrict__ out1, float* __restrict__ out2,
    unsigned short gs[64][72])
{
    const int tid = threadIdx.x;
    for (int i=tid; i<64*16; i+=256){
        int r = i>>4, dq4 = (i&15)*4;
        int tok = base + r;
        float4 g4 = make_float4(0.f,0.f,0.f,0.f);
        if (tok < nTok){
            float4 a = *(const float4*)(yslot + (size_t)tok*128 + dq4);
            float4 b = *(const float4*)(yslot + (size_t)tok*128 + 64 + dq4);
            g4.x = geluf(a.x+b.x); g4.y = geluf(a.y+b.y);
            g4.z = geluf(a.z+b.z); g4.w = geluf(a.w+b.w);
        }
        *(uint2*)&gs[r][dq4] = pack4bf(g4.x, g4.y, g4.z, g4.w);
    }
    __syncthreads();

    const int w    = tid >> 6;
    const int lane = tid & 63;
    const int lq   = lane & 15;
    const int lg   = lane >> 4;
    constexpr int NC = NPROJ/64;
    const int colbase = w*16*NC;

    bf16x8_t wf[NC][2];
    #pragma unroll
    for (int cb=0; cb<NC; ++cb)
        #pragma unroll
        for (int ks=0; ks<2; ++ks)
            wf[cb][ks] = *reinterpret_cast<const bf16x8_t*>(
                pwT + (size_t)(colbase + cb*16 + lq)*DD + ks*32 + lg*8);

    f32x4 acc[4][NC] = {};
    #pragma unroll
    for (int m=0; m<4; ++m){
        #pragma unroll
        for (int ks=0; ks<2; ++ks){
            bf16x8_t af = *reinterpret_cast<const bf16x8_t*>(&gs[m*16+lq][ks*32+lg*8]);
            #pragma unroll
            for (int cb=0; cb<NC; ++cb)
                acc[m][cb] = __builtin_amdgcn_mfma_f32_16x16x32_bf16(af, wf[cb][ks], acc[m][cb], 0, 0, 0);
        }
    }
    #pragma unroll
    for (int m=0; m<4; ++m){
        #pragma unroll
        for (int r=0; r<4; ++r){
            int tok = base + m*16 + lg*4 + r;
            if (tok >= nTok) continue;
            #pragma unroll
            for (int cb=0; cb<NC; ++cb){
                int j = colbase + cb*16 + lq;
                float v = acc[m][cb][r] + pbg[j];
                int bufi = j >> 6, jd = j & 63;
                float* dst = (bufi==0) ? out0 : (bufi==1) ? out1 : out2;
                dst[(size_t)tok*DD + jd] = v;
            }
        }
    }
}

__global__ __launch_bounds__(256) void moe_proj_kernel(
    const float* __restrict__ yslotM, const unsigned short* __restrict__ mpwT,
    const float* __restrict__ mpb,
    float* __restrict__ qB, float* __restrict__ kmB, float* __restrict__ vmB,
    const float* __restrict__ yslotT, const unsigned short* __restrict__ cpwT,
    const float* __restrict__ cpb,
    float* __restrict__ ktB, float* __restrict__ vtB)
{
    __shared__ __align__(16) unsigned short gs[64][72];
    if (blockIdx.x < PROJB_M){
        proj_body<192>(yslotM, mpwT, mpb, NTOK_M, blockIdx.x*64, qB, kmB, vmB, gs);
    } else {
        proj_body<128>(yslotT, cpwT, cpb, NTOK_T, (blockIdx.x-PROJB_M)*64, ktB, vtB, nullptr, gs);
    }
}

// ======== MFMA flash attention (split-s = 4): block = (b,h,64-row t-tile, split) ========
__global__ __launch_bounds__(256) void attn_kernel(
    const float* __restrict__ qb,
    const float* __restrict__ kmb,
    const float* __restrict__ vmb,
    const float* __restrict__ ktb,
    const float* __restrict__ vtb,
    const float* __restrict__ kd,   // (NDS,48,H,64) -> [0]
    const float* __restrict__ vd,
    const float* __restrict__ kr,   // (48,H,64)
    const float* __restrict__ vr,
    const int*   __restrict__ smask, // (B,T)
    const float* __restrict__ tcond, // (B,1)
    const float* __restrict__ kms_p, const float* __restrict__ kds_p,
    const float* __restrict__ krs_p, const float* __restrict__ kts_p,
    const float* __restrict__ sigma_p,
    float* __restrict__ po,          // (NSPLIT, NROWS, 64)
    float* __restrict__ pm,          // (NSPLIT, NROWS)
    float* __restrict__ pl)          // (NSPLIT, NROWS)
{
    __shared__ __align__(16) unsigned short Ks[64][72];
    __shared__ __align__(16) unsigned short Vt[64][72];
    __shared__ __align__(16) unsigned short Pl[4][16][72];
    __shared__ float madd[64];

    const int tid  = threadIdx.x;
    const int w    = tid >> 6;
    const int lane = tid & 63;
    const int lq   = lane & 15;
    const int lg   = lane >> 4;

    const int bid   = blockIdx.x;
    const int split = blockIdx.y;
    const int ch_lo = split*3;
    const int ch_hi = min(ch_lo + 3, NCH);
    const int ttile = bid & 7;
    const int bh    = bid >> 3;
    const int b = bh / HH, h = bh % HH;
    const int t0 = ttile * 64;

    const float sc = 0.125f;
    const float kms = kms_p[0]*sc, kds = kds_p[0]*sc, krs = krs_p[0]*sc, kts = kts_p[0]*sc;
    const float sg = sigma_p[0];
    const float inv2s = 1.0f/(2.0f*sg*sg);
    const bool text_on = tcond[b] > 0.f;

    bf16x8_t qf[2];
    {
        const float* qrow = qb + ((size_t)(b*TT + t0 + w*16 + lq)*HH + h)*DD;
        #pragma unroll
        for (int ks=0; ks<2; ++ks){
            float4 v0 = *(const float4*)(qrow + ks*32 + lg*8);
            float4 v1 = *(const float4*)(qrow + ks*32 + lg*8 + 4);
            u16x8 qt;
            qt[0]=f2bf(v0.x); qt[1]=f2bf(v0.y); qt[2]=f2bf(v0.z); qt[3]=f2bf(v0.w);
            qt[4]=f2bf(v1.x); qt[5]=f2bf(v1.y); qt[6]=f2bf(v1.z); qt[7]=f2bf(v1.w);
            qf[ks] = __builtin_bit_cast(bf16x8_t, qt);
        }
    }

    float m_r = -1e30f, l_r = 0.f;
    f32x4 oacc[4] = {};

    const int tgq = t0 + w*16 + lq;

    for (int ch=ch_lo; ch<ch_hi; ++ch){
        __syncthreads();
        for (int i=tid; i<64*16; i+=256){
            int r = i>>4, dq4 = (i&15)*4;
            int s = ch*64 + r;
            float4 kv = make_float4(0,0,0,0), vv = make_float4(0,0,0,0);
            if (s < TT){
                size_t o = ((size_t)(b*TT + s)*HH + h)*DD + dq4;
                kv = *(const float4*)(&kmb[o]);
                kv.x*=kms; kv.y*=kms; kv.z*=kms; kv.w*=kms;
                vv = *(const float4*)(&vmb[o]);
            } else if (s < TT+48){
                kv = *(const float4*)(&kd[((size_t)(s-TT)*HH + h)*DD + dq4]);
                kv.x*=kds; kv.y*=kds; kv.z*=kds; kv.w*=kds;
                vv = *(const float4*)(&vd[((size_t)(s-TT)*HH + h)*DD + dq4]);
            } else if (s < TT+96){
                kv = *(const float4*)(&kr[((size_t)(s-TT-48)*HH + h)*DD + dq4]);
                kv.x*=krs; kv.y*=krs; kv.z*=krs; kv.w*=krs;
                vv = *(const float4*)(&vr[((size_t)(s-TT-48)*HH + h)*DD + dq4]);
            } else if (s < NS){
                size_t o = ((size_t)(b*MM + (s-TT-96))*HH + h)*DD + dq4;
                kv = *(const float4*)(&ktb[o]);
                kv.x*=kts; kv.y*=kts; kv.z*=kts; kv.w*=kts;
                vv = *(const float4*)(&vtb[o]);
            }
            *(uint2*)&Ks[r][dq4] = pack4bf(kv.x, kv.y, kv.z, kv.w);
            int swcol = r ^ (((i&15)&7)<<3);
            Vt[dq4+0][swcol] = f2bf(vv.x);
            Vt[dq4+1][swcol] = f2bf(vv.y);
            Vt[dq4+2][swcol] = f2bf(vv.z);
            Vt[dq4+3][swcol] = f2bf(vv.w);
        }
        if (tid < 64){
            int s = ch*64 + tid;
            float a;
            if (s < TT)            a = (smask[b*TT + s] == 0) ? -1e9f : 0.f;
            else if (s < TT+96)    a = 0.f;
            else if (s < NS)       a = text_on ? 0.f : -1e9f;
            else                   a = -1e30f;
            madd[tid] = a;
        }
        __syncthreads();

        f32x4 sacc[4] = {};
        #pragma unroll
        for (int sl=0; sl<4; ++sl){
            #pragma unroll
            for (int ks=0; ks<2; ++ks){
                bf16x8_t kf = *reinterpret_cast<const bf16x8_t*>(&Ks[sl*16 + lq][ks*32 + lg*8]);
                sacc[sl] = __builtin_amdgcn_mfma_f32_16x16x32_bf16(kf, qf[ks], sacc[sl], 0, 0, 0);
            }
        }
        float sv[4][4];
        float pmax = -1e30f;
        #pragma unroll
        for (int sl=0; sl<4; ++sl){
            #pragma unroll
            for (int r=0; r<4; ++r){
                int s_loc = sl*16 + lg*4 + r;
                float a = madd[s_loc];
                if (ch < 8){ float dt = (float)(tgq - (ch*64 + s_loc)); a -= dt*dt*inv2s; }
                float v = sacc[sl][r] + a;
                sv[sl][r] = v;
                pmax = fmaxf(pmax, v);
            }
        }
        pmax = fmaxf(pmax, __shfl_xor(pmax, 16));
        pmax = fmaxf(pmax, __shfl_xor(pmax, 32));
        float mn  = fmaxf(m_r, pmax);
        float scl = __expf(m_r - mn);
        m_r = mn;
        float psum = 0.f;
        #pragma unroll
        for (int sl=0; sl<4; ++sl){
            #pragma unroll
            for (int r=0; r<4; ++r){
                float p = __expf(sv[sl][r] - mn);
                sv[sl][r] = p;
                psum += p;
            }
        }
        psum += __shfl_xor(psum, 16);
        psum += __shfl_xor(psum, 32);
        l_r = l_r*scl + psum;
        #pragma unroll
        for (int sl=0; sl<4; ++sl)
            *(uint2*)&Pl[w][lq][sl*16 + lg*4] = pack4bf(sv[sl][0], sv[sl][1], sv[sl][2], sv[sl][3]);

        #pragma unroll
        for (int r=0; r<4; ++r){
            float so = __shfl(scl, lg*4 + r);
            #pragma unroll
            for (int ds_=0; ds_<4; ++ds_) oacc[ds_][r] *= so;
        }
        #pragma unroll
        for (int ds_=0; ds_<4; ++ds_){
            int dcol = ds_*16 + lq;
            int swz = (((dcol>>2)&7)<<3);
            #pragma unroll
            for (int ks=0; ks<2; ++ks){
                bf16x8_t pf = *reinterpret_cast<const bf16x8_t*>(&Pl[w][lq][ks*32 + lg*8]);
                bf16x8_t vf = *reinterpret_cast<const bf16x8_t*>(&Vt[dcol][(ks*32 + lg*8) ^ swz]);
                oacc[ds_] = __builtin_amdgcn_mfma_f32_16x16x32_bf16(pf, vf, oacc[ds_], 0, 0, 0);
            }
        }
    }
    #pragma unroll
    for (int r=0; r<4; ++r){
        int t = t0 + w*16 + lg*4 + r;
        size_t off = (size_t)split*NROWS + (size_t)bh*TT + t;
        #pragma unroll
        for (int ds_=0; ds_<4; ++ds_)
            po[off*64 + ds_*16 + lq] = oacc[ds_][r];
    }
    if (lg == 0){
        size_t off = (size_t)split*NROWS + (size_t)bh*TT + (t0 + w*16 + lq);
        pm[off] = m_r;
        pl[off] = l_r;
    }
}

// ======== bf16 MFMA GEMM: C = A(or bf16 A) @ W + bias (+res). Wt bf16 [N][K] ========
template<bool A_BF16>
__global__ __launch_bounds__(256) void gemm_mfma_kernel(
    const void* __restrict__ Ap, const unsigned short* __restrict__ Wt,
    const float* __restrict__ bias, const float* __restrict__ res,
    float* __restrict__ C, int Mr, int Nr, int Kr)
{
    __shared__ __align__(16) unsigned short As[32][40];
    __shared__ __align__(16) unsigned short Bs[64][40];
    int tid = threadIdx.x;
    int row0 = blockIdx.x*32, col0 = blockIdx.y*64;
    int wave = tid >> 6, lane = tid & 63;
    int lr = lane & 15, lk = lane >> 4;

    f32x4 acc[2] = {};

    for (int k0 = 0; k0 < Kr; k0 += 32){
        __syncthreads();
        {
            int r = tid >> 3, kq = tid & 7;
            if (A_BF16){
                const unsigned short* A = (const unsigned short*)Ap;
                *(uint2*)&As[r][kq*4] = *(const uint2*)(A + (size_t)(row0 + r)*Kr + k0 + kq*4);
            } else {
                const float* A = (const float*)Ap;
                float4 v = *(const float4*)(A + (size_t)(row0 + r)*Kr + k0 + kq*4);
                *(uint2*)&As[r][kq*4] = pack4bf(v.x, v.y, v.z, v.w);
            }
        }
        {
            int n = tid >> 2, oq = tid & 3;
            *(uint4*)&Bs[n][oq*8] = *(const uint4*)(Wt + (size_t)(col0+n)*Kr + k0 + oq*8);
        }
        __syncthreads();
        bf16x8_t a0 = *reinterpret_cast<const bf16x8_t*>(&As[lr][lk*8]);
        bf16x8_t a1 = *reinterpret_cast<const bf16x8_t*>(&As[16 + lr][lk*8]);
        bf16x8_t bfr = *reinterpret_cast<const bf16x8_t*>(&Bs[wave*16 + lr][lk*8]);
        acc[0] = __builtin_amdgcn_mfma_f32_16x16x32_bf16(a0, bfr, acc[0], 0, 0, 0);
        acc[1] = __builtin_amdgcn_mfma_f32_16x16x32_bf16(a1, bfr, acc[1], 0, 0, 0);
    }
    int gc = col0 + wave*16 + lr;
    float bv = bias[gc];
    #pragma unroll
    for (int m=0;m<2;++m){
        #pragma unroll
        for (int r=0;r<4;++r){
            int gr = row0 + m*16 + lk*4 + r;
            float v = acc[m][r] + bv;
            size_t off = (size_t)gr*Nr + gc;
            if (res) v += res[off];
            C[off] = v;
        }
    }
}

// ======== fused 4-split combine + modulated LN + silu ========
__global__ __launch_bounds__(256) void lnmod_combine_kernel(
    const float* __restrict__ po, const float* __restrict__ pm, const float* __restrict__ pl,
    const float* __restrict__ g, const float* __restrict__ bb,
    const float* __restrict__ eo, float* __restrict__ out)
{
    int row = blockIdx.x, tid = threadIdx.x;
    int b = row / TT, t = row % TT;
    __shared__ float xsr[LATD];
    __shared__ float red[256];
    float s = 0.f;
    for (int i=tid;i<LATD;i+=256){
        int h = i >> 6, d = i & 63;
        size_t rowid = ((size_t)(b*HH + h))*TT + t;
        float m = -1e30f;
        #pragma unroll
        for (int k=0;k<NSPLIT;++k) m = fmaxf(m, pm[(size_t)k*NROWS + rowid]);
        float lsum = 0.f, acc = 0.f;
        #pragma unroll
        for (int k=0;k<NSPLIT;++k){
            float sk = __expf(pm[(size_t)k*NROWS + rowid] - m);
            lsum += pl[(size_t)k*NROWS + rowid]*sk;
            acc  += po[((size_t)k*NROWS + rowid)*64 + d]*sk;
        }
        float v = acc / lsum;
        xsr[i] = v; s += v;
    }
    red[tid]=s; __syncthreads();
    for (int k=128;k>0;k>>=1){ if (tid<k) red[tid]+=red[tid+k]; __syncthreads(); }
    float mean = red[0]*(1.0f/LATD);
    __syncthreads();
    float vs=0.f;
    for (int i=tid;i<LATD;i+=256){ float d=xsr[i]-mean; vs+=d*d; }
    red[tid]=vs; __syncthreads();
    for (int k=128;k>0;k>>=1){ if (tid<k) red[tid]+=red[tid+k]; __syncthreads(); }
    float rstd = rsqrtf(red[0]*(1.0f/LATD)+1e-5f);
    const float* ep = eo + (size_t)row*(2*LATD);
    float* op = out + (size_t)row*LATD;
    for (int i=tid;i<LATD;i+=256){
        float v = (xsr[i]-mean)*rstd*g[i] + bb[i];
        v = v*(1.0f + ep[i]) + ep[LATD+i];
        op[i] = siluf(v);
    }
}

extern "C" void kernel_launch(void* const* d_in, const int* in_sizes, int n_in,
                              void* d_out, int out_size, void* d_ws, size_t ws_size,
                              hipStream_t stream)
{
    (void)in_sizes; (void)n_in; (void)out_size; (void)ws_size;
    const float* x     = (const float*)d_in[0];
    const float* emb   = (const float*)d_in[1];
    const int*   smask = (const int*)d_in[2];
    const float* tcond = (const float*)d_in[5];
    const float* two   = (const float*)d_in[6];
    const float* ng    = (const float*)d_in[7];
    const float* nb    = (const float*)d_in[8];
    const float* memb  = (const float*)d_in[9];
    const float* m_wg  = (const float*)d_in[10];
    const float* m_w1  = (const float*)d_in[11];
    const float* m_b1  = (const float*)d_in[12];
    const float* m_w2  = (const float*)d_in[13];
    const float* m_b2  = (const float*)d_in[14];
    const float* m_pw  = (const float*)d_in[15];
    const float* m_pb  = (const float*)d_in[16];
    const float* kms   = (const float*)d_in[17];
    const float* sigma = (const float*)d_in[18];
    const float* kdat  = (const float*)d_in[19];
    const float* kds   = (const float*)d_in[20];
    const float* vdat  = (const float*)d_in[21];
    const float* krot  = (const float*)d_in[22];
    const float* krs   = (const float*)d_in[23];
    const float* vrot  = (const float*)d_in[24];
    const float* ntg   = (const float*)d_in[25];
    const float* ntb   = (const float*)d_in[26];
    const float* c_wg  = (const float*)d_in[27];
    const float* c_w1  = (const float*)d_in[28];
    const float* c_b1  = (const float*)d_in[29];
    const float* c_w2  = (const float*)d_in[30];
    const float* c_b2  = (const float*)d_in[31];
    const float* c_pw  = (const float*)d_in[32];
    const float* c_pb  = (const float*)d_in[33];
    const float* kts   = (const float*)d_in[34];
    const float* st_ew = (const float*)d_in[35];
    const float* st_eb = (const float*)d_in[36];
    const float* st_ng = (const float*)d_in[37];
    const float* st_nb = (const float*)d_in[38];
    const float* st_ow = (const float*)d_in[39];
    const float* st_ob = (const float*)d_in[40];

    float* ws = (float*)d_ws;
    float* xh   = ws;                    // 1310720
    float* qB   = xh  + 1310720;         // (B,T,H,64) token-major
    float* kmB  = qB  + 1310720;
    float* vmB  = kmB + 1310720;
    float* ctB  = vmB + 1310720;         // 197120
    float* ktB  = ctB + 197120;          // (B,M,H,64)
    float* vtB  = ktB + 197120;
    float* aout = vtB + 197120;          // 1310720 (routing scratch only)
    float* eoB  = aout + 1310720;        // 2621440
    float* shB  = eoB + 2621440;         // 1310720

    // pre-transposed bf16 weights (persist whole launch)
    unsigned short* w1Tm = (unsigned short*)(shB + 1310720);
    unsigned short* w2Tm = w1Tm + EE*FFND*DD;
    unsigned short* w1Tt = w2Tm + EE*FFND*DD;
    unsigned short* w2Tt = w1Tt + EE*FFND*DD;
    unsigned short* stewT = w2Tt + EE*FFND*DD;
    unsigned short* stowT = stewT + 512*1280;
    unsigned short* mpwT  = stowT + 640*640;
    unsigned short* cpwT  = mpwT + 320*64;
    unsigned short* embBf = cpwT + 128*64;       // 2048*512 bf16
    float* poB = (float*)(embBf + 2048*512);     // NSPLIT*NROWS*64
    float* pmB = poB + (size_t)NSPLIT*NROWS*64;
    float* plB = pmB + (size_t)NSPLIT*NROWS;

    float* yslotM = eoB;
    float* yslotT = shB;
    float* wAm   = aout;
    float* wAt   = wAm + NTOK_M*2;
    int*   cntA  = (int*)(wAt + NTOK_T*2);
    int*   listM = cntA + 16;
    int*   listT = listM + EE*NTOK_M;

    prep_ln_kernel<<<651 + BB*TT + BB*MM, 256, 0, stream>>>(
        m_w1, w1Tm, m_w2, w2Tm, c_w1, w1Tt, c_w2, w2Tt,
        st_ew, stewT, st_ow, stowT, m_pw, mpwT, c_pw, cpwT,
        emb, embBf, cntA,
        x, ng, nb, memb, xh, two, ntg, ntb, ctB);

    route_kernel<<<ROUTEB_M + ROUTEB_T, 256, 0, stream>>>(
        xh, m_wg, cntA, listM, wAm,
        ctB, c_wg, cntA+8, listT, wAt);

    moe_ffn_kernel<<<MAXB_M + MAXB_T, 256, 0, stream>>>(
        xh, w1Tm, m_b1, w2Tm, m_b2, cntA, listM, wAm, yslotM,
        ctB, w1Tt, c_b1, w2Tt, c_b2, cntA+8, listT, wAt, yslotT);

    moe_proj_kernel<<<PROJB_M + PROJB_T, 256, 0, stream>>>(
        yslotM, mpwT, m_pb, qB, kmB, vmB,
        yslotT, cpwT, c_pb, ktB, vtB);

    {
        dim3 ga(BB*HH*8, NSPLIT);
        attn_kernel<<<ga, 256, 0, stream>>>(
            qB, kmB, vmB, ktB, vtB, kdat, vdat, krot, vrot, smask, tcond,
            kms, kds, krs, kts, sigma, poB, pmB, plB);
    }
    {
        dim3 g1(2048/32, 1280/64);
        gemm_mfma_kernel<true><<<g1, 256, 0, stream>>>(embBf, stewT, st_eb, nullptr, eoB, 2048, 1280, 512);
    }
    lnmod_combine_kernel<<<BB*TT, 256, 0, stream>>>(
        poB, pmB, plB, st_ng, st_nb, eoB, shB);
    {
        dim3 g2(2048/32, 640/64);
        gemm_mfma_kernel<false><<<g2, 256, 0, stream>>>(shB, stowT, st_ob, x, (float*)d_out, 2048, 640, 640);
    }
}

// Round 13
// 112.570 us; speedup vs baseline: 1.8128x; 1.0760x over previous
//
#include <hip/hip_runtime.h>
#include <math.h>

#define BB 4
#define TT 512
#define MM 77
#define HH 10
#define DD 64
#define LATD 640
#define EE 8
#define FFND 256
#define NS 685     // 512 + 48 + 48 + 77
#define NCH 11     // ceil(685/64)
#define NROWS 20480
#define NSPLIT 4

#define NTOK_M (BB*TT*HH)   // 20480
#define NTOK_T (BB*MM*HH)   // 3080
#define MAXB_M 647
#define MAXB_T 103
#define PROJB_M 320
#define PROJB_T 49
#define ROUTEB_M 80
#define ROUTEB_T 13
#define ATTNB (BB*HH*8*NSPLIT)   // 1280
#define GEMM1B 1280              // (2048/32)*(1280/64)

typedef float f32x4 __attribute__((ext_vector_type(4)));
typedef __bf16 bf16x8_t __attribute__((ext_vector_type(8)));
typedef unsigned short u16x8 __attribute__((ext_vector_type(8)));

__device__ __forceinline__ float geluf(float x){
    float u = 0.7978845608028654f*(x + 0.044715f*x*x*x);
    u = fminf(fmaxf(u, -15.f), 15.f);
    float e = __expf(2.f*u);
    return 0.5f*x*(1.f + (e-1.f)/(e+1.f));
}
__device__ __forceinline__ float siluf(float x){
    return x / (1.0f + __expf(-x));
}
__device__ __forceinline__ unsigned short f2bf(float f){
    unsigned int u = __float_as_uint(f);
    u += 0x7fff + ((u >> 16) & 1);
    return (unsigned short)(u >> 16);
}
__device__ __forceinline__ uint2 pack4bf(float a, float b, float c, float d){
    uint2 r;
    r.x = (unsigned)f2bf(a) | ((unsigned)f2bf(b)<<16);
    r.y = (unsigned)f2bf(c) | ((unsigned)f2bf(d)<<16);
    return r;
}

// ======== fused prep + LN ========
__global__ __launch_bounds__(256) void prep_ln_kernel(
    const float* __restrict__ m_w1, unsigned short* __restrict__ w1Tm,
    const float* __restrict__ m_w2, unsigned short* __restrict__ w2Tm,
    const float* __restrict__ c_w1, unsigned short* __restrict__ w1Tt,
    const float* __restrict__ c_w2, unsigned short* __restrict__ w2Tt,
    const float* __restrict__ st_ew, unsigned short* __restrict__ stewT,
    const float* __restrict__ st_ow, unsigned short* __restrict__ stowT,
    const float* __restrict__ m_pw, unsigned short* __restrict__ mpwT,
    const float* __restrict__ c_pw, unsigned short* __restrict__ cpwT,
    const float* __restrict__ emb, unsigned short* __restrict__ embBf,
    int* __restrict__ cnt,
    const float* __restrict__ x, const float* __restrict__ ng, const float* __restrict__ nb,
    const float* __restrict__ memb, float* __restrict__ xh,
    const float* __restrict__ two, const float* __restrict__ ntg, const float* __restrict__ ntb,
    float* __restrict__ ctB)
{
    __shared__ float buf[64*65];
    const int bid = blockIdx.x, tid = threadIdx.x;
    if (bid >= 651){
        int lrow = bid - 651;
        const float* in; const float* g; const float* bb; const float* ap; float* out;
        int row;
        if (lrow < BB*TT){
            row = lrow; in = x; g = ng; bb = nb; out = xh;
            ap = memb + (size_t)(row % TT)*LATD;
        } else {
            row = lrow - BB*TT; in = two; g = ntg; bb = ntb; out = ctB;
            ap = nullptr;
        }
        float* xsr = buf;
        float* red = buf + LATD;
        const float* rp = in + (size_t)row*LATD;
        float s = 0.f;
        for (int i=tid;i<LATD;i+=256){ float v = rp[i]; xsr[i]=v; s+=v; }
        red[tid]=s; __syncthreads();
        for (int k=128;k>0;k>>=1){ if (tid<k) red[tid]+=red[tid+k]; __syncthreads(); }
        float mean = red[0]*(1.0f/LATD);
        __syncthreads();
        float vs=0.f;
        for (int i=tid;i<LATD;i+=256){ float d=xsr[i]-mean; vs+=d*d; }
        red[tid]=vs; __syncthreads();
        for (int k=128;k>0;k>>=1){ if (tid<k) red[tid]+=red[tid+k]; __syncthreads(); }
        float rstd = rsqrtf(red[0]*(1.0f/LATD)+1e-5f);
        float* op = out + (size_t)row*LATD;
        for (int i=tid;i<LATD;i+=256){
            float v = (xsr[i]-mean)*rstd*g[i] + bb[i];
            if (ap) v += ap[i];
            op[i] = v;
        }
        return;
    }
    if (bid >= 395){
        int l = bid - 395;
        if (l == 0 && tid < 16) cnt[tid] = 0;
        size_t base = (size_t)l*4096;
        #pragma unroll
        for (int p=0; p<4; ++p){
            size_t i = base + (size_t)p*1024 + tid*4;
            float4 v = *(const float4*)(emb + i);
            *(uint2*)(embBf + i) = pack4bf(siluf(v.x), siluf(v.y), siluf(v.z), siluf(v.w));
        }
        return;
    }
    float (*t)[65] = (float(*)[65])buf;
    const float* in; unsigned short* out; int R, C, z, rt, ct;
    if (bid < 32)      { int l=bid;     in=m_w1;  out=w1Tm;  R=64;  C=256;  z=l>>2; rt=0;    ct=l&3; }
    else if (bid < 64) { int l=bid-32;  in=m_w2;  out=w2Tm;  R=256; C=64;   z=l>>2; rt=l&3;  ct=0; }
    else if (bid < 96) { int l=bid-64;  in=c_w1;  out=w1Tt;  R=64;  C=256;  z=l>>2; rt=0;    ct=l&3; }
    else if (bid < 128){ int l=bid-96;  in=c_w2;  out=w2Tt;  R=256; C=64;   z=l>>2; rt=l&3;  ct=0; }
    else if (bid < 288){ int l=bid-128; in=st_ew; out=stewT; R=512; C=1280; z=0;    rt=l/20; ct=l%20; }
    else if (bid < 388){ int l=bid-288; in=st_ow; out=stowT; R=640; C=640;  z=0;    rt=l/10; ct=l%10; }
    else if (bid < 393){ int l=bid-388; in=m_pw;  out=mpwT;  R=64;  C=320;  z=0;    rt=0;    ct=l; }
    else               { int l=bid-393; in=c_pw;  out=cpwT;  R=64;  C=128;  z=0;    rt=0;    ct=l; }
    const size_t base = (size_t)z*R*C;
    const int r0 = rt*64, c0 = ct*64;
    #pragma unroll
    for (int p=0; p<16; ++p){
        int i = tid + p*256;
        int r = i>>6, c = i&63;
        t[r][c] = in[base + (size_t)(r0+r)*C + c0 + c];
    }
    __syncthreads();
    #pragma unroll
    for (int p=0; p<16; ++p){
        int i = tid + p*256;
        int c = i>>6, r = i&63;
        out[base + (size_t)(c0+c)*R + r0 + r] = f2bf(t[r][c]);
    }
}

// ======== MoE routing, M+T merged ========
__global__ __launch_bounds__(256) void route_kernel(
    const float* __restrict__ xinM, const float* __restrict__ wgM,
    int* __restrict__ countsM, int* __restrict__ listM, float* __restrict__ wAM,
    const float* __restrict__ xinT, const float* __restrict__ wgT,
    int* __restrict__ countsT, int* __restrict__ listT, float* __restrict__ wAT)
{
    __shared__ int bcnt[EE];
    __shared__ int bbase[EE];
    const int tid = threadIdx.x;
    const int bid = blockIdx.x;
    const float* xin; const float* wg; int* counts; int* list; float* wA; int nTok, t;
    if (bid < ROUTEB_M){
        xin = xinM; wg = wgM; counts = countsM; list = listM; wA = wAM; nTok = NTOK_M;
        t = bid*256 + tid;
    } else {
        xin = xinT; wg = wgT; counts = countsT; list = listT; wA = wAT; nTok = NTOK_T;
        t = (bid - ROUTEB_M)*256 + tid;
    }
    if (tid < EE) bcnt[tid] = 0;
    __syncthreads();

    int e0 = 0, e1 = 0, p0 = 0, p1 = 0;
    bool act = (t < nTok);
    if (act){
        float lg[EE];
        #pragma unroll
        for (int e=0;e<EE;e++) lg[e]=0.f;
        const float4* xp = (const float4*)(xin + (size_t)t*DD);
        #pragma unroll 4
        for (int dq=0; dq<16; ++dq){
            float4 xv = xp[dq];
            const float* w0 = wg + (dq*4+0)*EE;
            const float* w1 = wg + (dq*4+1)*EE;
            const float* w2 = wg + (dq*4+2)*EE;
            const float* w3 = wg + (dq*4+3)*EE;
            #pragma unroll
            for (int e=0;e<EE;e++)
                lg[e] += xv.x*w0[e] + xv.y*w1[e] + xv.z*w2[e] + xv.w*w3[e];
        }
        float mx = lg[0];
        #pragma unroll
        for (int e=1;e<EE;e++) mx = fmaxf(mx, lg[e]);
        float sum = 0.f;
        #pragma unroll
        for (int e=0;e<EE;e++){ lg[e] = __expf(lg[e]-mx); sum += lg[e]; }
        float inv = 1.0f/sum;
        #pragma unroll
        for (int e=0;e<EE;e++) lg[e] *= inv;
        float v0=lg[0];
        #pragma unroll
        for (int e=1;e<EE;e++){ if (lg[e] > v0){ v0 = lg[e]; e0 = e; } }
        float v1=-1e30f; e1 = (e0==0) ? 1 : 0;
        #pragma unroll
        for (int e=0;e<EE;e++){ if (e==e0) continue; if (lg[e] > v1){ v1 = lg[e]; e1 = e; } }
        wA[t*2+0]=v0; wA[t*2+1]=v1;
        p0 = atomicAdd(&bcnt[e0], 1);
        p1 = atomicAdd(&bcnt[e1], 1);
    }
    __syncthreads();
    if (tid < EE){
        bbase[tid] = (bcnt[tid] > 0) ? atomicAdd(&counts[tid], bcnt[tid]) : 0;
    }
    __syncthreads();
    if (act){
        list[(size_t)e0*nTok + bbase[e0] + p0] = t*2;
        list[(size_t)e1*nTok + bbase[e1] + p1] = t*2+1;
    }
}

// ======== grouped expert FFN (MFMA), M+T merged ========
__global__ __launch_bounds__(256) void moe_ffn_kernel(
    const float* __restrict__ xinM, const unsigned short* __restrict__ w1TM,
    const float* __restrict__ b1M, const unsigned short* __restrict__ w2TM,
    const float* __restrict__ b2M, const int* __restrict__ countsM,
    const int* __restrict__ listM, const float* __restrict__ wAM,
    float* __restrict__ yslotM,
    const float* __restrict__ xinT, const unsigned short* __restrict__ w1TT,
    const float* __restrict__ b1T, const unsigned short* __restrict__ w2TT,
    const float* __restrict__ b2T, const int* __restrict__ countsT,
    const int* __restrict__ listT, const float* __restrict__ wAT,
    float* __restrict__ yslotT)
{
    __shared__ __align__(16) unsigned short xs[64][72];
    __shared__ __align__(16) unsigned short w1s[64][72];
    __shared__ __align__(16) unsigned short w2s[64][72];
    __shared__ __align__(16) unsigned short hs[64][72];
    __shared__ int sCnt[EE];
    __shared__ int encs[64];
    __shared__ float wgts[64];
    const int tid = threadIdx.x;
    const float* xin; const unsigned short* w1T; const float* b1g;
    const unsigned short* w2T; const float* b2g; const int* counts;
    const int* list; const float* wA; float* yslot; int nTok, bidl;
    if (blockIdx.x < MAXB_M){
        xin=xinM; w1T=w1TM; b1g=b1M; w2T=w2TM; b2g=b2M; counts=countsM;
        list=listM; wA=wAM; yslot=yslotM; nTok=NTOK_M; bidl=blockIdx.x;
    } else {
        xin=xinT; w1T=w1TT; b1g=b1T; w2T=w2TT; b2g=b2T; counts=countsT;
        list=listT; wA=wAT; yslot=yslotT; nTok=NTOK_T; bidl=blockIdx.x-MAXB_M;
    }
    if (tid < EE) sCnt[tid] = counts[tid];
    __syncthreads();
    int e = -1, tile = 0;
    {
        int acc = 0;
        #pragma unroll
        for (int i=0;i<EE;++i){
            int tc = (sCnt[i]+63)>>6;
            if (e < 0 && bidl < acc + tc){ e = i; tile = bidl - acc; }
            acc += tc;
        }
    }
    if (e < 0) return;
    const int cnt = sCnt[e];
    if (tid < 64){
        int idx = tile*64 + tid;
        int enc = (idx < cnt) ? list[(size_t)e*nTok + idx] : -1;
        encs[tid] = enc;
        wgts[tid] = (enc >= 0) ? wA[enc] : 0.f;
    }
    __syncthreads();
    for (int i=tid; i<64*16; i+=256){
        int r = i>>4, dq4 = (i&15)*4;
        int enc = encs[r];
        float4 xv = make_float4(0.f,0.f,0.f,0.f);
        if (enc >= 0) xv = *(const float4*)(xin + (size_t)(enc>>1)*DD + dq4);
        *(uint2*)&xs[r][dq4] = pack4bf(xv.x, xv.y, xv.z, xv.w);
    }

    const int w    = tid >> 6;
    const int lane = tid & 63;
    const int lq   = lane & 15;
    const int lg   = lane >> 4;

    const unsigned short* w1e = w1T + (size_t)e*FFND*DD;
    const unsigned short* w2e = w2T + (size_t)e*DD*FFND;

    f32x4 acc2[4] = {};

    for (int fc=0; fc<4; ++fc){
        __syncthreads();
        for (int i=tid; i<512; i+=256){
            int r = i>>3, jq = i&7;
            *(uint4*)&w1s[r][jq*8] = *(const uint4*)(w1e + (size_t)(fc*64+r)*DD + jq*8);
            *(uint4*)&w2s[r][jq*8] = *(const uint4*)(w2e + (size_t)r*FFND + fc*64 + jq*8);
        }
        __syncthreads();
        f32x4 acc1[4] = {};
        #pragma unroll
        for (int fb=0; fb<4; ++fb){
            #pragma unroll
            for (int ks=0; ks<2; ++ks){
                bf16x8_t xf = *reinterpret_cast<const bf16x8_t*>(&xs[w*16+lq][ks*32+lg*8]);
                bf16x8_t wf = *reinterpret_cast<const bf16x8_t*>(&w1s[fb*16+lq][ks*32+lg*8]);
                acc1[fb] = __builtin_amdgcn_mfma_f32_16x16x32_bf16(xf, wf, acc1[fb], 0, 0, 0);
            }
        }
        #pragma unroll
        for (int fb=0; fb<4; ++fb){
            float b1v = b1g[e*FFND + fc*64 + fb*16 + lq];
            #pragma unroll
            for (int r=0; r<4; ++r)
                hs[w*16 + lg*4 + r][fb*16 + lq] = f2bf(geluf(acc1[fb][r] + b1v));
        }
        #pragma unroll
        for (int db=0; db<4; ++db){
            #pragma unroll
            for (int ks=0; ks<2; ++ks){
                bf16x8_t hf  = *reinterpret_cast<const bf16x8_t*>(&hs[w*16+lq][ks*32+lg*8]);
                bf16x8_t w2f = *reinterpret_cast<const bf16x8_t*>(&w2s[db*16+lq][ks*32+lg*8]);
                acc2[db] = __builtin_amdgcn_mfma_f32_16x16x32_bf16(hf, w2f, acc2[db], 0, 0, 0);
            }
        }
    }
    #pragma unroll
    for (int r=0; r<4; ++r){
        int tok = w*16 + lg*4 + r;
        int enc = encs[tok];
        if (enc >= 0){
            float gw = wgts[tok];
            #pragma unroll
            for (int db=0; db<4; ++db){
                int d = db*16 + lq;
                yslot[(size_t)enc*DD + d] = gw*(acc2[db][r] + b2g[e*DD + d]);
            }
        }
    }
}

// ======== combine slots + gelu + MFMA projection, M+T merged ========
template<int NPROJ>
__device__ __forceinline__ void proj_body(
    const float* __restrict__ yslot, const unsigned short* __restrict__ pwT,
    const float* __restrict__ pbg, int nTok, int base,
    float* __restrict__ out0, float* __restrict__ out1, float* __restrict__ out2,
    unsigned short gs[64][72])
{
    const int tid = threadIdx.x;
    for (int i=tid; i<64*16; i+=256){
        int r = i>>4, dq4 = (i&15)*4;
        int tok = base + r;
        float4 g4 = make_float4(0.f,0.f,0.f,0.f);
        if (tok < nTok){
            float4 a = *(const float4*)(yslot + (size_t)tok*128 + dq4);
            float4 b = *(const float4*)(yslot + (size_t)tok*128 + 64 + dq4);
            g4.x = geluf(a.x+b.x); g4.y = geluf(a.y+b.y);
            g4.z = geluf(a.z+b.z); g4.w = geluf(a.w+b.w);
        }
        *(uint2*)&gs[r][dq4] = pack4bf(g4.x, g4.y, g4.z, g4.w);
    }
    __syncthreads();

    const int w    = tid >> 6;
    const int lane = tid & 63;
    const int lq   = lane & 15;
    const int lg   = lane >> 4;
    constexpr int NC = NPROJ/64;
    const int colbase = w*16*NC;

    bf16x8_t wf[NC][2];
    #pragma unroll
    for (int cb=0; cb<NC; ++cb)
        #pragma unroll
        for (int ks=0; ks<2; ++ks)
            wf[cb][ks] = *reinterpret_cast<const bf16x8_t*>(
                pwT + (size_t)(colbase + cb*16 + lq)*DD + ks*32 + lg*8);

    f32x4 acc[4][NC] = {};
    #pragma unroll
    for (int m=0; m<4; ++m){
        #pragma unroll
        for (int ks=0; ks<2; ++ks){
            bf16x8_t af = *reinterpret_cast<const bf16x8_t*>(&gs[m*16+lq][ks*32+lg*8]);
            #pragma unroll
            for (int cb=0; cb<NC; ++cb)
                acc[m][cb] = __builtin_amdgcn_mfma_f32_16x16x32_bf16(af, wf[cb][ks], acc[m][cb], 0, 0, 0);
        }
    }
    #pragma unroll
    for (int m=0; m<4; ++m){
        #pragma unroll
        for (int r=0; r<4; ++r){
            int tok = base + m*16 + lg*4 + r;
            if (tok >= nTok) continue;
            #pragma unroll
            for (int cb=0; cb<NC; ++cb){
                int j = colbase + cb*16 + lq;
                float v = acc[m][cb][r] + pbg[j];
                int bufi = j >> 6, jd = j & 63;
                float* dst = (bufi==0) ? out0 : (bufi==1) ? out1 : out2;
                dst[(size_t)tok*DD + jd] = v;
            }
        }
    }
}

__global__ __launch_bounds__(256) void moe_proj_kernel(
    const float* __restrict__ yslotM, const unsigned short* __restrict__ mpwT,
    const float* __restrict__ mpb,
    float* __restrict__ qB, float* __restrict__ kmB, float* __restrict__ vmB,
    const float* __restrict__ yslotT, const unsigned short* __restrict__ cpwT,
    const float* __restrict__ cpb,
    float* __restrict__ ktB, float* __restrict__ vtB)
{
    __shared__ __align__(16) unsigned short gs[64][72];
    if (blockIdx.x < PROJB_M){
        proj_body<192>(yslotM, mpwT, mpb, NTOK_M, blockIdx.x*64, qB, kmB, vmB, gs);
    } else {
        proj_body<128>(yslotT, cpwT, cpb, NTOK_T, (blockIdx.x-PROJB_M)*64, ktB, vtB, nullptr, gs);
    }
}

// ======== merged: MFMA flash attention (split-s=4) ∥ gemm1 (eo = embBf @ stewT + bias) ====
__global__ __launch_bounds__(256) void attn_gemm_kernel(
    const float* __restrict__ qb,
    const float* __restrict__ kmb,
    const float* __restrict__ vmb,
    const float* __restrict__ ktb,
    const float* __restrict__ vtb,
    const float* __restrict__ kd,
    const float* __restrict__ vd,
    const float* __restrict__ kr,
    const float* __restrict__ vr,
    const int*   __restrict__ smask,
    const float* __restrict__ tcond,
    const float* __restrict__ kms_p, const float* __restrict__ kds_p,
    const float* __restrict__ krs_p, const float* __restrict__ kts_p,
    const float* __restrict__ sigma_p,
    float* __restrict__ po, float* __restrict__ pm, float* __restrict__ pl,
    const unsigned short* __restrict__ gA,   // embBf (2048,512) bf16
    const unsigned short* __restrict__ gWt,  // stewT bf16 [1280][512]
    const float* __restrict__ gbias, float* __restrict__ gC)  // eoB (2048,1280)
{
    __shared__ __align__(16) unsigned char smem[27904];
    const int tid  = threadIdx.x;

    if (blockIdx.x >= ATTNB){
        // ---------------- gemm1 branch: eo = embBf @ stewT + bias ----------------
        const int gbid = blockIdx.x - ATTNB;
        unsigned short (*As)[40] = (unsigned short(*)[40])smem;              // 32*40*2 = 2560
        unsigned short (*Bs)[40] = (unsigned short(*)[40])(smem + 2560);     // 64*40*2 = 5120
        const int Nr = 1280, Kr = 512;
        const int row0 = (gbid & 63)*32, col0 = (gbid >> 6)*64;
        const int wave = tid >> 6, lane = tid & 63;
        const int lr = lane & 15, lk = lane >> 4;
        f32x4 acc[2] = {};
        for (int k0 = 0; k0 < Kr; k0 += 32){
            __syncthreads();
            {
                int r = tid >> 3, kq = tid & 7;
                *(uint2*)&As[r][kq*4] = *(const uint2*)(gA + (size_t)(row0 + r)*Kr + k0 + kq*4);
            }
            {
                int n = tid >> 2, oq = tid & 3;
                *(uint4*)&Bs[n][oq*8] = *(const uint4*)(gWt + (size_t)(col0+n)*Kr + k0 + oq*8);
            }
            __syncthreads();
            bf16x8_t a0 = *reinterpret_cast<const bf16x8_t*>(&As[lr][lk*8]);
            bf16x8_t a1 = *reinterpret_cast<const bf16x8_t*>(&As[16 + lr][lk*8]);
            bf16x8_t bfr = *reinterpret_cast<const bf16x8_t*>(&Bs[wave*16 + lr][lk*8]);
            acc[0] = __builtin_amdgcn_mfma_f32_16x16x32_bf16(a0, bfr, acc[0], 0, 0, 0);
            acc[1] = __builtin_amdgcn_mfma_f32_16x16x32_bf16(a1, bfr, acc[1], 0, 0, 0);
        }
        int gc = col0 + wave*16 + lr;
        float bv = gbias[gc];
        #pragma unroll
        for (int m=0;m<2;++m){
            #pragma unroll
            for (int r=0;r<4;++r){
                int gr = row0 + m*16 + lk*4 + r;
                gC[(size_t)gr*Nr + gc] = acc[m][r] + bv;
            }
        }
        return;
    }

    // ---------------- attention branch ----------------
    unsigned short (*Ks)[72] = (unsigned short(*)[72])smem;                   // 9216
    unsigned short (*Vt)[72] = (unsigned short(*)[72])(smem + 9216);          // 9216
    unsigned short (*Pl)[72] = (unsigned short(*)[72])(smem + 18432);         // 4*16*72*2 = 9216 -> [w*16+q][s]
    float* madd = (float*)(smem + 27648);                                     // 256

    const int w    = tid >> 6;
    const int lane = tid & 63;
    const int lq   = lane & 15;
    const int lg   = lane >> 4;

    const int split = blockIdx.x & 3;
    const int xb    = blockIdx.x >> 2;
    const int ch_lo = split*3;
    const int ch_hi = min(ch_lo + 3, NCH);
    const int ttile = xb & 7;
    const int bh    = xb >> 3;
    const int b = bh / HH, h = bh % HH;
    const int t0 = ttile * 64;

    const float sc = 0.125f;
    const float kms = kms_p[0]*sc, kds = kds_p[0]*sc, krs = krs_p[0]*sc, kts = kts_p[0]*sc;
    const float sg = sigma_p[0];
    const float inv2s = 1.0f/(2.0f*sg*sg);
    const bool text_on = tcond[b] > 0.f;

    bf16x8_t qf[2];
    {
        const float* qrow = qb + ((size_t)(b*TT + t0 + w*16 + lq)*HH + h)*DD;
        #pragma unroll
        for (int ks=0; ks<2; ++ks){
            float4 v0 = *(const float4*)(qrow + ks*32 + lg*8);
            float4 v1 = *(const float4*)(qrow + ks*32 + lg*8 + 4);
            u16x8 qt;
            qt[0]=f2bf(v0.x); qt[1]=f2bf(v0.y); qt[2]=f2bf(v0.z); qt[3]=f2bf(v0.w);
            qt[4]=f2bf(v1.x); qt[5]=f2bf(v1.y); qt[6]=f2bf(v1.z); qt[7]=f2bf(v1.w);
            qf[ks] = __builtin_bit_cast(bf16x8_t, qt);
        }
    }

    float m_r = -1e30f, l_r = 0.f;
    f32x4 oacc[4] = {};

    const int tgq = t0 + w*16 + lq;

    for (int ch=ch_lo; ch<ch_hi; ++ch){
        __syncthreads();
        for (int i=tid; i<64*16; i+=256){
            int r = i>>4, dq4 = (i&15)*4;
            int s = ch*64 + r;
            float4 kv = make_float4(0,0,0,0), vv = make_float4(0,0,0,0);
            if (s < TT){
                size_t o = ((size_t)(b*TT + s)*HH + h)*DD + dq4;
                kv = *(const float4*)(&kmb[o]);
                kv.x*=kms; kv.y*=kms; kv.z*=kms; kv.w*=kms;
                vv = *(const float4*)(&vmb[o]);
            } else if (s < TT+48){
                kv = *(const float4*)(&kd[((size_t)(s-TT)*HH + h)*DD + dq4]);
                kv.x*=kds; kv.y*=kds; kv.z*=kds; kv.w*=kds;
                vv = *(const float4*)(&vd[((size_t)(s-TT)*HH + h)*DD + dq4]);
            } else if (s < TT+96){
                kv = *(const float4*)(&kr[((size_t)(s-TT-48)*HH + h)*DD + dq4]);
                kv.x*=krs; kv.y*=krs; kv.z*=krs; kv.w*=krs;
                vv = *(const float4*)(&vr[((size_t)(s-TT-48)*HH + h)*DD + dq4]);
            } else if (s < NS){
                size_t o = ((size_t)(b*MM + (s-TT-96))*HH + h)*DD + dq4;
                kv = *(const float4*)(&ktb[o]);
                kv.x*=kts; kv.y*=kts; kv.z*=kts; kv.w*=kts;
                vv = *(const float4*)(&vtb[o]);
            }
            *(uint2*)&Ks[r][dq4] = pack4bf(kv.x, kv.y, kv.z, kv.w);
            int swcol = r ^ (((i&15)&7)<<3);
            Vt[dq4+0][swcol] = f2bf(vv.x);
            Vt[dq4+1][swcol] = f2bf(vv.y);
            Vt[dq4+2][swcol] = f2bf(vv.z);
            Vt[dq4+3][swcol] = f2bf(vv.w);
        }
        if (tid < 64){
            int s = ch*64 + tid;
            float a;
            if (s < TT)            a = (smask[b*TT + s] == 0) ? -1e9f : 0.f;
            else if (s < TT+96)    a = 0.f;
            else if (s < NS)       a = text_on ? 0.f : -1e9f;
            else                   a = -1e30f;
            madd[tid] = a;
        }
        __syncthreads();

        f32x4 sacc[4] = {};
        #pragma unroll
        for (int sl=0; sl<4; ++sl){
            #pragma unroll
            for (int ks=0; ks<2; ++ks){
                bf16x8_t kf = *reinterpret_cast<const bf16x8_t*>(&Ks[sl*16 + lq][ks*32 + lg*8]);
                sacc[sl] = __builtin_amdgcn_mfma_f32_16x16x32_bf16(kf, qf[ks], sacc[sl], 0, 0, 0);
            }
        }
        float sv[4][4];
        float pmax = -1e30f;
        #pragma unroll
        for (int sl=0; sl<4; ++sl){
            #pragma unroll
            for (int r=0; r<4; ++r){
                int s_loc = sl*16 + lg*4 + r;
                float a = madd[s_loc];
                if (ch < 8){ float dt = (float)(tgq - (ch*64 + s_loc)); a -= dt*dt*inv2s; }
                float v = sacc[sl][r] + a;
                sv[sl][r] = v;
                pmax = fmaxf(pmax, v);
            }
        }
        pmax = fmaxf(pmax, __shfl_xor(pmax, 16));
        pmax = fmaxf(pmax, __shfl_xor(pmax, 32));
        float mn  = fmaxf(m_r, pmax);
        float scl = __expf(m_r - mn);
        m_r = mn;
        float psum = 0.f;
        #pragma unroll
        for (int sl=0; sl<4; ++sl){
            #pragma unroll
            for (int r=0; r<4; ++r){
                float p = __expf(sv[sl][r] - mn);
                sv[sl][r] = p;
                psum += p;
            }
        }
        psum += __shfl_xor(psum, 16);
        psum += __shfl_xor(psum, 32);
        l_r = l_r*scl + psum;
        #pragma unroll
        for (int sl=0; sl<4; ++sl)
            *(uint2*)&Pl[w*16 + lq][sl*16 + lg*4] = pack4bf(sv[sl][0], sv[sl][1], sv[sl][2], sv[sl][3]);

        #pragma unroll
        for (int r=0; r<4; ++r){
            float so = __shfl(scl, lg*4 + r);
            #pragma unroll
            for (int ds_=0; ds_<4; ++ds_) oacc[ds_][r] *= so;
        }
        #pragma unroll
        for (int ds_=0; ds_<4; ++ds_){
            int dcol = ds_*16 + lq;
            int swz = (((dcol>>2)&7)<<3);
            #pragma unroll
            for (int ks=0; ks<2; ++ks){
                bf16x8_t pf = *reinterpret_cast<const bf16x8_t*>(&Pl[w*16 + lq][ks*32 + lg*8]);
                bf16x8_t vf = *reinterpret_cast<const bf16x8_t*>(&Vt[dcol][(ks*32 + lg*8) ^ swz]);
                oacc[ds_] = __builtin_amdgcn_mfma_f32_16x16x32_bf16(pf, vf, oacc[ds_], 0, 0, 0);
            }
        }
    }
    #pragma unroll
    for (int r=0; r<4; ++r){
        int t = t0 + w*16 + lg*4 + r;
        size_t off = (size_t)split*NROWS + (size_t)bh*TT + t;
        #pragma unroll
        for (int ds_=0; ds_<4; ++ds_)
            po[off*64 + ds_*16 + lq] = oacc[ds_][r];
    }
    if (lg == 0){
        size_t off = (size_t)split*NROWS + (size_t)bh*TT + (t0 + w*16 + lq);
        pm[off] = m_r;
        pl[off] = l_r;
    }
}

// ======== bf16 MFMA GEMM (gemm2): C = bf16(A) @ W + bias + res ========
__global__ __launch_bounds__(256) void gemm_mfma_kernel(
    const float* __restrict__ A, const unsigned short* __restrict__ Wt,
    const float* __restrict__ bias, const float* __restrict__ res,
    float* __restrict__ C, int Mr, int Nr, int Kr)
{
    __shared__ __align__(16) unsigned short As[32][40];
    __shared__ __align__(16) unsigned short Bs[64][40];
    int tid = threadIdx.x;
    int row0 = blockIdx.x*32, col0 = blockIdx.y*64;
    int wave = tid >> 6, lane = tid & 63;
    int lr = lane & 15, lk = lane >> 4;

    f32x4 acc[2] = {};

    for (int k0 = 0; k0 < Kr; k0 += 32){
        __syncthreads();
        {
            int r = tid >> 3, kq = tid & 7;
            float4 v = *(const float4*)(A + (size_t)(row0 + r)*Kr + k0 + kq*4);
            *(uint2*)&As[r][kq*4] = pack4bf(v.x, v.y, v.z, v.w);
        }
        {
            int n = tid >> 2, oq = tid & 3;
            *(uint4*)&Bs[n][oq*8] = *(const uint4*)(Wt + (size_t)(col0+n)*Kr + k0 + oq*8);
        }
        __syncthreads();
        bf16x8_t a0 = *reinterpret_cast<const bf16x8_t*>(&As[lr][lk*8]);
        bf16x8_t a1 = *reinterpret_cast<const bf16x8_t*>(&As[16 + lr][lk*8]);
        bf16x8_t bfr = *reinterpret_cast<const bf16x8_t*>(&Bs[wave*16 + lr][lk*8]);
        acc[0] = __builtin_amdgcn_mfma_f32_16x16x32_bf16(a0, bfr, acc[0], 0, 0, 0);
        acc[1] = __builtin_amdgcn_mfma_f32_16x16x32_bf16(a1, bfr, acc[1], 0, 0, 0);
    }
    int gc = col0 + wave*16 + lr;
    float bv = bias[gc];
    #pragma unroll
    for (int m=0;m<2;++m){
        #pragma unroll
        for (int r=0;r<4;++r){
            int gr = row0 + m*16 + lk*4 + r;
            float v = acc[m][r] + bv;
            size_t off = (size_t)gr*Nr + gc;
            if (res) v += res[off];
            C[off] = v;
        }
    }
}

// ======== fused 4-split combine + modulated LN + silu ========
__global__ __launch_bounds__(256) void lnmod_combine_kernel(
    const float* __restrict__ po, const float* __restrict__ pm, const float* __restrict__ pl,
    const float* __restrict__ g, const float* __restrict__ bb,
    const float* __restrict__ eo, float* __restrict__ out)
{
    int row = blockIdx.x, tid = threadIdx.x;
    int b = row / TT, t = row % TT;
    __shared__ float xsr[LATD];
    __shared__ float red[256];
    float s = 0.f;
    for (int i=tid;i<LATD;i+=256){
        int h = i >> 6, d = i & 63;
        size_t rowid = ((size_t)(b*HH + h))*TT + t;
        float m = -1e30f;
        #pragma unroll
        for (int k=0;k<NSPLIT;++k) m = fmaxf(m, pm[(size_t)k*NROWS + rowid]);
        float lsum = 0.f, acc = 0.f;
        #pragma unroll
        for (int k=0;k<NSPLIT;++k){
            float sk = __expf(pm[(size_t)k*NROWS + rowid] - m);
            lsum += pl[(size_t)k*NROWS + rowid]*sk;
            acc  += po[((size_t)k*NROWS + rowid)*64 + d]*sk;
        }
        float v = acc / lsum;
        xsr[i] = v; s += v;
    }
    red[tid]=s; __syncthreads();
    for (int k=128;k>0;k>>=1){ if (tid<k) red[tid]+=red[tid+k]; __syncthreads(); }
    float mean = red[0]*(1.0f/LATD);
    __syncthreads();
    float vs=0.f;
    for (int i=tid;i<LATD;i+=256){ float d=xsr[i]-mean; vs+=d*d; }
    red[tid]=vs; __syncthreads();
    for (int k=128;k>0;k>>=1){ if (tid<k) red[tid]+=red[tid+k]; __syncthreads(); }
    float rstd = rsqrtf(red[0]*(1.0f/LATD)+1e-5f);
    const float* ep = eo + (size_t)row*(2*LATD);
    float* op = out + (size_t)row*LATD;
    for (int i=tid;i<LATD;i+=256){
        float v = (xsr[i]-mean)*rstd*g[i] + bb[i];
        v = v*(1.0f + ep[i]) + ep[LATD+i];
        op[i] = siluf(v);
    }
}

extern "C" void kernel_launch(void* const* d_in, const int* in_sizes, int n_in,
                              void* d_out, int out_size, void* d_ws, size_t ws_size,
                              hipStream_t stream)
{
    (void)in_sizes; (void)n_in; (void)out_size; (void)ws_size;
    const float* x     = (const float*)d_in[0];
    const float* emb   = (const float*)d_in[1];
    const int*   smask = (const int*)d_in[2];
    const float* tcond = (const float*)d_in[5];
    const float* two   = (const float*)d_in[6];
    const float* ng    = (const float*)d_in[7];
    const float* nb    = (const float*)d_in[8];
    const float* memb  = (const float*)d_in[9];
    const float* m_wg  = (const float*)d_in[10];
    const float* m_w1  = (const float*)d_in[11];
    const float* m_b1  = (const float*)d_in[12];
    const float* m_w2  = (const float*)d_in[13];
    const float* m_b2  = (const float*)d_in[14];
    const float* m_pw  = (const float*)d_in[15];
    const float* m_pb  = (const float*)d_in[16];
    const float* kms   = (const float*)d_in[17];
    const float* sigma = (const float*)d_in[18];
    const float* kdat  = (const float*)d_in[19];
    const float* kds   = (const float*)d_in[20];
    const float* vdat  = (const float*)d_in[21];
    const float* krot  = (const float*)d_in[22];
    const float* krs   = (const float*)d_in[23];
    const float* vrot  = (const float*)d_in[24];
    const float* ntg   = (const float*)d_in[25];
    const float* ntb   = (const float*)d_in[26];
    const float* c_wg  = (const float*)d_in[27];
    const float* c_w1  = (const float*)d_in[28];
    const float* c_b1  = (const float*)d_in[29];
    const float* c_w2  = (const float*)d_in[30];
    const float* c_b2  = (const float*)d_in[31];
    const float* c_pw  = (const float*)d_in[32];
    const float* c_pb  = (const float*)d_in[33];
    const float* kts   = (const float*)d_in[34];
    const float* st_ew = (const float*)d_in[35];
    const float* st_eb = (const float*)d_in[36];
    const float* st_ng = (const float*)d_in[37];
    const float* st_nb = (const float*)d_in[38];
    const float* st_ow = (const float*)d_in[39];
    const float* st_ob = (const float*)d_in[40];

    float* ws = (float*)d_ws;
    float* xh   = ws;
    float* qB   = xh  + 1310720;
    float* kmB  = qB  + 1310720;
    float* vmB  = kmB + 1310720;
    float* ctB  = vmB + 1310720;
    float* ktB  = ctB + 197120;
    float* vtB  = ktB + 197120;
    float* aout = vtB + 197120;
    float* eoB  = aout + 1310720;
    float* shB  = eoB + 2621440;

    unsigned short* w1Tm = (unsigned short*)(shB + 1310720);
    unsigned short* w2Tm = w1Tm + EE*FFND*DD;
    unsigned short* w1Tt = w2Tm + EE*FFND*DD;
    unsigned short* w2Tt = w1Tt + EE*FFND*DD;
    unsigned short* stewT = w2Tt + EE*FFND*DD;
    unsigned short* stowT = stewT + 512*1280;
    unsigned short* mpwT  = stowT + 640*640;
    unsigned short* cpwT  = mpwT + 320*64;
    unsigned short* embBf = cpwT + 128*64;
    float* poB = (float*)(embBf + 2048*512);
    float* pmB = poB + (size_t)NSPLIT*NROWS*64;
    float* plB = pmB + (size_t)NSPLIT*NROWS;

    float* yslotM = eoB;
    float* yslotT = shB;
    float* wAm   = aout;
    float* wAt   = wAm + NTOK_M*2;
    int*   cntA  = (int*)(wAt + NTOK_T*2);
    int*   listM = cntA + 16;
    int*   listT = listM + EE*NTOK_M;

    prep_ln_kernel<<<651 + BB*TT + BB*MM, 256, 0, stream>>>(
        m_w1, w1Tm, m_w2, w2Tm, c_w1, w1Tt, c_w2, w2Tt,
        st_ew, stewT, st_ow, stowT, m_pw, mpwT, c_pw, cpwT,
        emb, embBf, cntA,
        x, ng, nb, memb, xh, two, ntg, ntb, ctB);

    route_kernel<<<ROUTEB_M + ROUTEB_T, 256, 0, stream>>>(
        xh, m_wg, cntA, listM, wAm,
        ctB, c_wg, cntA+8, listT, wAt);

    moe_ffn_kernel<<<MAXB_M + MAXB_T, 256, 0, stream>>>(
        xh, w1Tm, m_b1, w2Tm, m_b2, cntA, listM, wAm, yslotM,
        ctB, w1Tt, c_b1, w2Tt, c_b2, cntA+8, listT, wAt, yslotT);

    moe_proj_kernel<<<PROJB_M + PROJB_T, 256, 0, stream>>>(
        yslotM, mpwT, m_pb, qB, kmB, vmB,
        yslotT, cpwT, c_pb, ktB, vtB);

    attn_gemm_kernel<<<ATTNB + GEMM1B, 256, 0, stream>>>(
        qB, kmB, vmB, ktB, vtB, kdat, vdat, krot, vrot, smask, tcond,
        kms, kds, krs, kts, sigma, poB, pmB, plB,
        embBf, stewT, st_eb, eoB);

    lnmod_combine_kernel<<<BB*TT, 256, 0, stream>>>(
        poB, pmB, plB, st_ng, st_nb, eoB, shB);

    {
        dim3 g2(2048/32, 640/64);
        gemm_mfma_kernel<<<g2, 256, 0, stream>>>(shB, stowT, st_ob, x, (float*)d_out, 2048, 640, 640);
    }
}

// Round 14
// 111.057 us; speedup vs baseline: 1.8375x; 1.0136x over previous
//
#include <hip/hip_runtime.h>
#include <math.h>

#define BB 4
#define TT 512
#define MM 77
#define HH 10
#define DD 64
#define LATD 640
#define EE 8
#define FFND 256
#define NS 685     // 512 + 48 + 48 + 77
#define NCH 11     // ceil(685/64)
#define NSP (NCH*64)
#define NROWS 20480
#define NSPLIT 4

#define NTOK_M (BB*TT*HH)   // 20480
#define NTOK_T (BB*MM*HH)   // 3080
#define MAXB_M 647
#define MAXB_T 103
#define PROJB_M 320
#define PROJB_T 49
#define ROUTEB_M 80
#define ROUTEB_T 13
#define ATTNB (BB*HH*8*NSPLIT)   // 1280
#define GEMM1B 1280              // (2048/32)*(1280/64)

typedef float f32x4 __attribute__((ext_vector_type(4)));
typedef __bf16 bf16x8_t __attribute__((ext_vector_type(8)));
typedef unsigned short u16x8 __attribute__((ext_vector_type(8)));

__device__ __forceinline__ float geluf(float x){
    float u = 0.7978845608028654f*(x + 0.044715f*x*x*x);
    u = fminf(fmaxf(u, -15.f), 15.f);
    float e = __expf(2.f*u);
    return 0.5f*x*(1.f + (e-1.f)/(e+1.f));
}
__device__ __forceinline__ float siluf(float x){
    return x / (1.0f + __expf(-x));
}
__device__ __forceinline__ unsigned short f2bf(float f){
    unsigned int u = __float_as_uint(f);
    u += 0x7fff + ((u >> 16) & 1);
    return (unsigned short)(u >> 16);
}
__device__ __forceinline__ uint2 pack4bf(float a, float b, float c, float d){
    uint2 r;
    r.x = (unsigned)f2bf(a) | ((unsigned)f2bf(b)<<16);
    r.y = (unsigned)f2bf(c) | ((unsigned)f2bf(d)<<16);
    return r;
}

// ======== fused prep + LN ========
__global__ __launch_bounds__(256) void prep_ln_kernel(
    const float* __restrict__ m_w1, unsigned short* __restrict__ w1Tm,
    const float* __restrict__ m_w2, unsigned short* __restrict__ w2Tm,
    const float* __restrict__ c_w1, unsigned short* __restrict__ w1Tt,
    const float* __restrict__ c_w2, unsigned short* __restrict__ w2Tt,
    const float* __restrict__ st_ew, unsigned short* __restrict__ stewT,
    const float* __restrict__ st_ow, unsigned short* __restrict__ stowT,
    const float* __restrict__ m_pw, unsigned short* __restrict__ mpwT,
    const float* __restrict__ c_pw, unsigned short* __restrict__ cpwT,
    const float* __restrict__ emb, unsigned short* __restrict__ embBf,
    int* __restrict__ cnt,
    const float* __restrict__ x, const float* __restrict__ ng, const float* __restrict__ nb,
    const float* __restrict__ memb, float* __restrict__ xh,
    const float* __restrict__ two, const float* __restrict__ ntg, const float* __restrict__ ntb,
    float* __restrict__ ctB)
{
    __shared__ float buf[64*65];
    const int bid = blockIdx.x, tid = threadIdx.x;
    if (bid >= 651){
        int lrow = bid - 651;
        const float* in; const float* g; const float* bb; const float* ap; float* out;
        int row;
        if (lrow < BB*TT){
            row = lrow; in = x; g = ng; bb = nb; out = xh;
            ap = memb + (size_t)(row % TT)*LATD;
        } else {
            row = lrow - BB*TT; in = two; g = ntg; bb = ntb; out = ctB;
            ap = nullptr;
        }
        float* xsr = buf;
        float* red = buf + LATD;
        const float* rp = in + (size_t)row*LATD;
        float s = 0.f;
        for (int i=tid;i<LATD;i+=256){ float v = rp[i]; xsr[i]=v; s+=v; }
        red[tid]=s; __syncthreads();
        for (int k=128;k>0;k>>=1){ if (tid<k) red[tid]+=red[tid+k]; __syncthreads(); }
        float mean = red[0]*(1.0f/LATD);
        __syncthreads();
        float vs=0.f;
        for (int i=tid;i<LATD;i+=256){ float d=xsr[i]-mean; vs+=d*d; }
        red[tid]=vs; __syncthreads();
        for (int k=128;k>0;k>>=1){ if (tid<k) red[tid]+=red[tid+k]; __syncthreads(); }
        float rstd = rsqrtf(red[0]*(1.0f/LATD)+1e-5f);
        float* op = out + (size_t)row*LATD;
        for (int i=tid;i<LATD;i+=256){
            float v = (xsr[i]-mean)*rstd*g[i] + bb[i];
            if (ap) v += ap[i];
            op[i] = v;
        }
        return;
    }
    if (bid >= 395){
        int l = bid - 395;
        if (l == 0 && tid < 16) cnt[tid] = 0;
        size_t base = (size_t)l*4096;
        #pragma unroll
        for (int p=0; p<4; ++p){
            size_t i = base + (size_t)p*1024 + tid*4;
            float4 v = *(const float4*)(emb + i);
            *(uint2*)(embBf + i) = pack4bf(siluf(v.x), siluf(v.y), siluf(v.z), siluf(v.w));
        }
        return;
    }
    float (*t)[65] = (float(*)[65])buf;
    const float* in; unsigned short* out; int R, C, z, rt, ct;
    if (bid < 32)      { int l=bid;     in=m_w1;  out=w1Tm;  R=64;  C=256;  z=l>>2; rt=0;    ct=l&3; }
    else if (bid < 64) { int l=bid-32;  in=m_w2;  out=w2Tm;  R=256; C=64;   z=l>>2; rt=l&3;  ct=0; }
    else if (bid < 96) { int l=bid-64;  in=c_w1;  out=w1Tt;  R=64;  C=256;  z=l>>2; rt=0;    ct=l&3; }
    else if (bid < 128){ int l=bid-96;  in=c_w2;  out=w2Tt;  R=256; C=64;   z=l>>2; rt=l&3;  ct=0; }
    else if (bid < 288){ int l=bid-128; in=st_ew; out=stewT; R=512; C=1280; z=0;    rt=l/20; ct=l%20; }
    else if (bid < 388){ int l=bid-288; in=st_ow; out=stowT; R=640; C=640;  z=0;    rt=l/10; ct=l%10; }
    else if (bid < 393){ int l=bid-388; in=m_pw;  out=mpwT;  R=64;  C=320;  z=0;    rt=0;    ct=l; }
    else               { int l=bid-393; in=c_pw;  out=cpwT;  R=64;  C=128;  z=0;    rt=0;    ct=l; }
    const size_t base = (size_t)z*R*C;
    const int r0 = rt*64, c0 = ct*64;
    #pragma unroll
    for (int p=0; p<16; ++p){
        int i = tid + p*256;
        int r = i>>6, c = i&63;
        t[r][c] = in[base + (size_t)(r0+r)*C + c0 + c];
    }
    __syncthreads();
    #pragma unroll
    for (int p=0; p<16; ++p){
        int i = tid + p*256;
        int c = i>>6, r = i&63;
        out[base + (size_t)(c0+c)*R + r0 + r] = f2bf(t[r][c]);
    }
}

// ======== MoE routing, M+T merged ========
__global__ __launch_bounds__(256) void route_kernel(
    const float* __restrict__ xinM, const float* __restrict__ wgM,
    int* __restrict__ countsM, int* __restrict__ listM, float* __restrict__ wAM,
    const float* __restrict__ xinT, const float* __restrict__ wgT,
    int* __restrict__ countsT, int* __restrict__ listT, float* __restrict__ wAT)
{
    __shared__ int bcnt[EE];
    __shared__ int bbase[EE];
    const int tid = threadIdx.x;
    const int bid = blockIdx.x;
    const float* xin; const float* wg; int* counts; int* list; float* wA; int nTok, t;
    if (bid < ROUTEB_M){
        xin = xinM; wg = wgM; counts = countsM; list = listM; wA = wAM; nTok = NTOK_M;
        t = bid*256 + tid;
    } else {
        xin = xinT; wg = wgT; counts = countsT; list = listT; wA = wAT; nTok = NTOK_T;
        t = (bid - ROUTEB_M)*256 + tid;
    }
    if (tid < EE) bcnt[tid] = 0;
    __syncthreads();

    int e0 = 0, e1 = 0, p0 = 0, p1 = 0;
    bool act = (t < nTok);
    if (act){
        float lg[EE];
        #pragma unroll
        for (int e=0;e<EE;e++) lg[e]=0.f;
        const float4* xp = (const float4*)(xin + (size_t)t*DD);
        #pragma unroll 4
        for (int dq=0; dq<16; ++dq){
            float4 xv = xp[dq];
            const float* w0 = wg + (dq*4+0)*EE;
            const float* w1 = wg + (dq*4+1)*EE;
            const float* w2 = wg + (dq*4+2)*EE;
            const float* w3 = wg + (dq*4+3)*EE;
            #pragma unroll
            for (int e=0;e<EE;e++)
                lg[e] += xv.x*w0[e] + xv.y*w1[e] + xv.z*w2[e] + xv.w*w3[e];
        }
        float mx = lg[0];
        #pragma unroll
        for (int e=1;e<EE;e++) mx = fmaxf(mx, lg[e]);
        float sum = 0.f;
        #pragma unroll
        for (int e=0;e<EE;e++){ lg[e] = __expf(lg[e]-mx); sum += lg[e]; }
        float inv = 1.0f/sum;
        #pragma unroll
        for (int e=0;e<EE;e++) lg[e] *= inv;
        float v0=lg[0];
        #pragma unroll
        for (int e=1;e<EE;e++){ if (lg[e] > v0){ v0 = lg[e]; e0 = e; } }
        float v1=-1e30f; e1 = (e0==0) ? 1 : 0;
        #pragma unroll
        for (int e=0;e<EE;e++){ if (e==e0) continue; if (lg[e] > v1){ v1 = lg[e]; e1 = e; } }
        wA[t*2+0]=v0; wA[t*2+1]=v1;
        p0 = atomicAdd(&bcnt[e0], 1);
        p1 = atomicAdd(&bcnt[e1], 1);
    }
    __syncthreads();
    if (tid < EE){
        bbase[tid] = (bcnt[tid] > 0) ? atomicAdd(&counts[tid], bcnt[tid]) : 0;
    }
    __syncthreads();
    if (act){
        list[(size_t)e0*nTok + bbase[e0] + p0] = t*2;
        list[(size_t)e1*nTok + bbase[e1] + p1] = t*2+1;
    }
}

// ======== grouped expert FFN (MFMA), M+T merged ========
__global__ __launch_bounds__(256) void moe_ffn_kernel(
    const float* __restrict__ xinM, const unsigned short* __restrict__ w1TM,
    const float* __restrict__ b1M, const unsigned short* __restrict__ w2TM,
    const float* __restrict__ b2M, const int* __restrict__ countsM,
    const int* __restrict__ listM, const float* __restrict__ wAM,
    float* __restrict__ yslotM,
    const float* __restrict__ xinT, const unsigned short* __restrict__ w1TT,
    const float* __restrict__ b1T, const unsigned short* __restrict__ w2TT,
    const float* __restrict__ b2T, const int* __restrict__ countsT,
    const int* __restrict__ listT, const float* __restrict__ wAT,
    float* __restrict__ yslotT)
{
    __shared__ __align__(16) unsigned short xs[64][72];
    __shared__ __align__(16) unsigned short w1s[64][72];
    __shared__ __align__(16) unsigned short w2s[64][72];
    __shared__ __align__(16) unsigned short hs[64][72];
    __shared__ int sCnt[EE];
    __shared__ int encs[64];
    __shared__ float wgts[64];
    const int tid = threadIdx.x;
    const float* xin; const unsigned short* w1T; const float* b1g;
    const unsigned short* w2T; const float* b2g; const int* counts;
    const int* list; const float* wA; float* yslot; int nTok, bidl;
    if (blockIdx.x < MAXB_M){
        xin=xinM; w1T=w1TM; b1g=b1M; w2T=w2TM; b2g=b2M; counts=countsM;
        list=listM; wA=wAM; yslot=yslotM; nTok=NTOK_M; bidl=blockIdx.x;
    } else {
        xin=xinT; w1T=w1TT; b1g=b1T; w2T=w2TT; b2g=b2T; counts=countsT;
        list=listT; wA=wAT; yslot=yslotT; nTok=NTOK_T; bidl=blockIdx.x-MAXB_M;
    }
    if (tid < EE) sCnt[tid] = counts[tid];
    __syncthreads();
    int e = -1, tile = 0;
    {
        int acc = 0;
        #pragma unroll
        for (int i=0;i<EE;++i){
            int tc = (sCnt[i]+63)>>6;
            if (e < 0 && bidl < acc + tc){ e = i; tile = bidl - acc; }
            acc += tc;
        }
    }
    if (e < 0) return;
    const int cnt = sCnt[e];
    if (tid < 64){
        int idx = tile*64 + tid;
        int enc = (idx < cnt) ? list[(size_t)e*nTok + idx] : -1;
        encs[tid] = enc;
        wgts[tid] = (enc >= 0) ? wA[enc] : 0.f;
    }
    __syncthreads();
    for (int i=tid; i<64*16; i+=256){
        int r = i>>4, dq4 = (i&15)*4;
        int enc = encs[r];
        float4 xv = make_float4(0.f,0.f,0.f,0.f);
        if (enc >= 0) xv = *(const float4*)(xin + (size_t)(enc>>1)*DD + dq4);
        *(uint2*)&xs[r][dq4] = pack4bf(xv.x, xv.y, xv.z, xv.w);
    }

    const int w    = tid >> 6;
    const int lane = tid & 63;
    const int lq   = lane & 15;
    const int lg   = lane >> 4;

    const unsigned short* w1e = w1T + (size_t)e*FFND*DD;
    const unsigned short* w2e = w2T + (size_t)e*DD*FFND;

    f32x4 acc2[4] = {};

    for (int fc=0; fc<4; ++fc){
        __syncthreads();
        for (int i=tid; i<512; i+=256){
            int r = i>>3, jq = i&7;
            *(uint4*)&w1s[r][jq*8] = *(const uint4*)(w1e + (size_t)(fc*64+r)*DD + jq*8);
            *(uint4*)&w2s[r][jq*8] = *(const uint4*)(w2e + (size_t)r*FFND + fc*64 + jq*8);
        }
        __syncthreads();
        f32x4 acc1[4] = {};
        #pragma unroll
        for (int fb=0; fb<4; ++fb){
            #pragma unroll
            for (int ks=0; ks<2; ++ks){
                bf16x8_t xf = *reinterpret_cast<const bf16x8_t*>(&xs[w*16+lq][ks*32+lg*8]);
                bf16x8_t wf = *reinterpret_cast<const bf16x8_t*>(&w1s[fb*16+lq][ks*32+lg*8]);
                acc1[fb] = __builtin_amdgcn_mfma_f32_16x16x32_bf16(xf, wf, acc1[fb], 0, 0, 0);
            }
        }
        #pragma unroll
        for (int fb=0; fb<4; ++fb){
            float b1v = b1g[e*FFND + fc*64 + fb*16 + lq];
            #pragma unroll
            for (int r=0; r<4; ++r)
                hs[w*16 + lg*4 + r][fb*16 + lq] = f2bf(geluf(acc1[fb][r] + b1v));
        }
        #pragma unroll
        for (int db=0; db<4; ++db){
            #pragma unroll
            for (int ks=0; ks<2; ++ks){
                bf16x8_t hf  = *reinterpret_cast<const bf16x8_t*>(&hs[w*16+lq][ks*32+lg*8]);
                bf16x8_t w2f = *reinterpret_cast<const bf16x8_t*>(&w2s[db*16+lq][ks*32+lg*8]);
                acc2[db] = __builtin_amdgcn_mfma_f32_16x16x32_bf16(hf, w2f, acc2[db], 0, 0, 0);
            }
        }
    }
    #pragma unroll
    for (int r=0; r<4; ++r){
        int tok = w*16 + lg*4 + r;
        int enc = encs[tok];
        if (enc >= 0){
            float gw = wgts[tok];
            #pragma unroll
            for (int db=0; db<4; ++db){
                int d = db*16 + lq;
                yslot[(size_t)enc*DD + d] = gw*(acc2[db][r] + b2g[e*DD + d]);
            }
        }
    }
}

// ======== combine slots + gelu + MFMA projection, M+T merged ========
template<int NPROJ>
__device__ __forceinline__ void proj_body(
    const float* __restrict__ yslot, const unsigned short* __restrict__ pwT,
    const float* __restrict__ pbg, int nTok, int base,
    float* __restrict__ out0, float* __restrict__ out1, float* __restrict__ out2,
    unsigned short gs[64][72])
{
    const int tid = threadIdx.x;
    for (int i=tid; i<64*16; i+=256){
        int r = i>>4, dq4 = (i&15)*4;
        int tok = base + r;
        float4 g4 = make_float4(0.f,0.f,0.f,0.f);
        if (tok < nTok){
            float4 a = *(const float4*)(yslot + (size_t)tok*128 + dq4);
            float4 b = *(const float4*)(yslot + (size_t)tok*128 + 64 + dq4);
            g4.x = geluf(a.x+b.x); g4.y = geluf(a.y+b.y);
            g4.z = geluf(a.z+b.z); g4.w = geluf(a.w+b.w);
        }
        *(uint2*)&gs[r][dq4] = pack4bf(g4.x, g4.y, g4.z, g4.w);
    }
    __syncthreads();

    const int w    = tid >> 6;
    const int lane = tid & 63;
    const int lq   = lane & 15;
    const int lg   = lane >> 4;
    constexpr int NC = NPROJ/64;
    const int colbase = w*16*NC;

    bf16x8_t wf[NC][2];
    #pragma unroll
    for (int cb=0; cb<NC; ++cb)
        #pragma unroll
        for (int ks=0; ks<2; ++ks)
            wf[cb][ks] = *reinterpret_cast<const bf16x8_t*>(
                pwT + (size_t)(colbase + cb*16 + lq)*DD + ks*32 + lg*8);

    f32x4 acc[4][NC] = {};
    #pragma unroll
    for (int m=0; m<4; ++m){
        #pragma unroll
        for (int ks=0; ks<2; ++ks){
            bf16x8_t af = *reinterpret_cast<const bf16x8_t*>(&gs[m*16+lq][ks*32+lg*8]);
            #pragma unroll
            for (int cb=0; cb<NC; ++cb)
                acc[m][cb] = __builtin_amdgcn_mfma_f32_16x16x32_bf16(af, wf[cb][ks], acc[m][cb], 0, 0, 0);
        }
    }
    #pragma unroll
    for (int m=0; m<4; ++m){
        #pragma unroll
        for (int r=0; r<4; ++r){
            int tok = base + m*16 + lg*4 + r;
            if (tok >= nTok) continue;
            #pragma unroll
            for (int cb=0; cb<NC; ++cb){
                int j = colbase + cb*16 + lq;
                float v = acc[m][cb][r] + pbg[j];
                int bufi = j >> 6, jd = j & 63;
                float* dst = (bufi==0) ? out0 : (bufi==1) ? out1 : out2;
                dst[(size_t)tok*DD + jd] = v;
            }
        }
    }
}

__global__ __launch_bounds__(256) void moe_proj_kernel(
    const float* __restrict__ yslotM, const unsigned short* __restrict__ mpwT,
    const float* __restrict__ mpb,
    float* __restrict__ qB, float* __restrict__ kmB, float* __restrict__ vmB,
    const float* __restrict__ yslotT, const unsigned short* __restrict__ cpwT,
    const float* __restrict__ cpb,
    float* __restrict__ ktB, float* __restrict__ vtB)
{
    __shared__ __align__(16) unsigned short gs[64][72];
    if (blockIdx.x < PROJB_M){
        proj_body<192>(yslotM, mpwT, mpb, NTOK_M, blockIdx.x*64, qB, kmB, vmB, gs);
    } else {
        proj_body<128>(yslotT, cpwT, cpb, NTOK_T, (blockIdx.x-PROJB_M)*64, ktB, vtB, nullptr, gs);
    }
}

// ======== KV prep: fused pre-scaled bf16 K + pre-swizzled bf16 V^T + mask rows ========
__global__ __launch_bounds__(256) void kv_prep_kernel(
    const float* __restrict__ kmb, const float* __restrict__ vmb,   // (B,T,H,64)
    const float* __restrict__ ktb, const float* __restrict__ vtb,   // (B,M,H,64)
    const float* __restrict__ kd,  const float* __restrict__ vd,
    const float* __restrict__ kr,  const float* __restrict__ vr,
    const int*   __restrict__ smask, const float* __restrict__ tcond,
    const float* __restrict__ kms_p, const float* __restrict__ kds_p,
    const float* __restrict__ krs_p, const float* __restrict__ kts_p,
    unsigned short* __restrict__ Kbf,   // (B*H, NCH, 64, 64)
    unsigned short* __restrict__ VTbf,  // (B*H, NCH, 64, 64) swizzled V^T
    float* __restrict__ maddg)          // (B, NSP)
{
    __shared__ __align__(16) unsigned short Vs[64][72];
    const int tid = threadIdx.x;
    const int bh = blockIdx.x, ch = blockIdx.y;
    const int b = bh / HH, h = bh % HH;
    const float sc = 0.125f;
    const float kms = kms_p[0]*sc, kds = kds_p[0]*sc, krs = krs_p[0]*sc, kts = kts_p[0]*sc;
    unsigned short* kc = Kbf + ((size_t)(bh*NCH + ch) << 12);
    unsigned short* vc = VTbf + ((size_t)(bh*NCH + ch) << 12);
    for (int i=tid; i<64*16; i+=256){
        int r = i>>4, dq4 = (i&15)*4;
        int s = ch*64 + r;
        float4 kv = make_float4(0,0,0,0), vv = make_float4(0,0,0,0);
        if (s < TT){
            size_t o = ((size_t)(b*TT + s)*HH + h)*DD + dq4;
            kv = *(const float4*)(&kmb[o]);
            kv.x*=kms; kv.y*=kms; kv.z*=kms; kv.w*=kms;
            vv = *(const float4*)(&vmb[o]);
        } else if (s < TT+48){
            kv = *(const float4*)(&kd[((size_t)(s-TT)*HH + h)*DD + dq4]);
            kv.x*=kds; kv.y*=kds; kv.z*=kds; kv.w*=kds;
            vv = *(const float4*)(&vd[((size_t)(s-TT)*HH + h)*DD + dq4]);
        } else if (s < TT+96){
            kv = *(const float4*)(&kr[((size_t)(s-TT-48)*HH + h)*DD + dq4]);
            kv.x*=krs; kv.y*=krs; kv.z*=krs; kv.w*=krs;
            vv = *(const float4*)(&vr[((size_t)(s-TT-48)*HH + h)*DD + dq4]);
        } else if (s < NS){
            size_t o = ((size_t)(b*MM + (s-TT-96))*HH + h)*DD + dq4;
            kv = *(const float4*)(&ktb[o]);
            kv.x*=kts; kv.y*=kts; kv.z*=kts; kv.w*=kts;
            vv = *(const float4*)(&vtb[o]);
        }
        *(uint2*)(kc + r*64 + dq4) = pack4bf(kv.x, kv.y, kv.z, kv.w);
        int swcol = r ^ (((i&15)&7)<<3);
        Vs[dq4+0][swcol] = f2bf(vv.x);
        Vs[dq4+1][swcol] = f2bf(vv.y);
        Vs[dq4+2][swcol] = f2bf(vv.z);
        Vs[dq4+3][swcol] = f2bf(vv.w);
    }
    __syncthreads();
    for (int i=tid; i<512; i+=256){
        int d = i>>3, seg = i&7;
        *(uint4*)(vc + d*64 + seg*8) = *(const uint4*)&Vs[d][seg*8];
    }
    if (h == 0 && tid < 64){
        int s = ch*64 + tid;
        float a;
        if (s < TT)            a = (smask[b*TT + s] == 0) ? -1e9f : 0.f;
        else if (s < TT+96)    a = 0.f;
        else if (s < NS)       a = (tcond[b] > 0.f) ? 0.f : -1e9f;
        else                   a = -1e30f;
        maddg[b*NSP + s] = a;
    }
}

// ======== merged: MFMA flash attention (split-s=4, bf16 K/V copies) ∥ gemm1 ========
__global__ __launch_bounds__(256) void attn_gemm_kernel(
    const float* __restrict__ qb,
    const unsigned short* __restrict__ Kbf,
    const unsigned short* __restrict__ VTbf,
    const float* __restrict__ maddg,
    const float* __restrict__ sigma_p,
    float* __restrict__ po, float* __restrict__ pm, float* __restrict__ pl,
    const unsigned short* __restrict__ gA,   // embBf (2048,512) bf16
    const unsigned short* __restrict__ gWt,  // stewT bf16 [1280][512]
    const float* __restrict__ gbias, float* __restrict__ gC)  // eoB (2048,1280)
{
    __shared__ __align__(16) unsigned char smem[27904];
    const int tid  = threadIdx.x;

    if (blockIdx.x >= ATTNB){
        // ---------------- gemm1 branch ----------------
        const int gbid = blockIdx.x - ATTNB;
        unsigned short (*As)[40] = (unsigned short(*)[40])smem;
        unsigned short (*Bs)[40] = (unsigned short(*)[40])(smem + 2560);
        const int Nr = 1280, Kr = 512;
        const int row0 = (gbid & 63)*32, col0 = (gbid >> 6)*64;
        const int wave = tid >> 6, lane = tid & 63;
        const int lr = lane & 15, lk = lane >> 4;
        f32x4 acc[2] = {};
        for (int k0 = 0; k0 < Kr; k0 += 32){
            __syncthreads();
            {
                int r = tid >> 3, kq = tid & 7;
                *(uint2*)&As[r][kq*4] = *(const uint2*)(gA + (size_t)(row0 + r)*Kr + k0 + kq*4);
            }
            {
                int n = tid >> 2, oq = tid & 3;
                *(uint4*)&Bs[n][oq*8] = *(const uint4*)(gWt + (size_t)(col0+n)*Kr + k0 + oq*8);
            }
            __syncthreads();
            bf16x8_t a0 = *reinterpret_cast<const bf16x8_t*>(&As[lr][lk*8]);
            bf16x8_t a1 = *reinterpret_cast<const bf16x8_t*>(&As[16 + lr][lk*8]);
            bf16x8_t bfr = *reinterpret_cast<const bf16x8_t*>(&Bs[wave*16 + lr][lk*8]);
            acc[0] = __builtin_amdgcn_mfma_f32_16x16x32_bf16(a0, bfr, acc[0], 0, 0, 0);
            acc[1] = __builtin_amdgcn_mfma_f32_16x16x32_bf16(a1, bfr, acc[1], 0, 0, 0);
        }
        int gc = col0 + wave*16 + lr;
        float bv = gbias[gc];
        #pragma unroll
        for (int m=0;m<2;++m){
            #pragma unroll
            for (int r=0;r<4;++r){
                int gr = row0 + m*16 + lk*4 + r;
                gC[(size_t)gr*Nr + gc] = acc[m][r] + bv;
            }
        }
        return;
    }

    // ---------------- attention branch ----------------
    unsigned short (*Ks)[72] = (unsigned short(*)[72])smem;
    unsigned short (*Vt)[72] = (unsigned short(*)[72])(smem + 9216);
    unsigned short (*Pl)[72] = (unsigned short(*)[72])(smem + 18432);
    float* madd = (float*)(smem + 27648);

    const int w    = tid >> 6;
    const int lane = tid & 63;
    const int lq   = lane & 15;
    const int lg   = lane >> 4;

    const int split = blockIdx.x & 3;
    const int xb    = blockIdx.x >> 2;
    const int ch_lo = split*3;
    const int ch_hi = min(ch_lo + 3, NCH);
    const int ttile = xb & 7;
    const int bh    = xb >> 3;
    const int b = bh / HH, h = bh % HH;
    const int t0 = ttile * 64;

    const float sg = sigma_p[0];
    const float inv2s = 1.0f/(2.0f*sg*sg);

    bf16x8_t qf[2];
    {
        const float* qrow = qb + ((size_t)(b*TT + t0 + w*16 + lq)*HH + h)*DD;
        #pragma unroll
        for (int ks=0; ks<2; ++ks){
            float4 v0 = *(const float4*)(qrow + ks*32 + lg*8);
            float4 v1 = *(const float4*)(qrow + ks*32 + lg*8 + 4);
            u16x8 qt;
            qt[0]=f2bf(v0.x); qt[1]=f2bf(v0.y); qt[2]=f2bf(v0.z); qt[3]=f2bf(v0.w);
            qt[4]=f2bf(v1.x); qt[5]=f2bf(v1.y); qt[6]=f2bf(v1.z); qt[7]=f2bf(v1.w);
            qf[ks] = __builtin_bit_cast(bf16x8_t, qt);
        }
    }

    float m_r = -1e30f, l_r = 0.f;
    f32x4 oacc[4] = {};

    const int tgq = t0 + w*16 + lq;
    const float* mrow = maddg + b*NSP;

    for (int ch=ch_lo; ch<ch_hi; ++ch){
        __syncthreads();
        {
            const unsigned short* kc = Kbf + ((size_t)(bh*NCH + ch) << 12);
            const unsigned short* vc = VTbf + ((size_t)(bh*NCH + ch) << 12);
            #pragma unroll
            for (int p=0; p<4; ++p){
                int i = tid + p*256;
                int bsel = i >> 9, j = i & 511;
                int r = j >> 3, seg = j & 7;
                if (bsel == 0)
                    *(uint4*)&Ks[r][seg*8] = *(const uint4*)(kc + r*64 + seg*8);
                else
                    *(uint4*)&Vt[r][seg*8] = *(const uint4*)(vc + r*64 + seg*8);
            }
            if (tid < 64) madd[tid] = mrow[ch*64 + tid];
        }
        __syncthreads();

        f32x4 sacc[4] = {};
        #pragma unroll
        for (int sl=0; sl<4; ++sl){
            #pragma unroll
            for (int ks=0; ks<2; ++ks){
                bf16x8_t kf = *reinterpret_cast<const bf16x8_t*>(&Ks[sl*16 + lq][ks*32 + lg*8]);
                sacc[sl] = __builtin_amdgcn_mfma_f32_16x16x32_bf16(kf, qf[ks], sacc[sl], 0, 0, 0);
            }
        }
        float sv[4][4];
        float pmax = -1e30f;
        #pragma unroll
        for (int sl=0; sl<4; ++sl){
            #pragma unroll
            for (int r=0; r<4; ++r){
                int s_loc = sl*16 + lg*4 + r;
                float a = madd[s_loc];
                if (ch < 8){ float dt = (float)(tgq - (ch*64 + s_loc)); a -= dt*dt*inv2s; }
                float v = sacc[sl][r] + a;
                sv[sl][r] = v;
                pmax = fmaxf(pmax, v);
            }
        }
        pmax = fmaxf(pmax, __shfl_xor(pmax, 16));
        pmax = fmaxf(pmax, __shfl_xor(pmax, 32));
        float mn  = fmaxf(m_r, pmax);
        float scl = __expf(m_r - mn);
        m_r = mn;
        float psum = 0.f;
        #pragma unroll
        for (int sl=0; sl<4; ++sl){
            #pragma unroll
            for (int r=0; r<4; ++r){
                float p = __expf(sv[sl][r] - mn);
                sv[sl][r] = p;
                psum += p;
            }
        }
        psum += __shfl_xor(psum, 16);
        psum += __shfl_xor(psum, 32);
        l_r = l_r*scl + psum;
        #pragma unroll
        for (int sl=0; sl<4; ++sl)
            *(uint2*)&Pl[w*16 + lq][sl*16 + lg*4] = pack4bf(sv[sl][0], sv[sl][1], sv[sl][2], sv[sl][3]);

        #pragma unroll
        for (int r=0; r<4; ++r){
            float so = __shfl(scl, lg*4 + r);
            #pragma unroll
            for (int ds_=0; ds_<4; ++ds_) oacc[ds_][r] *= so;
        }
        #pragma unroll
        for (int ds_=0; ds_<4; ++ds_){
            int dcol = ds_*16 + lq;
            int swz = (((dcol>>2)&7)<<3);
            #pragma unroll
            for (int ks=0; ks<2; ++ks){
                bf16x8_t pf = *reinterpret_cast<const bf16x8_t*>(&Pl[w*16 + lq][ks*32 + lg*8]);
                bf16x8_t vf = *reinterpret_cast<const bf16x8_t*>(&Vt[dcol][(ks*32 + lg*8) ^ swz]);
                oacc[ds_] = __builtin_amdgcn_mfma_f32_16x16x32_bf16(pf, vf, oacc[ds_], 0, 0, 0);
            }
        }
    }
    #pragma unroll
    for (int r=0; r<4; ++r){
        int t = t0 + w*16 + lg*4 + r;
        size_t off = (size_t)split*NROWS + (size_t)bh*TT + t;
        #pragma unroll
        for (int ds_=0; ds_<4; ++ds_)
            po[off*64 + ds_*16 + lq] = oacc[ds_][r];
    }
    if (lg == 0){
        size_t off = (size_t)split*NROWS + (size_t)bh*TT + (t0 + w*16 + lq);
        pm[off] = m_r;
        pl[off] = l_r;
    }
}

// ======== bf16 MFMA GEMM (gemm2): C = shBf(bf16) @ W + bias + res ========
__global__ __launch_bounds__(256) void gemm_mfma_kernel(
    const unsigned short* __restrict__ A, const unsigned short* __restrict__ Wt,
    const float* __restrict__ bias, const float* __restrict__ res,
    float* __restrict__ C, int Mr, int Nr, int Kr)
{
    __shared__ __align__(16) unsigned short As[32][40];
    __shared__ __align__(16) unsigned short Bs[64][40];
    int tid = threadIdx.x;
    int row0 = blockIdx.x*32, col0 = blockIdx.y*64;
    int wave = tid >> 6, lane = tid & 63;
    int lr = lane & 15, lk = lane >> 4;

    f32x4 acc[2] = {};

    for (int k0 = 0; k0 < Kr; k0 += 32){
        __syncthreads();
        {
            int r = tid >> 3, kq = tid & 7;
            *(uint2*)&As[r][kq*4] = *(const uint2*)(A + (size_t)(row0 + r)*Kr + k0 + kq*4);
        }
        {
            int n = tid >> 2, oq = tid & 3;
            *(uint4*)&Bs[n][oq*8] = *(const uint4*)(Wt + (size_t)(col0+n)*Kr + k0 + oq*8);
        }
        __syncthreads();
        bf16x8_t a0 = *reinterpret_cast<const bf16x8_t*>(&As[lr][lk*8]);
        bf16x8_t a1 = *reinterpret_cast<const bf16x8_t*>(&As[16 + lr][lk*8]);
        bf16x8_t bfr = *reinterpret_cast<const bf16x8_t*>(&Bs[wave*16 + lr][lk*8]);
        acc[0] = __builtin_amdgcn_mfma_f32_16x16x32_bf16(a0, bfr, acc[0], 0, 0, 0);
        acc[1] = __builtin_amdgcn_mfma_f32_16x16x32_bf16(a1, bfr, acc[1], 0, 0, 0);
    }
    int gc = col0 + wave*16 + lr;
    float bv = bias[gc];
    #pragma unroll
    for (int m=0;m<2;++m){
        #pragma unroll
        for (int r=0;r<4;++r){
            int gr = row0 + m*16 + lk*4 + r;
            float v = acc[m][r] + bv;
            size_t off = (size_t)gr*Nr + gc;
            if (res) v += res[off];
            C[off] = v;
        }
    }
}

// ======== fused 4-split combine + modulated LN + silu -> bf16 output ========
__global__ __launch_bounds__(256) void lnmod_combine_kernel(
    const float* __restrict__ po, const float* __restrict__ pm, const float* __restrict__ pl,
    const float* __restrict__ g, const float* __restrict__ bb,
    const float* __restrict__ eo, unsigned short* __restrict__ outBf)
{
    int row = blockIdx.x, tid = threadIdx.x;
    int b = row / TT, t = row % TT;
    __shared__ float xsr[LATD];
    __shared__ float red[256];
    float s = 0.f;
    for (int i=tid;i<LATD;i+=256){
        int h = i >> 6, d = i & 63;
        size_t rowid = ((size_t)(b*HH + h))*TT + t;
        float m = -1e30f;
        #pragma unroll
        for (int k=0;k<NSPLIT;++k) m = fmaxf(m, pm[(size_t)k*NROWS + rowid]);
        float lsum = 0.f, acc = 0.f;
        #pragma unroll
        for (int k=0;k<NSPLIT;++k){
            float sk = __expf(pm[(size_t)k*NROWS + rowid] - m);
            lsum += pl[(size_t)k*NROWS + rowid]*sk;
            acc  += po[((size_t)k*NROWS + rowid)*64 + d]*sk;
        }
        float v = acc / lsum;
        xsr[i] = v; s += v;
    }
    red[tid]=s; __syncthreads();
    for (int k=128;k>0;k>>=1){ if (tid<k) red[tid]+=red[tid+k]; __syncthreads(); }
    float mean = red[0]*(1.0f/LATD);
    __syncthreads();
    float vs=0.f;
    for (int i=tid;i<LATD;i+=256){ float d=xsr[i]-mean; vs+=d*d; }
    red[tid]=vs; __syncthreads();
    for (int k=128;k>0;k>>=1){ if (tid<k) red[tid]+=red[tid+k]; __syncthreads(); }
    float rstd = rsqrtf(red[0]*(1.0f/LATD)+1e-5f);
    const float* ep = eo + (size_t)row*(2*LATD);
    unsigned short* op = outBf + (size_t)row*LATD;
    for (int i=tid;i<LATD;i+=256){
        float v = (xsr[i]-mean)*rstd*g[i] + bb[i];
        v = v*(1.0f + ep[i]) + ep[LATD+i];
        op[i] = f2bf(siluf(v));
    }
}

extern "C" void kernel_launch(void* const* d_in, const int* in_sizes, int n_in,
                              void* d_out, int out_size, void* d_ws, size_t ws_size,
                              hipStream_t stream)
{
    (void)in_sizes; (void)n_in; (void)out_size; (void)ws_size;
    const float* x     = (const float*)d_in[0];
    const float* emb   = (const float*)d_in[1];
    const int*   smask = (const int*)d_in[2];
    const float* tcond = (const float*)d_in[5];
    const float* two   = (const float*)d_in[6];
    const float* ng    = (const float*)d_in[7];
    const float* nb    = (const float*)d_in[8];
    const float* memb  = (const float*)d_in[9];
    const float* m_wg  = (const float*)d_in[10];
    const float* m_w1  = (const float*)d_in[11];
    const float* m_b1  = (const float*)d_in[12];
    const float* m_w2  = (const float*)d_in[13];
    const float* m_b2  = (const float*)d_in[14];
    const float* m_pw  = (const float*)d_in[15];
    const float* m_pb  = (const float*)d_in[16];
    const float* kms   = (const float*)d_in[17];
    const float* sigma = (const float*)d_in[18];
    const float* kdat  = (const float*)d_in[19];
    const float* kds   = (const float*)d_in[20];
    const float* vdat  = (const float*)d_in[21];
    const float* krot  = (const float*)d_in[22];
    const float* krs   = (const float*)d_in[23];
    const float* vrot  = (const float*)d_in[24];
    const float* ntg   = (const float*)d_in[25];
    const float* ntb   = (const float*)d_in[26];
    const float* c_wg  = (const float*)d_in[27];
    const float* c_w1  = (const float*)d_in[28];
    const float* c_b1  = (const float*)d_in[29];
    const float* c_w2  = (const float*)d_in[30];
    const float* c_b2  = (const float*)d_in[31];
    const float* c_pw  = (const float*)d_in[32];
    const float* c_pb  = (const float*)d_in[33];
    const float* kts   = (const float*)d_in[34];
    const float* st_ew = (const float*)d_in[35];
    const float* st_eb = (const float*)d_in[36];
    const float* st_ng = (const float*)d_in[37];
    const float* st_nb = (const float*)d_in[38];
    const float* st_ow = (const float*)d_in[39];
    const float* st_ob = (const float*)d_in[40];

    float* ws = (float*)d_ws;
    float* xh   = ws;
    float* qB   = xh  + 1310720;
    float* kmB  = qB  + 1310720;
    float* vmB  = kmB + 1310720;
    float* ctB  = vmB + 1310720;
    float* ktB  = ctB + 197120;
    float* vtB  = ktB + 197120;
    float* aout = vtB + 197120;
    float* eoB  = aout + 1310720;
    float* shB  = eoB + 2621440;

    unsigned short* w1Tm = (unsigned short*)(shB + 1310720);
    unsigned short* w2Tm = w1Tm + EE*FFND*DD;
    unsigned short* w1Tt = w2Tm + EE*FFND*DD;
    unsigned short* w2Tt = w1Tt + EE*FFND*DD;
    unsigned short* stewT = w2Tt + EE*FFND*DD;
    unsigned short* stowT = stewT + 512*1280;
    unsigned short* mpwT  = stowT + 640*640;
    unsigned short* cpwT  = mpwT + 320*64;
    unsigned short* embBf = cpwT + 128*64;
    float* poB = (float*)(embBf + 2048*512);
    float* pmB = poB + (size_t)NSPLIT*NROWS*64;
    float* plB = pmB + (size_t)NSPLIT*NROWS;
    unsigned short* KbfB  = (unsigned short*)(plB + (size_t)NSPLIT*NROWS);  // 40*11*4096 u16
    unsigned short* VTbfB = KbfB + (size_t)BB*HH*NCH*4096;
    float* maddB = (float*)(VTbfB + (size_t)BB*HH*NCH*4096);                // B*NSP

    float* yslotM = eoB;
    float* yslotT = shB;
    unsigned short* shBf = (unsigned short*)shB;   // bf16 LN output (aliases shB; yslotT dead by then)
    float* wAm   = aout;
    float* wAt   = wAm + NTOK_M*2;
    int*   cntA  = (int*)(wAt + NTOK_T*2);
    int*   listM = cntA + 16;
    int*   listT = listM + EE*NTOK_M;

    prep_ln_kernel<<<651 + BB*TT + BB*MM, 256, 0, stream>>>(
        m_w1, w1Tm, m_w2, w2Tm, c_w1, w1Tt, c_w2, w2Tt,
        st_ew, stewT, st_ow, stowT, m_pw, mpwT, c_pw, cpwT,
        emb, embBf, cntA,
        x, ng, nb, memb, xh, two, ntg, ntb, ctB);

    route_kernel<<<ROUTEB_M + ROUTEB_T, 256, 0, stream>>>(
        xh, m_wg, cntA, listM, wAm,
        ctB, c_wg, cntA+8, listT, wAt);

    moe_ffn_kernel<<<MAXB_M + MAXB_T, 256, 0, stream>>>(
        xh, w1Tm, m_b1, w2Tm, m_b2, cntA, listM, wAm, yslotM,
        ctB, w1Tt, c_b1, w2Tt, c_b2, cntA+8, listT, wAt, yslotT);

    moe_proj_kernel<<<PROJB_M + PROJB_T, 256, 0, stream>>>(
        yslotM, mpwT, m_pb, qB, kmB, vmB,
        yslotT, cpwT, c_pb, ktB, vtB);

    {
        dim3 gp(BB*HH, NCH);
        kv_prep_kernel<<<gp, 256, 0, stream>>>(
            kmB, vmB, ktB, vtB, kdat, vdat, krot, vrot, smask, tcond,
            kms, kds, krs, kts, KbfB, VTbfB, maddB);
    }

    attn_gemm_kernel<<<ATTNB + GEMM1B, 256, 0, stream>>>(
        qB, KbfB, VTbfB, maddB, sigma, poB, pmB, plB,
        embBf, stewT, st_eb, eoB);

    lnmod_combine_kernel<<<BB*TT, 256, 0, stream>>>(
        poB, pmB, plB, st_ng, st_nb, eoB, shBf);

    {
        dim3 g2(2048/32, 640/64);
        gemm_mfma_kernel<<<g2, 256, 0, stream>>>(shBf, stowT, st_ob, x, (float*)d_out, 2048, 640, 640);
    }
}